// Round 7
// baseline (10336.938 us; speedup 1.0000x reference)
//
#include <hip/hip_runtime.h>
#include <cstdint>

constexpr int NB   = 8;
constexpr int S    = 1024;
constexpr int CD   = 128;
constexpr int DIN  = 512;
constexpr int BATCH= 16;
constexpr int T    = 4096;
constexpr int NTOK = BATCH * T;        // 65536
constexpr int FCAP = 24;
constexpr float MARGIN = 4e-3f;        // >> 1.3e-3 worst-case bf16 approx error

typedef __attribute__((ext_vector_type(8))) short bf16x8;
typedef __attribute__((ext_vector_type(4))) float f32x4;

__device__ __forceinline__ unsigned short f2bf(float f) {
  unsigned int u = __float_as_uint(f);
  return (unsigned short)((u + 0x7fffu + ((u >> 16) & 1u)) >> 16);
}
__device__ __forceinline__ float bf2f(unsigned short h) {
  return __uint_as_float((unsigned int)h << 16);
}

// ---------------------------------------------------------------------------
__global__ __launch_bounds__(256) void cbn32_kernel(const float* __restrict__ cbs,
                                                    float* __restrict__ cbn32) {
  int row = blockIdx.x * 256 + threadIdx.x;
  if (row >= NB * S) return;
  const float4* r4 = reinterpret_cast<const float4*>(cbs + (size_t)row * CD);
  double s = 0.0;
  for (int q = 0; q < 32; ++q) {
    float4 v = r4[q];
    s += (double)v.x * v.x + (double)v.y * v.y + (double)v.z * v.z + (double)v.w * v.w;
  }
  cbn32[row] = (float)s;
}

__global__ __launch_bounds__(256) void cb16_kernel(const float* __restrict__ cbs,
                                                   unsigned short* __restrict__ cb16) {
  int i = blockIdx.x * 256 + threadIdx.x;
  if (i < NB * S * CD) cb16[i] = f2bf(cbs[i]);
}

__global__ __launch_bounds__(256) void p64t_kernel(const float* __restrict__ Win,
                                                   const float* __restrict__ Wout,
                                                   double* __restrict__ P64t) {
  int n = blockIdx.x * 256 + threadIdx.x;   // 16384
  int k = n >> 7, d = n & 127;
  double s = 0.0;
  for (int D = 0; D < DIN; ++D)
    s = fma((double)Win[(size_t)d * DIN + D], (double)Wout[(size_t)D * CD + k], s);
  P64t[(size_t)k * CD + d] = s;
}

__global__ void cvec64_kernel(const float* __restrict__ Win,
                              const float* __restrict__ bout,
                              double* __restrict__ cvec64) {
  int d = threadIdx.x;  // 128
  double s = 0.0;
  for (int D = 0; D < DIN; ++D)
    s = fma((double)Win[(size_t)d * DIN + D], (double)bout[D], s);
  cvec64[d] = s;
}

// ---------------------------------------------------------------------------
// A64[b][d][t] = fp64( sum_D Win[d,D]*z[b,D,t] + bin[d] )
__global__ __launch_bounds__(256) void a64_kernel(const float* __restrict__ z,
                                                  const float* __restrict__ Win,
                                                  const float* __restrict__ bin,
                                                  double* __restrict__ A64) {
  __shared__ __align__(16) float Al[32][132];
  __shared__ __align__(16) float Bl[32][68];
  const int tid = threadIdx.x;
  const int t0 = blockIdx.x * 64;
  const int b  = blockIdx.y;
  const int mx = tid & 15, nx = tid >> 4;
  double acc[8][4] = {};
  for (int kc = 0; kc < 16; ++kc) {
    __syncthreads();
#pragma unroll
    for (int rep = 0; rep < 4; ++rep) {
      int idx = rep * 256 + tid;
      int r = idx >> 3, q = idx & 7;
      float4 v = reinterpret_cast<const float4*>(Win)[(size_t)r * 128 + kc * 8 + q];
      Al[q * 4 + 0][r] = v.x; Al[q * 4 + 1][r] = v.y;
      Al[q * 4 + 2][r] = v.z; Al[q * 4 + 3][r] = v.w;
    }
#pragma unroll
    for (int rep = 0; rep < 2; ++rep) {
      int idx = rep * 256 + tid;
      int kk = idx >> 4, q = idx & 15;
      float4 v = reinterpret_cast<const float4*>(z + ((size_t)(b * DIN + kc * 32 + kk)) * T + t0)[q];
      *reinterpret_cast<float4*>(&Bl[kk][q * 4]) = v;
    }
    __syncthreads();
#pragma unroll
    for (int kk = 0; kk < 32; ++kk) {
      float4 a0 = *reinterpret_cast<const float4*>(&Al[kk][mx * 8]);
      float4 a1 = *reinterpret_cast<const float4*>(&Al[kk][mx * 8 + 4]);
      float4 bv = *reinterpret_cast<const float4*>(&Bl[kk][nx * 4]);
      double a[8] = {a0.x, a0.y, a0.z, a0.w, a1.x, a1.y, a1.z, a1.w};
      double bb[4] = {bv.x, bv.y, bv.z, bv.w};
#pragma unroll
      for (int u = 0; u < 8; ++u)
#pragma unroll
        for (int j = 0; j < 4; ++j) acc[u][j] = fma(a[u], bb[j], acc[u][j]);
    }
  }
#pragma unroll
  for (int u = 0; u < 8; ++u) {
    int d = mx * 8 + u;
    double bi = (double)bin[d];
    double* Ap = A64 + ((size_t)(b * CD + d)) * T + t0 + nx * 4;
#pragma unroll
    for (int j = 0; j < 4; ++j) Ap[j] = acc[u][j] + bi;
  }
}

// ---------------------------------------------------------------------------
// z32 = fl32(A64 - P*qs64 - book*cvec) ; z16 = bf16(z32)
__global__ __launch_bounds__(256) void zproj32_kernel(const double* __restrict__ A64,
                                                      const double* __restrict__ qs64,
                                                      const double* __restrict__ P64t,
                                                      const double* __restrict__ cvec64,
                                                      float* __restrict__ z32,
                                                      unsigned short* __restrict__ z16,
                                                      int book) {
  __shared__ double Q[16][64];
  const int tid = threadIdx.x;
  const int tok0 = blockIdx.x * 64;
  const int b = tok0 >> 12, tloc = tok0 & (T - 1);
  const int d = tid & 127, h = tid >> 7;
  double acc[32];
  const double* Ap = A64 + ((size_t)(b * CD + d)) * T + tloc + h * 32;
#pragma unroll
  for (int j = 0; j < 32; ++j) acc[j] = Ap[j];
  if (book > 0) {
    for (int kc = 0; kc < 8; ++kc) {
      __syncthreads();
#pragma unroll
      for (int rep = 0; rep < 4; ++rep) {
        int idx = rep * 256 + tid;
        int kkk = idx >> 6, tt = idx & 63;
        Q[kkk][tt] = qs64[(size_t)(kc * 16 + kkk) * NTOK + tok0 + tt];
      }
      __syncthreads();
#pragma unroll
      for (int kk = 0; kk < 16; ++kk) {
        double p = P64t[(size_t)(kc * 16 + kk) * CD + d];
#pragma unroll
        for (int j = 0; j < 32; ++j) acc[j] = fma(-p, Q[kk][h * 32 + j], acc[j]);
      }
    }
    double cv = (double)book * cvec64[d];
#pragma unroll
    for (int j = 0; j < 32; ++j) acc[j] -= cv;
  }
  float* zp = z32 + (size_t)d * NTOK + tok0 + h * 32;
  unsigned short* hp = z16 + (size_t)d * NTOK + tok0 + h * 32;
#pragma unroll
  for (int j = 0; j < 32; ++j) {
    float f = (float)acc[j];
    zp[j] = f;
    hp[j] = f2bf(f);
  }
}

// ---------------------------------------------------------------------------
// bf16 MFMA approx scores + conservative candidate flagging.
__global__ __launch_bounds__(256) void score_mfma_kernel(
    const unsigned short* __restrict__ z16,
    const unsigned short* __restrict__ cb16b,
    const float* __restrict__ cbn32b,
    unsigned short* __restrict__ fgl,
    int* __restrict__ fcg,
    float* __restrict__ dump,
    int book) {
  __shared__ unsigned short cbL[128][136];
  __shared__ unsigned short ZtT[64][136];
  __shared__ float Cn[128];
  __shared__ float gmin[64];
  __shared__ float wmin[4][64];
  __shared__ int   fcnt[64];
  __shared__ unsigned short fls[64][FCAP];
  const int tid = threadIdx.x;
  const int tok0 = blockIdx.x * 64;
  const int wv = tid >> 6, ln = tid & 63;
  const int lr = ln & 15, lg = ln >> 4;

  for (int rep = 0; rep < 4; ++rep) {           // z16 [k][tok] -> LDS [t][k]
    int idx = rep * 256 + tid;
    int k = idx >> 3, tg = idx & 7;
    bf16x8 v = *reinterpret_cast<const bf16x8*>(z16 + (size_t)k * NTOK + tok0 + tg * 8);
#pragma unroll
    for (int e = 0; e < 8; ++e) ZtT[tg * 8 + e][k] = (unsigned short)v[e];
  }
  if (tid < 64) { gmin[tid] = 3.4e38f; fcnt[tid] = 0; }

  for (int c = 0; c < 8; ++c) {
    __syncthreads();
    for (int rep = 0; rep < 8; ++rep) {         // cb16 chunk rows
      int idx = rep * 256 + tid;
      int s = idx >> 4, q = idx & 15;
      *reinterpret_cast<bf16x8*>(&cbL[s][q * 8]) =
          *reinterpret_cast<const bf16x8*>(cb16b + (size_t)(c * 128 + s) * 128 + q * 8);
    }
    if (tid < 128) Cn[tid] = cbn32b[c * 128 + tid];
    __syncthreads();

    f32x4 acc[2][4];
#pragma unroll
    for (int ss = 0; ss < 2; ++ss)
#pragma unroll
      for (int ts = 0; ts < 4; ++ts) acc[ss][ts] = (f32x4){0.f, 0.f, 0.f, 0.f};
#pragma unroll
    for (int ks = 0; ks < 4; ++ks) {
      bf16x8 a0 = *reinterpret_cast<const bf16x8*>(&cbL[wv * 32 + lr][ks * 32 + lg * 8]);
      bf16x8 a1 = *reinterpret_cast<const bf16x8*>(&cbL[wv * 32 + 16 + lr][ks * 32 + lg * 8]);
      bf16x8 b0 = *reinterpret_cast<const bf16x8*>(&ZtT[lr][ks * 32 + lg * 8]);
      bf16x8 b1 = *reinterpret_cast<const bf16x8*>(&ZtT[16 + lr][ks * 32 + lg * 8]);
      bf16x8 b2 = *reinterpret_cast<const bf16x8*>(&ZtT[32 + lr][ks * 32 + lg * 8]);
      bf16x8 b3 = *reinterpret_cast<const bf16x8*>(&ZtT[48 + lr][ks * 32 + lg * 8]);
      acc[0][0] = __builtin_amdgcn_mfma_f32_16x16x32_bf16(a0, b0, acc[0][0], 0, 0, 0);
      acc[0][1] = __builtin_amdgcn_mfma_f32_16x16x32_bf16(a0, b1, acc[0][1], 0, 0, 0);
      acc[0][2] = __builtin_amdgcn_mfma_f32_16x16x32_bf16(a0, b2, acc[0][2], 0, 0, 0);
      acc[0][3] = __builtin_amdgcn_mfma_f32_16x16x32_bf16(a0, b3, acc[0][3], 0, 0, 0);
      acc[1][0] = __builtin_amdgcn_mfma_f32_16x16x32_bf16(a1, b0, acc[1][0], 0, 0, 0);
      acc[1][1] = __builtin_amdgcn_mfma_f32_16x16x32_bf16(a1, b1, acc[1][1], 0, 0, 0);
      acc[1][2] = __builtin_amdgcn_mfma_f32_16x16x32_bf16(a1, b2, acc[1][2], 0, 0, 0);
      acc[1][3] = __builtin_amdgcn_mfma_f32_16x16x32_bf16(a1, b3, acc[1][3], 0, 0, 0);
    }
    // d2a = cbn - 2*E  (C layout: col=lane&15 -> t, row=(lane>>4)*4+reg -> s)
#pragma unroll
    for (int ss = 0; ss < 2; ++ss)
#pragma unroll
      for (int ts = 0; ts < 4; ++ts)
#pragma unroll
        for (int r = 0; r < 4; ++r)
          acc[ss][ts][r] = fmaf(-2.f, acc[ss][ts][r], Cn[wv * 32 + ss * 16 + lg * 4 + r]);
    float mts[4];
#pragma unroll
    for (int ts = 0; ts < 4; ++ts) {
      float m = acc[0][ts][0];
#pragma unroll
      for (int r = 1; r < 4; ++r) m = fminf(m, acc[0][ts][r]);
#pragma unroll
      for (int r = 0; r < 4; ++r) m = fminf(m, acc[1][ts][r]);
      m = fminf(m, __shfl_xor(m, 16));
      m = fminf(m, __shfl_xor(m, 32));
      mts[ts] = m;
    }
    if (lg == 0) {
#pragma unroll
      for (int ts = 0; ts < 4; ++ts) wmin[wv][ts * 16 + lr] = mts[ts];
    }
    __syncthreads();
    if (tid < 64) {
      float g = fminf(fminf(wmin[0][tid], wmin[1][tid]), fminf(wmin[2][tid], wmin[3][tid]));
      gmin[tid] = fminf(gmin[tid], g);
    }
    __syncthreads();
    // conservative flag pass (vs running min incl. this chunk => superset)
#pragma unroll
    for (int ts = 0; ts < 4; ++ts) {
      int t = ts * 16 + lr;
      float thr = gmin[t] + MARGIN;
#pragma unroll
      for (int ss = 0; ss < 2; ++ss)
#pragma unroll
        for (int r = 0; r < 4; ++r) {
          float v = acc[ss][ts][r];
          int s = c * 128 + wv * 32 + ss * 16 + lg * 4 + r;
          if (book == 0 && blockIdx.x == 0 && c == 0)
            dump[(size_t)(wv * 32 + ss * 16 + lg * 4 + r) * 64 + t] = v;
          if (v <= thr) {
            int pos = atomicAdd(&fcnt[t], 1);
            if (pos < FCAP) fls[t][pos] = (unsigned short)s;
          }
        }
    }
  }
  __syncthreads();
  if (tid < 64) fcg[tok0 + tid] = fcnt[tid];
  for (int idx = tid; idx < 64 * FCAP; idx += 256) {
    int t = idx / FCAP, i = idx - t * FCAP;
    fgl[(size_t)(tok0 + t) * FCAP + i] = fls[t][i];
  }
}

// ---------------------------------------------------------------------------
// Verify MFMA layout: dump tile vs fp64 recompute of bf16-dequantized inputs.
__global__ __launch_bounds__(256) void probe_kernel(const unsigned short* __restrict__ z16,
                                                    const unsigned short* __restrict__ cb16,
                                                    const float* __restrict__ cbn32,
                                                    const float* __restrict__ dump,
                                                    int* __restrict__ probe_ok) {
  __shared__ float red[256];
  const int tid = threadIdx.x;
  float mx = 0.f;
  for (int p = tid; p < 8192; p += 256) {
    int s = p >> 6, t = p & 63;
    double e = 0.0;
    for (int d = 0; d < 128; ++d)
      e += (double)bf2f(cb16[(size_t)s * 128 + d]) * (double)bf2f(z16[(size_t)d * NTOK + t]);
    float ref = fmaf(-2.f, (float)e, cbn32[s]);
    mx = fmaxf(mx, fabsf(ref - dump[p]));
  }
  red[tid] = mx;
  __syncthreads();
  for (int off = 128; off; off >>= 1) {
    if (tid < off) red[tid] = fmaxf(red[tid], red[tid + off]);
    __syncthreads();
  }
  if (tid == 0) *probe_ok = (red[0] < 1e-4f) ? 1 : 0;
}

// ---------------------------------------------------------------------------
// Exact (bitwise round-6) evaluation of flagged candidates; first-index ties.
__global__ __launch_bounds__(256) void refine_kernel(const float* __restrict__ z32,
                                                     const float* __restrict__ cbb,
                                                     const float* __restrict__ cbn32b,
                                                     const unsigned short* __restrict__ fgl,
                                                     const int* __restrict__ fcg,
                                                     const int* __restrict__ probe_ok,
                                                     int* __restrict__ codes,
                                                     double* __restrict__ lpartF,
                                                     int book) {
  if (!*probe_ok) return;
  __shared__ float Zl[128][64];
  __shared__ double znp[4][64];
  __shared__ float znl[64];
  __shared__ float bestv[4][64];
  __shared__ int   bests[4][64];
  __shared__ double lred[64];
  const int tid = threadIdx.x;
  const int tok0 = blockIdx.x * 64;
  const int b = tok0 >> 12;
  const int tl = tid & 63, h = tid >> 6;
  // stage z32 tile
  for (int rep = 0; rep < 8; ++rep) {
    int idx = rep * 256 + tid;
    int d = idx >> 4, q = idx & 15;
    float4 v = *reinterpret_cast<const float4*>(z32 + (size_t)d * NTOK + tok0 + q * 4);
    Zl[d][q * 4 + 0] = v.x; Zl[d][q * 4 + 1] = v.y;
    Zl[d][q * 4 + 2] = v.z; Zl[d][q * 4 + 3] = v.w;
  }
  __syncthreads();
  { // zn: bitwise-identical to round-6 path
    double s = 0.0;
#pragma unroll
    for (int dd = 0; dd < 32; ++dd) { double v = (double)Zl[h * 32 + dd][tl]; s += v * v; }
    znp[h][tl] = s;
  }
  __syncthreads();
  if (tid < 64) znl[tid] = (float)(((znp[0][tid] + znp[1][tid]) + znp[2][tid]) + znp[3][tid]);
  __syncthreads();
  const float zn = znl[tl];
  const int tok = tok0 + tl;
  const int cnt = fcg[tok];
  float bm = 3.4e38f; int bi = 0x7fffffff;
  if (cnt <= FCAP) {
    for (int i = h; i < cnt; i += 4) {
      int s = fgl[(size_t)tok * FCAP + i];
      const float* cr = cbb + (size_t)s * CD;
      double e = 0.0;
      for (int d = 0; d < CD; ++d) e = fma((double)cr[d], (double)Zl[d][tl], e);
      float M = (float)e;
      float d2 = __fadd_rn(__fsub_rn(zn, __fmul_rn(2.f, M)), cbn32b[s]);
      if (d2 < bm || (d2 == bm && s < bi)) { bm = d2; bi = s; }
    }
  } else {   // overflow: full exact scan (rare)
    for (int s = h; s < S; s += 4) {
      const float* cr = cbb + (size_t)s * CD;
      double e = 0.0;
      for (int d = 0; d < CD; ++d) e = fma((double)cr[d], (double)Zl[d][tl], e);
      float M = (float)e;
      float d2 = __fadd_rn(__fsub_rn(zn, __fmul_rn(2.f, M)), cbn32b[s]);
      if (d2 < bm || (d2 == bm && s < bi)) { bm = d2; bi = s; }
    }
  }
  bestv[h][tl] = bm; bests[h][tl] = bi;
  __syncthreads();
  if (tid < 64) {
    float fv = bestv[0][tid]; int fs = bests[0][tid];
#pragma unroll
    for (int x = 1; x < 4; ++x) {
      float v = bestv[x][tid]; int s = bests[x][tid];
      if (v < fv || (v == fv && s < fs)) { fv = v; fs = s; }
    }
    codes[((size_t)b * NB + book) * T + (tok & (T - 1))] = fs;
    lred[tid] = (double)fv;
  }
  __syncthreads();
  if (tid == 0) {
    double sum = 0.0;
    for (int i = 0; i < 64; ++i) sum += lred[i];
    lpartF[(size_t)book * 1024 + blockIdx.x] = sum;
  }
}

// ---------------------------------------------------------------------------
// FALLBACK: round-6 proven score kernel, active only if probe failed.
__global__ __launch_bounds__(256) void score_fb_kernel(const float* __restrict__ z32,
                                                       const float* __restrict__ cb,
                                                       const float* __restrict__ cbn32b,
                                                       int* __restrict__ codes,
                                                       double* __restrict__ lpart,
                                                       const int* __restrict__ probe_ok,
                                                       int book) {
  if (*probe_ok) return;
  __shared__ __align__(16) float Zl[128][68];
  __shared__ __align__(16) float Al[32][132];
  __shared__ float Cn[128];
  __shared__ double znp[4][64];
  __shared__ float zn[64];
  __shared__ double lred[16];
  const int tid = threadIdx.x;
  const int t0 = blockIdx.x * 64;
  const int b  = blockIdx.y;
  const int mx = tid & 15, nx = tid >> 4;
  const size_t tokbase = (size_t)b * T + t0;
  float* Rm1 = &Al[0][0];
  int*   Ri  = reinterpret_cast<int*>(&Al[0][0]) + 1024;
#pragma unroll
  for (int rep = 0; rep < 8; ++rep) {
    int idx = rep * 256 + tid;
    int d = idx >> 4, q = idx & 15;
    float4 v = *reinterpret_cast<const float4*>(z32 + (size_t)d * NTOK + tokbase + q * 4);
    *reinterpret_cast<float4*>(&Zl[d][q * 4]) = v;
  }
  __syncthreads();
  {
    int tt = tid & 63, part = tid >> 6;
    double s = 0.0;
#pragma unroll
    for (int dd = 0; dd < 32; ++dd) { double v = (double)Zl[part * 32 + dd][tt]; s += v * v; }
    znp[part][tt] = s;
  }
  __syncthreads();
  if (tid < 64) zn[tid] = (float)(((znp[0][tid] + znp[1][tid]) + znp[2][tid]) + znp[3][tid]);
  const float INF = 3.4e38f;
  float gm1[4] = {INF, INF, INF, INF};
  int   gi1[4] = {0, 0, 0, 0};
  for (int c = 0; c < 8; ++c) {
    double acc[8][4] = {};
    for (int kc = 0; kc < 4; ++kc) {
      __syncthreads();
      if (kc == 0 && tid < 128) Cn[tid] = cbn32b[c * 128 + tid];
#pragma unroll
      for (int rep = 0; rep < 4; ++rep) {
        int idx = rep * 256 + tid;
        int r = idx >> 3, q = idx & 7;
        float4 v = reinterpret_cast<const float4*>(cb)[(size_t)(c * 128 + r) * 32 + kc * 8 + q];
        Al[q * 4 + 0][r] = v.x; Al[q * 4 + 1][r] = v.y;
        Al[q * 4 + 2][r] = v.z; Al[q * 4 + 3][r] = v.w;
      }
      __syncthreads();
#pragma unroll
      for (int kk = 0; kk < 32; ++kk) {
        float4 a0 = *reinterpret_cast<const float4*>(&Al[kk][mx * 8]);
        float4 a1 = *reinterpret_cast<const float4*>(&Al[kk][mx * 8 + 4]);
        float4 bv = *reinterpret_cast<const float4*>(&Zl[kc * 32 + kk][nx * 4]);
        double a[8] = {a0.x, a0.y, a0.z, a0.w, a1.x, a1.y, a1.z, a1.w};
        double bb[4] = {bv.x, bv.y, bv.z, bv.w};
#pragma unroll
        for (int u = 0; u < 8; ++u)
#pragma unroll
          for (int j = 0; j < 4; ++j) acc[u][j] = fma(a[u], bb[j], acc[u][j]);
      }
    }
    float tm1[4]; int ti1[4];
#pragma unroll
    for (int j = 0; j < 4; ++j) {
      float m1 = INF; int i1 = 0;
      float znj = zn[nx * 4 + j];
#pragma unroll
      for (int u = 0; u < 8; ++u) {
        float M  = (float)acc[u][j];
        float dv = __fsub_rn(znj, __fmul_rn(2.0f, M));
        float d2 = __fadd_rn(dv, Cn[mx * 8 + u]);
        if (d2 < m1) { m1 = d2; i1 = c * 128 + mx * 8 + u; }
      }
      tm1[j] = m1; ti1[j] = i1;
    }
    __syncthreads();
#pragma unroll
    for (int j = 0; j < 4; ++j) {
      int slot = j * 256 + nx * 16 + mx;
      Rm1[slot] = tm1[j]; Ri[slot] = ti1[j];
    }
    __syncthreads();
    if (mx == 0) {
#pragma unroll
      for (int j = 0; j < 4; ++j) {
        float m1 = INF; int i1 = 0;
        for (int x = 0; x < 16; ++x) {
          int slot = j * 256 + nx * 16 + x;
          float am = Rm1[slot];
          if (am < m1) { m1 = am; i1 = Ri[slot]; }
        }
        if (m1 < gm1[j]) { gm1[j] = m1; gi1[j] = i1; }
      }
    }
  }
  if (mx == 0) {
    double lp = 0.0;
#pragma unroll
    for (int j = 0; j < 4; ++j) {
      codes[((size_t)b * NB + book) * T + t0 + nx * 4 + j] = gi1[j];
      lp += (double)gm1[j];
    }
    lred[nx] = lp;
  }
  __syncthreads();
  if (tid == 0) {
    double s = 0.0;
#pragma unroll
    for (int i = 0; i < 16; ++i) s += lred[i];
    lpart[(size_t)book * 1024 + b * 64 + blockIdx.x] = s;
  }
}

// ---------------------------------------------------------------------------
__global__ __launch_bounds__(256) void qsum64_kernel(double* __restrict__ qs64,
                                                     const float* __restrict__ cb,
                                                     const int* __restrict__ codes,
                                                     int book) {
  int tok = blockIdx.x * 256 + threadIdx.x;
  int b = tok >> 12, t = tok & (T - 1);
  int code = codes[((size_t)b * NB + book) * T + t];
  const float* row = cb + (size_t)code * CD;
  for (int k = 0; k < CD; ++k)
    qs64[(size_t)k * NTOK + tok] += (double)row[k];
}

// ---------------------------------------------------------------------------
__global__ __launch_bounds__(256) void final64_kernel(const double* __restrict__ qs64,
                                                      const float* __restrict__ Wout,
                                                      const float* __restrict__ bout,
                                                      float* __restrict__ out) {
  __shared__ __align__(16) float Al[32][132];
  __shared__ double Bl64[32][65];
  const int tid = threadIdx.x;
  const int t0 = blockIdx.x * 64;
  const int Dg = blockIdx.y;
  const int b  = blockIdx.z;
  const int mx = tid & 15, nx = tid >> 4;
  const size_t tokbase = (size_t)b * T + t0;
  double acc[8][4] = {};
  for (int kc = 0; kc < 4; ++kc) {
    __syncthreads();
#pragma unroll
    for (int rep = 0; rep < 4; ++rep) {
      int idx = rep * 256 + tid;
      int r = idx >> 3, q = idx & 7;
      float4 v = reinterpret_cast<const float4*>(Wout)[(size_t)(Dg * 128 + r) * 32 + kc * 8 + q];
      Al[q * 4 + 0][r] = v.x; Al[q * 4 + 1][r] = v.y;
      Al[q * 4 + 2][r] = v.z; Al[q * 4 + 3][r] = v.w;
    }
#pragma unroll
    for (int rep = 0; rep < 8; ++rep) {
      int idx = rep * 256 + tid;
      int kk = idx >> 6, tt = idx & 63;
      Bl64[kk][tt] = qs64[(size_t)(kc * 32 + kk) * NTOK + tokbase + tt];
    }
    __syncthreads();
#pragma unroll
    for (int kk = 0; kk < 32; ++kk) {
      double a[8];
#pragma unroll
      for (int u = 0; u < 8; ++u) a[u] = (double)Al[kk][mx * 8 + u];
#pragma unroll
      for (int j = 0; j < 4; ++j) {
        double bb = Bl64[kk][nx * 4 + j];
#pragma unroll
        for (int u = 0; u < 8; ++u) acc[u][j] = fma(a[u], bb, acc[u][j]);
      }
    }
  }
#pragma unroll
  for (int u = 0; u < 8; ++u) {
    int D = Dg * 128 + mx * 8 + u;
    double bo = 8.0 * (double)bout[D];
    float4 o = make_float4((float)(acc[u][0] + bo), (float)(acc[u][1] + bo),
                           (float)(acc[u][2] + bo), (float)(acc[u][3] + bo));
    reinterpret_cast<float4*>(out + ((size_t)b * DIN + D) * T + t0)[nx] = o;
  }
}

// ---------------------------------------------------------------------------
__global__ __launch_bounds__(256) void codes_out_kernel(const int* __restrict__ codes,
                                                        float* __restrict__ out) {
  int k = blockIdx.x * 256 + threadIdx.x;
  if (k < BATCH * NB * T)
    out[(size_t)BATCH * DIN * T + k] = (float)codes[k];
}

__global__ __launch_bounds__(256) void loss_out_kernel(const double* __restrict__ lpF,
                                                       const double* __restrict__ lpS,
                                                       const int* __restrict__ probe_ok,
                                                       float* __restrict__ out) {
  __shared__ double red[256];
  const double* lp = (*probe_ok) ? lpF : lpS;
  double s = 0.0;
  for (int i = threadIdx.x; i < NB * 1024; i += 256) s += lp[i];
  red[threadIdx.x] = s;
  __syncthreads();
  for (int off = 128; off; off >>= 1) {
    if (threadIdx.x < off) red[threadIdx.x] += red[threadIdx.x + off];
    __syncthreads();
  }
  if (threadIdx.x == 0)
    out[(size_t)BATCH * DIN * T + (size_t)BATCH * NB * T] =
        (float)(red[0] * 1.25 / 8388608.0);
}

// ---------------------------------------------------------------------------
extern "C" void kernel_launch(void* const* d_in, const int* in_sizes, int n_in,
                              void* d_out, int out_size, void* d_ws, size_t ws_size,
                              hipStream_t stream) {
  (void)in_sizes; (void)n_in; (void)out_size; (void)ws_size;
  const float* z    = (const float*)d_in[0];
  const float* Win  = (const float*)d_in[1];
  const float* bin  = (const float*)d_in[2];
  const float* Wout = (const float*)d_in[3];
  const float* bout = (const float*)d_in[4];
  const float* cbs  = (const float*)d_in[5];
  float* out = (float*)d_out;
  double* A64 = (double*)d_out;   // aliases z_q region; overwritten by final64

  char* w = (char*)d_ws;
  double* qs64  = (double*)w;  w += (size_t)CD * NTOK * 8;        // 67.1 MB
  double* P64t  = (double*)w;  w += (size_t)CD * CD * 8;
  double* cvec64= (double*)w;  w += CD * 8;
  double* lpartF= (double*)w;  w += (size_t)NB * 1024 * 8;
  double* lpartS= (double*)w;  w += (size_t)NB * 1024 * 8;
  float*  z32   = (float*)w;   w += (size_t)CD * NTOK * 4;        // 33.6 MB
  float*  cbn32 = (float*)w;   w += (size_t)NB * S * 4;
  float*  dump  = (float*)w;   w += 8192 * 4;
  unsigned short* z16  = (unsigned short*)w; w += (size_t)CD * NTOK * 2;   // 16.8 MB
  unsigned short* cb16 = (unsigned short*)w; w += (size_t)NB * S * CD * 2; // 2.1 MB
  unsigned short* fgl  = (unsigned short*)w; w += (size_t)NTOK * FCAP * 2; // 3.1 MB
  int*    fcg   = (int*)w;     w += (size_t)NTOK * 4;
  int*    codes = (int*)w;     w += (size_t)BATCH * NB * T * 4;
  int*    probe_ok = (int*)w;  w += 256;

  cbn32_kernel<<<(NB * S + 255) / 256, 256, 0, stream>>>(cbs, cbn32);
  cb16_kernel<<<(NB * S * CD + 255) / 256, 256, 0, stream>>>(cbs, cb16);
  p64t_kernel<<<64, 256, 0, stream>>>(Win, Wout, P64t);
  cvec64_kernel<<<1, 128, 0, stream>>>(Win, bout, cvec64);
  a64_kernel<<<dim3(T / 64, BATCH), 256, 0, stream>>>(z, Win, bin, A64);
  hipMemsetAsync(qs64, 0, (size_t)CD * NTOK * 8, stream);

  for (int book = 0; book < NB; ++book) {
    const float* cb = cbs + (size_t)book * S * CD;
    const unsigned short* cbh = cb16 + (size_t)book * S * CD;
    zproj32_kernel<<<NTOK / 64, 256, 0, stream>>>(A64, qs64, P64t, cvec64, z32, z16, book);
    score_mfma_kernel<<<NTOK / 64, 256, 0, stream>>>(z16, cbh, cbn32 + book * S,
                                                     fgl, fcg, dump, book);
    if (book == 0)
      probe_kernel<<<1, 256, 0, stream>>>(z16, cb16, cbn32, dump, probe_ok);
    refine_kernel<<<NTOK / 64, 256, 0, stream>>>(z32, cb, cbn32 + book * S,
                                                 fgl, fcg, probe_ok, codes, lpartF, book);
    score_fb_kernel<<<dim3(T / 64, BATCH), 256, 0, stream>>>(z32, cb, cbn32 + book * S,
                                                             codes, lpartS, probe_ok, book);
    qsum64_kernel<<<NTOK / 256, 256, 0, stream>>>(qs64, cb, codes, book);
  }
  final64_kernel<<<dim3(T / 64, DIN / 128, BATCH), 256, 0, stream>>>(qs64, Wout, bout, out);
  codes_out_kernel<<<(BATCH * NB * T + 255) / 256, 256, 0, stream>>>(codes, out);
  loss_out_kernel<<<1, 256, 0, stream>>>(lpartF, lpartS, probe_ok, out);
}

// Round 8
// 2898.324 us; speedup vs baseline: 3.5665x; 3.5665x over previous
//
#include <hip/hip_runtime.h>
#include <cstdint>

constexpr int NB   = 8;
constexpr int S    = 1024;
constexpr int CD   = 128;
constexpr int DIN  = 512;
constexpr int BATCH= 16;
constexpr int T    = 4096;
constexpr int NTOK = BATCH * T;        // 65536
constexpr int FCAP = 24;
constexpr float MARGIN = 4e-3f;        // > 2 * 1.3e-3 worst-case bf16 approx error

typedef __attribute__((ext_vector_type(8))) short bf16x8;
typedef __attribute__((ext_vector_type(4))) float f32x4;

__device__ __forceinline__ unsigned short f2bf(float f) {
  unsigned int u = __float_as_uint(f);
  return (unsigned short)((u + 0x7fffu + ((u >> 16) & 1u)) >> 16);
}
__device__ __forceinline__ float bf2f(unsigned short h) {
  return __uint_as_float((unsigned int)h << 16);
}

// ---------------------------------------------------------------------------
__global__ __launch_bounds__(256) void cbn32_kernel(const float* __restrict__ cbs,
                                                    float* __restrict__ cbn32) {
  int row = blockIdx.x * 256 + threadIdx.x;
  if (row >= NB * S) return;
  const float4* r4 = reinterpret_cast<const float4*>(cbs + (size_t)row * CD);
  double s = 0.0;
  for (int q = 0; q < 32; ++q) {
    float4 v = r4[q];
    s += (double)v.x * v.x + (double)v.y * v.y + (double)v.z * v.z + (double)v.w * v.w;
  }
  cbn32[row] = (float)s;
}

__global__ __launch_bounds__(256) void cb16_kernel(const float* __restrict__ cbs,
                                                   unsigned short* __restrict__ cb16) {
  int i = blockIdx.x * 256 + threadIdx.x;
  if (i < NB * S * CD) cb16[i] = f2bf(cbs[i]);
}

__global__ __launch_bounds__(256) void p64t_kernel(const float* __restrict__ Win,
                                                   const float* __restrict__ Wout,
                                                   double* __restrict__ P64t) {
  int n = blockIdx.x * 256 + threadIdx.x;   // 16384
  int k = n >> 7, d = n & 127;
  double s = 0.0;
  for (int D = 0; D < DIN; ++D)
    s = fma((double)Win[(size_t)d * DIN + D], (double)Wout[(size_t)D * CD + k], s);
  P64t[(size_t)k * CD + d] = s;
}

__global__ void cvec64_kernel(const float* __restrict__ Win,
                              const float* __restrict__ bout,
                              double* __restrict__ cvec64) {
  int d = threadIdx.x;  // 128
  double s = 0.0;
  for (int D = 0; D < DIN; ++D)
    s = fma((double)Win[(size_t)d * DIN + D], (double)bout[D], s);
  cvec64[d] = s;
}

// ---------------------------------------------------------------------------
// A64[b][d][t] = fp64( sum_D Win[d,D]*z[b,D,t] + bin[d] )
__global__ __launch_bounds__(256) void a64_kernel(const float* __restrict__ z,
                                                  const float* __restrict__ Win,
                                                  const float* __restrict__ bin,
                                                  double* __restrict__ A64) {
  __shared__ __align__(16) float Al[32][132];
  __shared__ __align__(16) float Bl[32][68];
  const int tid = threadIdx.x;
  const int t0 = blockIdx.x * 64;
  const int b  = blockIdx.y;
  const int mx = tid & 15, nx = tid >> 4;
  double acc[8][4] = {};
  for (int kc = 0; kc < 16; ++kc) {
    __syncthreads();
#pragma unroll
    for (int rep = 0; rep < 4; ++rep) {
      int idx = rep * 256 + tid;
      int r = idx >> 3, q = idx & 7;
      float4 v = reinterpret_cast<const float4*>(Win)[(size_t)r * 128 + kc * 8 + q];
      Al[q * 4 + 0][r] = v.x; Al[q * 4 + 1][r] = v.y;
      Al[q * 4 + 2][r] = v.z; Al[q * 4 + 3][r] = v.w;
    }
#pragma unroll
    for (int rep = 0; rep < 2; ++rep) {
      int idx = rep * 256 + tid;
      int kk = idx >> 4, q = idx & 15;
      float4 v = reinterpret_cast<const float4*>(z + ((size_t)(b * DIN + kc * 32 + kk)) * T + t0)[q];
      *reinterpret_cast<float4*>(&Bl[kk][q * 4]) = v;
    }
    __syncthreads();
#pragma unroll
    for (int kk = 0; kk < 32; ++kk) {
      float4 a0 = *reinterpret_cast<const float4*>(&Al[kk][mx * 8]);
      float4 a1 = *reinterpret_cast<const float4*>(&Al[kk][mx * 8 + 4]);
      float4 bv = *reinterpret_cast<const float4*>(&Bl[kk][nx * 4]);
      double a[8] = {a0.x, a0.y, a0.z, a0.w, a1.x, a1.y, a1.z, a1.w};
      double bb[4] = {bv.x, bv.y, bv.z, bv.w};
#pragma unroll
      for (int u = 0; u < 8; ++u)
#pragma unroll
        for (int j = 0; j < 4; ++j) acc[u][j] = fma(a[u], bb[j], acc[u][j]);
    }
  }
#pragma unroll
  for (int u = 0; u < 8; ++u) {
    int d = mx * 8 + u;
    double bi = (double)bin[d];
    double* Ap = A64 + ((size_t)(b * CD + d)) * T + t0 + nx * 4;
#pragma unroll
    for (int j = 0; j < 4; ++j) Ap[j] = acc[u][j] + bi;
  }
}

// ---------------------------------------------------------------------------
// z32 = fl32(A64 - P*qs64 - book*cvec) ; z16 = bf16(z32)
__global__ __launch_bounds__(256) void zproj32_kernel(const double* __restrict__ A64,
                                                      const double* __restrict__ qs64,
                                                      const double* __restrict__ P64t,
                                                      const double* __restrict__ cvec64,
                                                      float* __restrict__ z32,
                                                      unsigned short* __restrict__ z16,
                                                      int book) {
  __shared__ double Q[16][64];
  const int tid = threadIdx.x;
  const int tok0 = blockIdx.x * 64;
  const int b = tok0 >> 12, tloc = tok0 & (T - 1);
  const int d = tid & 127, h = tid >> 7;
  double acc[32];
  const double* Ap = A64 + ((size_t)(b * CD + d)) * T + tloc + h * 32;
#pragma unroll
  for (int j = 0; j < 32; ++j) acc[j] = Ap[j];
  if (book > 0) {
    for (int kc = 0; kc < 8; ++kc) {
      __syncthreads();
#pragma unroll
      for (int rep = 0; rep < 4; ++rep) {
        int idx = rep * 256 + tid;
        int kkk = idx >> 6, tt = idx & 63;
        Q[kkk][tt] = qs64[(size_t)(kc * 16 + kkk) * NTOK + tok0 + tt];
      }
      __syncthreads();
#pragma unroll
      for (int kk = 0; kk < 16; ++kk) {
        double p = P64t[(size_t)(kc * 16 + kk) * CD + d];
#pragma unroll
        for (int j = 0; j < 32; ++j) acc[j] = fma(-p, Q[kk][h * 32 + j], acc[j]);
      }
    }
    double cv = (double)book * cvec64[d];
#pragma unroll
    for (int j = 0; j < 32; ++j) acc[j] -= cv;
  }
  float* zp = z32 + (size_t)d * NTOK + tok0 + h * 32;
  unsigned short* hp = z16 + (size_t)d * NTOK + tok0 + h * 32;
#pragma unroll
  for (int j = 0; j < 32; ++j) {
    float f = (float)acc[j];
    zp[j] = f;
    hp[j] = f2bf(f);
  }
}

// ---------------------------------------------------------------------------
// bf16 MFMA approx scores, TWO-PASS:
//   pass A: per-token global min over all 1024 codes (no flags)
//   pass B: recompute (bitwise-identical MFMA) and flag d2a <= gmin + MARGIN
__global__ __launch_bounds__(256) void score_mfma_kernel(
    const unsigned short* __restrict__ z16,
    const unsigned short* __restrict__ cb16b,
    const float* __restrict__ cbn32b,
    unsigned short* __restrict__ fgl,
    int* __restrict__ fcg,
    float* __restrict__ dump,
    int book) {
  __shared__ unsigned short cbL[128][136];
  __shared__ unsigned short ZtT[64][136];
  __shared__ float Cna[1024];
  __shared__ float gmin[64];
  __shared__ float wmin[4][64];
  __shared__ int   fcnt[64];
  __shared__ unsigned short fls[64][FCAP];
  const int tid = threadIdx.x;
  const int tok0 = blockIdx.x * 64;
  const int wv = tid >> 6, ln = tid & 63;
  const int lr = ln & 15, lg = ln >> 4;

  for (int rep = 0; rep < 4; ++rep) {           // z16 [k][tok] -> LDS [t][k]
    int idx = rep * 256 + tid;
    int k = idx >> 3, tg = idx & 7;
    bf16x8 v = *reinterpret_cast<const bf16x8*>(z16 + (size_t)k * NTOK + tok0 + tg * 8);
#pragma unroll
    for (int e = 0; e < 8; ++e) ZtT[tg * 8 + e][k] = (unsigned short)v[e];
  }
#pragma unroll
  for (int rep = 0; rep < 4; ++rep) Cna[rep * 256 + tid] = cbn32b[rep * 256 + tid];
  if (tid < 64) { gmin[tid] = 3.4e38f; fcnt[tid] = 0; }

  // ======== PASS A: exact global min of d2a ========
  for (int c = 0; c < 8; ++c) {
    __syncthreads();
    for (int rep = 0; rep < 8; ++rep) {
      int idx = rep * 256 + tid;
      int s = idx >> 4, q = idx & 15;
      *reinterpret_cast<bf16x8*>(&cbL[s][q * 8]) =
          *reinterpret_cast<const bf16x8*>(cb16b + (size_t)(c * 128 + s) * 128 + q * 8);
    }
    __syncthreads();

    f32x4 acc[2][4];
#pragma unroll
    for (int ss = 0; ss < 2; ++ss)
#pragma unroll
      for (int ts = 0; ts < 4; ++ts) acc[ss][ts] = (f32x4){0.f, 0.f, 0.f, 0.f};
#pragma unroll
    for (int ks = 0; ks < 4; ++ks) {
      bf16x8 a0 = *reinterpret_cast<const bf16x8*>(&cbL[wv * 32 + lr][ks * 32 + lg * 8]);
      bf16x8 a1 = *reinterpret_cast<const bf16x8*>(&cbL[wv * 32 + 16 + lr][ks * 32 + lg * 8]);
      bf16x8 b0 = *reinterpret_cast<const bf16x8*>(&ZtT[lr][ks * 32 + lg * 8]);
      bf16x8 b1 = *reinterpret_cast<const bf16x8*>(&ZtT[16 + lr][ks * 32 + lg * 8]);
      bf16x8 b2 = *reinterpret_cast<const bf16x8*>(&ZtT[32 + lr][ks * 32 + lg * 8]);
      bf16x8 b3 = *reinterpret_cast<const bf16x8*>(&ZtT[48 + lr][ks * 32 + lg * 8]);
      acc[0][0] = __builtin_amdgcn_mfma_f32_16x16x32_bf16(a0, b0, acc[0][0], 0, 0, 0);
      acc[0][1] = __builtin_amdgcn_mfma_f32_16x16x32_bf16(a0, b1, acc[0][1], 0, 0, 0);
      acc[0][2] = __builtin_amdgcn_mfma_f32_16x16x32_bf16(a0, b2, acc[0][2], 0, 0, 0);
      acc[0][3] = __builtin_amdgcn_mfma_f32_16x16x32_bf16(a0, b3, acc[0][3], 0, 0, 0);
      acc[1][0] = __builtin_amdgcn_mfma_f32_16x16x32_bf16(a1, b0, acc[1][0], 0, 0, 0);
      acc[1][1] = __builtin_amdgcn_mfma_f32_16x16x32_bf16(a1, b1, acc[1][1], 0, 0, 0);
      acc[1][2] = __builtin_amdgcn_mfma_f32_16x16x32_bf16(a1, b2, acc[1][2], 0, 0, 0);
      acc[1][3] = __builtin_amdgcn_mfma_f32_16x16x32_bf16(a1, b3, acc[1][3], 0, 0, 0);
    }
    // d2a = cbn - 2*E  (C layout: col=lane&15 -> t, row=(lane>>4)*4+reg -> s)
#pragma unroll
    for (int ss = 0; ss < 2; ++ss)
#pragma unroll
      for (int ts = 0; ts < 4; ++ts)
#pragma unroll
        for (int r = 0; r < 4; ++r)
          acc[ss][ts][r] = fmaf(-2.f, acc[ss][ts][r],
                                Cna[c * 128 + wv * 32 + ss * 16 + lg * 4 + r]);
    float mts[4];
#pragma unroll
    for (int ts = 0; ts < 4; ++ts) {
      float m = acc[0][ts][0];
#pragma unroll
      for (int r = 1; r < 4; ++r) m = fminf(m, acc[0][ts][r]);
#pragma unroll
      for (int r = 0; r < 4; ++r) m = fminf(m, acc[1][ts][r]);
      m = fminf(m, __shfl_xor(m, 16));
      m = fminf(m, __shfl_xor(m, 32));
      mts[ts] = m;
    }
    if (lg == 0) {
#pragma unroll
      for (int ts = 0; ts < 4; ++ts) wmin[wv][ts * 16 + lr] = mts[ts];
    }
    __syncthreads();
    if (tid < 64) {
      float g = fminf(fminf(wmin[0][tid], wmin[1][tid]), fminf(wmin[2][tid], wmin[3][tid]));
      gmin[tid] = fminf(gmin[tid], g);
    }
  }
  __syncthreads();   // gmin final; read-only below

  // ======== PASS B: recompute, flag vs global min ========
  for (int c = 0; c < 8; ++c) {
    __syncthreads();
    for (int rep = 0; rep < 8; ++rep) {
      int idx = rep * 256 + tid;
      int s = idx >> 4, q = idx & 15;
      *reinterpret_cast<bf16x8*>(&cbL[s][q * 8]) =
          *reinterpret_cast<const bf16x8*>(cb16b + (size_t)(c * 128 + s) * 128 + q * 8);
    }
    __syncthreads();

    f32x4 acc[2][4];
#pragma unroll
    for (int ss = 0; ss < 2; ++ss)
#pragma unroll
      for (int ts = 0; ts < 4; ++ts) acc[ss][ts] = (f32x4){0.f, 0.f, 0.f, 0.f};
#pragma unroll
    for (int ks = 0; ks < 4; ++ks) {
      bf16x8 a0 = *reinterpret_cast<const bf16x8*>(&cbL[wv * 32 + lr][ks * 32 + lg * 8]);
      bf16x8 a1 = *reinterpret_cast<const bf16x8*>(&cbL[wv * 32 + 16 + lr][ks * 32 + lg * 8]);
      bf16x8 b0 = *reinterpret_cast<const bf16x8*>(&ZtT[lr][ks * 32 + lg * 8]);
      bf16x8 b1 = *reinterpret_cast<const bf16x8*>(&ZtT[16 + lr][ks * 32 + lg * 8]);
      bf16x8 b2 = *reinterpret_cast<const bf16x8*>(&ZtT[32 + lr][ks * 32 + lg * 8]);
      bf16x8 b3 = *reinterpret_cast<const bf16x8*>(&ZtT[48 + lr][ks * 32 + lg * 8]);
      acc[0][0] = __builtin_amdgcn_mfma_f32_16x16x32_bf16(a0, b0, acc[0][0], 0, 0, 0);
      acc[0][1] = __builtin_amdgcn_mfma_f32_16x16x32_bf16(a0, b1, acc[0][1], 0, 0, 0);
      acc[0][2] = __builtin_amdgcn_mfma_f32_16x16x32_bf16(a0, b2, acc[0][2], 0, 0, 0);
      acc[0][3] = __builtin_amdgcn_mfma_f32_16x16x32_bf16(a0, b3, acc[0][3], 0, 0, 0);
      acc[1][0] = __builtin_amdgcn_mfma_f32_16x16x32_bf16(a1, b0, acc[1][0], 0, 0, 0);
      acc[1][1] = __builtin_amdgcn_mfma_f32_16x16x32_bf16(a1, b1, acc[1][1], 0, 0, 0);
      acc[1][2] = __builtin_amdgcn_mfma_f32_16x16x32_bf16(a1, b2, acc[1][2], 0, 0, 0);
      acc[1][3] = __builtin_amdgcn_mfma_f32_16x16x32_bf16(a1, b3, acc[1][3], 0, 0, 0);
    }
#pragma unroll
    for (int ss = 0; ss < 2; ++ss)
#pragma unroll
      for (int ts = 0; ts < 4; ++ts)
#pragma unroll
        for (int r = 0; r < 4; ++r)
          acc[ss][ts][r] = fmaf(-2.f, acc[ss][ts][r],
                                Cna[c * 128 + wv * 32 + ss * 16 + lg * 4 + r]);
#pragma unroll
    for (int ts = 0; ts < 4; ++ts) {
      int t = ts * 16 + lr;
      float thr = gmin[t] + MARGIN;
#pragma unroll
      for (int ss = 0; ss < 2; ++ss)
#pragma unroll
        for (int r = 0; r < 4; ++r) {
          float v = acc[ss][ts][r];
          int s = c * 128 + wv * 32 + ss * 16 + lg * 4 + r;
          if (book == 0 && blockIdx.x == 0 && c == 0)
            dump[(size_t)(wv * 32 + ss * 16 + lg * 4 + r) * 64 + t] = v;
          if (v <= thr) {
            int pos = atomicAdd(&fcnt[t], 1);
            if (pos < FCAP) fls[t][pos] = (unsigned short)s;
          }
        }
    }
  }
  __syncthreads();
  if (tid < 64) fcg[tok0 + tid] = fcnt[tid];
  for (int idx = tid; idx < 64 * FCAP; idx += 256) {
    int t = idx / FCAP, i = idx - t * FCAP;
    fgl[(size_t)(tok0 + t) * FCAP + i] = fls[t][i];
  }
}

// ---------------------------------------------------------------------------
// Verify MFMA layout: dump tile vs fp64 recompute of bf16-dequantized inputs.
__global__ __launch_bounds__(256) void probe_kernel(const unsigned short* __restrict__ z16,
                                                    const unsigned short* __restrict__ cb16,
                                                    const float* __restrict__ cbn32,
                                                    const float* __restrict__ dump,
                                                    int* __restrict__ probe_ok) {
  __shared__ float red[256];
  const int tid = threadIdx.x;
  float mx = 0.f;
  for (int p = tid; p < 8192; p += 256) {
    int s = p >> 6, t = p & 63;
    double e = 0.0;
    for (int d = 0; d < 128; ++d)
      e += (double)bf2f(cb16[(size_t)s * 128 + d]) * (double)bf2f(z16[(size_t)d * NTOK + t]);
    float ref = fmaf(-2.f, (float)e, cbn32[s]);
    mx = fmaxf(mx, fabsf(ref - dump[p]));
  }
  red[tid] = mx;
  __syncthreads();
  for (int off = 128; off; off >>= 1) {
    if (tid < off) red[tid] = fmaxf(red[tid], red[tid + off]);
    __syncthreads();
  }
  if (tid == 0) *probe_ok = (red[0] < 1e-4f) ? 1 : 0;
}

// ---------------------------------------------------------------------------
// Exact (bitwise round-6) evaluation of flagged candidates; first-index ties.
__global__ __launch_bounds__(256) void refine_kernel(const float* __restrict__ z32,
                                                     const float* __restrict__ cbb,
                                                     const float* __restrict__ cbn32b,
                                                     const unsigned short* __restrict__ fgl,
                                                     const int* __restrict__ fcg,
                                                     const int* __restrict__ probe_ok,
                                                     int* __restrict__ codes,
                                                     double* __restrict__ lpartF,
                                                     int book) {
  if (!*probe_ok) return;
  __shared__ float Zl[128][64];
  __shared__ double znp[4][64];
  __shared__ float znl[64];
  __shared__ float bestv[4][64];
  __shared__ int   bests[4][64];
  __shared__ double lred[64];
  const int tid = threadIdx.x;
  const int tok0 = blockIdx.x * 64;
  const int b = tok0 >> 12;
  const int tl = tid & 63, h = tid >> 6;
  for (int rep = 0; rep < 8; ++rep) {
    int idx = rep * 256 + tid;
    int d = idx >> 4, q = idx & 15;
    float4 v = *reinterpret_cast<const float4*>(z32 + (size_t)d * NTOK + tok0 + q * 4);
    Zl[d][q * 4 + 0] = v.x; Zl[d][q * 4 + 1] = v.y;
    Zl[d][q * 4 + 2] = v.z; Zl[d][q * 4 + 3] = v.w;
  }
  __syncthreads();
  { // zn: bitwise-identical to round-6 path
    double s = 0.0;
#pragma unroll
    for (int dd = 0; dd < 32; ++dd) { double v = (double)Zl[h * 32 + dd][tl]; s += v * v; }
    znp[h][tl] = s;
  }
  __syncthreads();
  if (tid < 64) znl[tid] = (float)(((znp[0][tid] + znp[1][tid]) + znp[2][tid]) + znp[3][tid]);
  __syncthreads();
  const float zn = znl[tl];
  const int tok = tok0 + tl;
  const int cnt = fcg[tok];
  float bm = 3.4e38f; int bi = 0x7fffffff;
  if (cnt <= FCAP) {
    for (int i = h; i < cnt; i += 4) {
      int s = fgl[(size_t)tok * FCAP + i];
      const float* cr = cbb + (size_t)s * CD;
      double e = 0.0;
      for (int d = 0; d < CD; ++d) e = fma((double)cr[d], (double)Zl[d][tl], e);
      float M = (float)e;
      float d2 = __fadd_rn(__fsub_rn(zn, __fmul_rn(2.f, M)), cbn32b[s]);
      if (d2 < bm || (d2 == bm && s < bi)) { bm = d2; bi = s; }
    }
  } else {   // overflow: full exact scan (statistically never with exact-min flags)
    for (int s = h; s < S; s += 4) {
      const float* cr = cbb + (size_t)s * CD;
      double e = 0.0;
      for (int d = 0; d < CD; ++d) e = fma((double)cr[d], (double)Zl[d][tl], e);
      float M = (float)e;
      float d2 = __fadd_rn(__fsub_rn(zn, __fmul_rn(2.f, M)), cbn32b[s]);
      if (d2 < bm || (d2 == bm && s < bi)) { bm = d2; bi = s; }
    }
  }
  bestv[h][tl] = bm; bests[h][tl] = bi;
  __syncthreads();
  if (tid < 64) {
    float fv = bestv[0][tid]; int fs = bests[0][tid];
#pragma unroll
    for (int x = 1; x < 4; ++x) {
      float v = bestv[x][tid]; int s = bests[x][tid];
      if (v < fv || (v == fv && s < fs)) { fv = v; fs = s; }
    }
    codes[((size_t)b * NB + book) * T + (tok & (T - 1))] = fs;
    lred[tid] = (double)fv;
  }
  __syncthreads();
  if (tid == 0) {
    double sum = 0.0;
    for (int i = 0; i < 64; ++i) sum += lred[i];
    lpartF[(size_t)book * 1024 + blockIdx.x] = sum;
  }
}

// ---------------------------------------------------------------------------
// FALLBACK: round-6 proven score kernel, active only if probe failed.
__global__ __launch_bounds__(256) void score_fb_kernel(const float* __restrict__ z32,
                                                       const float* __restrict__ cb,
                                                       const float* __restrict__ cbn32b,
                                                       int* __restrict__ codes,
                                                       double* __restrict__ lpart,
                                                       const int* __restrict__ probe_ok,
                                                       int book) {
  if (*probe_ok) return;
  __shared__ __align__(16) float Zl[128][68];
  __shared__ __align__(16) float Al[32][132];
  __shared__ float Cn[128];
  __shared__ double znp[4][64];
  __shared__ float zn[64];
  __shared__ double lred[16];
  const int tid = threadIdx.x;
  const int t0 = blockIdx.x * 64;
  const int b  = blockIdx.y;
  const int mx = tid & 15, nx = tid >> 4;
  const size_t tokbase = (size_t)b * T + t0;
  float* Rm1 = &Al[0][0];
  int*   Ri  = reinterpret_cast<int*>(&Al[0][0]) + 1024;
#pragma unroll
  for (int rep = 0; rep < 8; ++rep) {
    int idx = rep * 256 + tid;
    int d = idx >> 4, q = idx & 15;
    float4 v = *reinterpret_cast<const float4*>(z32 + (size_t)d * NTOK + tokbase + q * 4);
    *reinterpret_cast<float4*>(&Zl[d][q * 4]) = v;
  }
  __syncthreads();
  {
    int tt = tid & 63, part = tid >> 6;
    double s = 0.0;
#pragma unroll
    for (int dd = 0; dd < 32; ++dd) { double v = (double)Zl[part * 32 + dd][tt]; s += v * v; }
    znp[part][tt] = s;
  }
  __syncthreads();
  if (tid < 64) zn[tid] = (float)(((znp[0][tid] + znp[1][tid]) + znp[2][tid]) + znp[3][tid]);
  const float INF = 3.4e38f;
  float gm1[4] = {INF, INF, INF, INF};
  int   gi1[4] = {0, 0, 0, 0};
  for (int c = 0; c < 8; ++c) {
    double acc[8][4] = {};
    for (int kc = 0; kc < 4; ++kc) {
      __syncthreads();
      if (kc == 0 && tid < 128) Cn[tid] = cbn32b[c * 128 + tid];
#pragma unroll
      for (int rep = 0; rep < 4; ++rep) {
        int idx = rep * 256 + tid;
        int r = idx >> 3, q = idx & 7;
        float4 v = reinterpret_cast<const float4*>(cb)[(size_t)(c * 128 + r) * 32 + kc * 8 + q];
        Al[q * 4 + 0][r] = v.x; Al[q * 4 + 1][r] = v.y;
        Al[q * 4 + 2][r] = v.z; Al[q * 4 + 3][r] = v.w;
      }
      __syncthreads();
#pragma unroll
      for (int kk = 0; kk < 32; ++kk) {
        float4 a0 = *reinterpret_cast<const float4*>(&Al[kk][mx * 8]);
        float4 a1 = *reinterpret_cast<const float4*>(&Al[kk][mx * 8 + 4]);
        float4 bv = *reinterpret_cast<const float4*>(&Zl[kc * 32 + kk][nx * 4]);
        double a[8] = {a0.x, a0.y, a0.z, a0.w, a1.x, a1.y, a1.z, a1.w};
        double bb[4] = {bv.x, bv.y, bv.z, bv.w};
#pragma unroll
        for (int u = 0; u < 8; ++u)
#pragma unroll
          for (int j = 0; j < 4; ++j) acc[u][j] = fma(a[u], bb[j], acc[u][j]);
      }
    }
    float tm1[4]; int ti1[4];
#pragma unroll
    for (int j = 0; j < 4; ++j) {
      float m1 = INF; int i1 = 0;
      float znj = zn[nx * 4 + j];
#pragma unroll
      for (int u = 0; u < 8; ++u) {
        float M  = (float)acc[u][j];
        float dv = __fsub_rn(znj, __fmul_rn(2.0f, M));
        float d2 = __fadd_rn(dv, Cn[mx * 8 + u]);
        if (d2 < m1) { m1 = d2; i1 = c * 128 + mx * 8 + u; }
      }
      tm1[j] = m1; ti1[j] = i1;
    }
    __syncthreads();
#pragma unroll
    for (int j = 0; j < 4; ++j) {
      int slot = j * 256 + nx * 16 + mx;
      Rm1[slot] = tm1[j]; Ri[slot] = ti1[j];
    }
    __syncthreads();
    if (mx == 0) {
#pragma unroll
      for (int j = 0; j < 4; ++j) {
        float m1 = INF; int i1 = 0;
        for (int x = 0; x < 16; ++x) {
          int slot = j * 256 + nx * 16 + x;
          float am = Rm1[slot];
          if (am < m1) { m1 = am; i1 = Ri[slot]; }
        }
        if (m1 < gm1[j]) { gm1[j] = m1; gi1[j] = i1; }
      }
    }
  }
  if (mx == 0) {
    double lp = 0.0;
#pragma unroll
    for (int j = 0; j < 4; ++j) {
      codes[((size_t)b * NB + book) * T + t0 + nx * 4 + j] = gi1[j];
      lp += (double)gm1[j];
    }
    lred[nx] = lp;
  }
  __syncthreads();
  if (tid == 0) {
    double s = 0.0;
#pragma unroll
    for (int i = 0; i < 16; ++i) s += lred[i];
    lpart[(size_t)book * 1024 + b * 64 + blockIdx.x] = s;
  }
}

// ---------------------------------------------------------------------------
__global__ __launch_bounds__(256) void qsum64_kernel(double* __restrict__ qs64,
                                                     const float* __restrict__ cb,
                                                     const int* __restrict__ codes,
                                                     int book) {
  int tok = blockIdx.x * 256 + threadIdx.x;
  int b = tok >> 12, t = tok & (T - 1);
  int code = codes[((size_t)b * NB + book) * T + t];
  const float* row = cb + (size_t)code * CD;
  for (int k = 0; k < CD; ++k)
    qs64[(size_t)k * NTOK + tok] += (double)row[k];
}

// ---------------------------------------------------------------------------
__global__ __launch_bounds__(256) void final64_kernel(const double* __restrict__ qs64,
                                                      const float* __restrict__ Wout,
                                                      const float* __restrict__ bout,
                                                      float* __restrict__ out) {
  __shared__ __align__(16) float Al[32][132];
  __shared__ double Bl64[32][65];
  const int tid = threadIdx.x;
  const int t0 = blockIdx.x * 64;
  const int Dg = blockIdx.y;
  const int b  = blockIdx.z;
  const int mx = tid & 15, nx = tid >> 4;
  const size_t tokbase = (size_t)b * T + t0;
  double acc[8][4] = {};
  for (int kc = 0; kc < 4; ++kc) {
    __syncthreads();
#pragma unroll
    for (int rep = 0; rep < 4; ++rep) {
      int idx = rep * 256 + tid;
      int r = idx >> 3, q = idx & 7;
      float4 v = reinterpret_cast<const float4*>(Wout)[(size_t)(Dg * 128 + r) * 32 + kc * 8 + q];
      Al[q * 4 + 0][r] = v.x; Al[q * 4 + 1][r] = v.y;
      Al[q * 4 + 2][r] = v.z; Al[q * 4 + 3][r] = v.w;
    }
#pragma unroll
    for (int rep = 0; rep < 8; ++rep) {
      int idx = rep * 256 + tid;
      int kk = idx >> 6, tt = idx & 63;
      Bl64[kk][tt] = qs64[(size_t)(kc * 32 + kk) * NTOK + tokbase + tt];
    }
    __syncthreads();
#pragma unroll
    for (int kk = 0; kk < 32; ++kk) {
      double a[8];
#pragma unroll
      for (int u = 0; u < 8; ++u) a[u] = (double)Al[kk][mx * 8 + u];
#pragma unroll
      for (int j = 0; j < 4; ++j) {
        double bb = Bl64[kk][nx * 4 + j];
#pragma unroll
        for (int u = 0; u < 8; ++u) acc[u][j] = fma(a[u], bb, acc[u][j]);
      }
    }
  }
#pragma unroll
  for (int u = 0; u < 8; ++u) {
    int D = Dg * 128 + mx * 8 + u;
    double bo = 8.0 * (double)bout[D];
    float4 o = make_float4((float)(acc[u][0] + bo), (float)(acc[u][1] + bo),
                           (float)(acc[u][2] + bo), (float)(acc[u][3] + bo));
    reinterpret_cast<float4*>(out + ((size_t)b * DIN + D) * T + t0)[nx] = o;
  }
}

// ---------------------------------------------------------------------------
__global__ __launch_bounds__(256) void codes_out_kernel(const int* __restrict__ codes,
                                                        float* __restrict__ out) {
  int k = blockIdx.x * 256 + threadIdx.x;
  if (k < BATCH * NB * T)
    out[(size_t)BATCH * DIN * T + k] = (float)codes[k];
}

__global__ __launch_bounds__(256) void loss_out_kernel(const double* __restrict__ lpF,
                                                       const double* __restrict__ lpS,
                                                       const int* __restrict__ probe_ok,
                                                       float* __restrict__ out) {
  __shared__ double red[256];
  const double* lp = (*probe_ok) ? lpF : lpS;
  double s = 0.0;
  for (int i = threadIdx.x; i < NB * 1024; i += 256) s += lp[i];
  red[threadIdx.x] = s;
  __syncthreads();
  for (int off = 128; off; off >>= 1) {
    if (threadIdx.x < off) red[threadIdx.x] += red[threadIdx.x + off];
    __syncthreads();
  }
  if (threadIdx.x == 0)
    out[(size_t)BATCH * DIN * T + (size_t)BATCH * NB * T] =
        (float)(red[0] * 1.25 / 8388608.0);
}

// ---------------------------------------------------------------------------
extern "C" void kernel_launch(void* const* d_in, const int* in_sizes, int n_in,
                              void* d_out, int out_size, void* d_ws, size_t ws_size,
                              hipStream_t stream) {
  (void)in_sizes; (void)n_in; (void)out_size; (void)ws_size;
  const float* z    = (const float*)d_in[0];
  const float* Win  = (const float*)d_in[1];
  const float* bin  = (const float*)d_in[2];
  const float* Wout = (const float*)d_in[3];
  const float* bout = (const float*)d_in[4];
  const float* cbs  = (const float*)d_in[5];
  float* out = (float*)d_out;
  double* A64 = (double*)d_out;   // aliases z_q region; overwritten by final64

  char* w = (char*)d_ws;
  double* qs64  = (double*)w;  w += (size_t)CD * NTOK * 8;        // 67.1 MB
  double* P64t  = (double*)w;  w += (size_t)CD * CD * 8;
  double* cvec64= (double*)w;  w += CD * 8;
  double* lpartF= (double*)w;  w += (size_t)NB * 1024 * 8;
  double* lpartS= (double*)w;  w += (size_t)NB * 1024 * 8;
  float*  z32   = (float*)w;   w += (size_t)CD * NTOK * 4;        // 33.6 MB
  float*  cbn32 = (float*)w;   w += (size_t)NB * S * 4;
  float*  dump  = (float*)w;   w += 8192 * 4;
  unsigned short* z16  = (unsigned short*)w; w += (size_t)CD * NTOK * 2;   // 16.8 MB
  unsigned short* cb16 = (unsigned short*)w; w += (size_t)NB * S * CD * 2; // 2.1 MB
  unsigned short* fgl  = (unsigned short*)w; w += (size_t)NTOK * FCAP * 2; // 3.1 MB
  int*    fcg   = (int*)w;     w += (size_t)NTOK * 4;
  int*    codes = (int*)w;     w += (size_t)BATCH * NB * T * 4;
  int*    probe_ok = (int*)w;  w += 256;

  cbn32_kernel<<<(NB * S + 255) / 256, 256, 0, stream>>>(cbs, cbn32);
  cb16_kernel<<<(NB * S * CD + 255) / 256, 256, 0, stream>>>(cbs, cb16);
  p64t_kernel<<<64, 256, 0, stream>>>(Win, Wout, P64t);
  cvec64_kernel<<<1, 128, 0, stream>>>(Win, bout, cvec64);
  a64_kernel<<<dim3(T / 64, BATCH), 256, 0, stream>>>(z, Win, bin, A64);
  hipMemsetAsync(qs64, 0, (size_t)CD * NTOK * 8, stream);

  for (int book = 0; book < NB; ++book) {
    const float* cb = cbs + (size_t)book * S * CD;
    const unsigned short* cbh = cb16 + (size_t)book * S * CD;
    zproj32_kernel<<<NTOK / 64, 256, 0, stream>>>(A64, qs64, P64t, cvec64, z32, z16, book);
    score_mfma_kernel<<<NTOK / 64, 256, 0, stream>>>(z16, cbh, cbn32 + book * S,
                                                     fgl, fcg, dump, book);
    if (book == 0)
      probe_kernel<<<1, 256, 0, stream>>>(z16, cb16, cbn32, dump, probe_ok);
    refine_kernel<<<NTOK / 64, 256, 0, stream>>>(z32, cb, cbn32 + book * S,
                                                 fgl, fcg, probe_ok, codes, lpartF, book);
    score_fb_kernel<<<dim3(T / 64, BATCH), 256, 0, stream>>>(z32, cb, cbn32 + book * S,
                                                             codes, lpartS, probe_ok, book);
    qsum64_kernel<<<NTOK / 256, 256, 0, stream>>>(qs64, cb, codes, book);
  }
  final64_kernel<<<dim3(T / 64, DIN / 128, BATCH), 256, 0, stream>>>(qs64, Wout, bout, out);
  codes_out_kernel<<<(BATCH * NB * T + 255) / 256, 256, 0, stream>>>(codes, out);
  loss_out_kernel<<<1, 256, 0, stream>>>(lpartF, lpartS, probe_ok, out);
}

// Round 9
// 2286.678 us; speedup vs baseline: 4.5205x; 1.2675x over previous
//
#include <hip/hip_runtime.h>
#include <cstdint>

constexpr int NB   = 8;
constexpr int S    = 1024;
constexpr int CD   = 128;
constexpr int DIN  = 512;
constexpr int BATCH= 16;
constexpr int T    = 4096;
constexpr int NTOK = BATCH * T;        // 65536
constexpr int FCAP = 24;
constexpr float MARGIN = 4e-3f;        // > 2 * 1.3e-3 worst-case bf16 approx error

typedef __attribute__((ext_vector_type(8))) short bf16x8;
typedef __attribute__((ext_vector_type(4))) float f32x4;

__device__ __forceinline__ unsigned short f2bf(float f) {
  unsigned int u = __float_as_uint(f);
  return (unsigned short)((u + 0x7fffu + ((u >> 16) & 1u)) >> 16);
}
__device__ __forceinline__ float bf2f(unsigned short h) {
  return __uint_as_float((unsigned int)h << 16);
}

// ---------------------------------------------------------------------------
__global__ __launch_bounds__(256) void cbn32_kernel(const float* __restrict__ cbs,
                                                    float* __restrict__ cbn32) {
  int row = blockIdx.x * 256 + threadIdx.x;
  if (row >= NB * S) return;
  const float4* r4 = reinterpret_cast<const float4*>(cbs + (size_t)row * CD);
  double s = 0.0;
  for (int q = 0; q < 32; ++q) {
    float4 v = r4[q];
    s += (double)v.x * v.x + (double)v.y * v.y + (double)v.z * v.z + (double)v.w * v.w;
  }
  cbn32[row] = (float)s;
}

__global__ __launch_bounds__(256) void cb16_kernel(const float* __restrict__ cbs,
                                                   unsigned short* __restrict__ cb16) {
  int i = blockIdx.x * 256 + threadIdx.x;
  if (i < NB * S * CD) cb16[i] = f2bf(cbs[i]);
}

__global__ __launch_bounds__(256) void p64t_kernel(const float* __restrict__ Win,
                                                   const float* __restrict__ Wout,
                                                   double* __restrict__ P64t) {
  int n = blockIdx.x * 256 + threadIdx.x;   // 16384
  int k = n >> 7, d = n & 127;
  double s = 0.0;
  for (int D = 0; D < DIN; ++D)
    s = fma((double)Win[(size_t)d * DIN + D], (double)Wout[(size_t)D * CD + k], s);
  P64t[(size_t)k * CD + d] = s;
}

__global__ void cvec64_kernel(const float* __restrict__ Win,
                              const float* __restrict__ bout,
                              double* __restrict__ cvec64) {
  int d = threadIdx.x;  // 128
  double s = 0.0;
  for (int D = 0; D < DIN; ++D)
    s = fma((double)Win[(size_t)d * DIN + D], (double)bout[D], s);
  cvec64[d] = s;
}

// ---------------------------------------------------------------------------
// A64[b][d][t] = fp64( sum_D Win[d,D]*z[b,D,t] + bin[d] )
__global__ __launch_bounds__(256) void a64_kernel(const float* __restrict__ z,
                                                  const float* __restrict__ Win,
                                                  const float* __restrict__ bin,
                                                  double* __restrict__ A64) {
  __shared__ __align__(16) float Al[32][132];
  __shared__ __align__(16) float Bl[32][68];
  const int tid = threadIdx.x;
  const int t0 = blockIdx.x * 64;
  const int b  = blockIdx.y;
  const int mx = tid & 15, nx = tid >> 4;
  double acc[8][4] = {};
  for (int kc = 0; kc < 16; ++kc) {
    __syncthreads();
#pragma unroll
    for (int rep = 0; rep < 4; ++rep) {
      int idx = rep * 256 + tid;
      int r = idx >> 3, q = idx & 7;
      float4 v = reinterpret_cast<const float4*>(Win)[(size_t)r * 128 + kc * 8 + q];
      Al[q * 4 + 0][r] = v.x; Al[q * 4 + 1][r] = v.y;
      Al[q * 4 + 2][r] = v.z; Al[q * 4 + 3][r] = v.w;
    }
#pragma unroll
    for (int rep = 0; rep < 2; ++rep) {
      int idx = rep * 256 + tid;
      int kk = idx >> 4, q = idx & 15;
      float4 v = reinterpret_cast<const float4*>(z + ((size_t)(b * DIN + kc * 32 + kk)) * T + t0)[q];
      *reinterpret_cast<float4*>(&Bl[kk][q * 4]) = v;
    }
    __syncthreads();
#pragma unroll
    for (int kk = 0; kk < 32; ++kk) {
      float4 a0 = *reinterpret_cast<const float4*>(&Al[kk][mx * 8]);
      float4 a1 = *reinterpret_cast<const float4*>(&Al[kk][mx * 8 + 4]);
      float4 bv = *reinterpret_cast<const float4*>(&Bl[kk][nx * 4]);
      double a[8] = {a0.x, a0.y, a0.z, a0.w, a1.x, a1.y, a1.z, a1.w};
      double bb[4] = {bv.x, bv.y, bv.z, bv.w};
#pragma unroll
      for (int u = 0; u < 8; ++u)
#pragma unroll
        for (int j = 0; j < 4; ++j) acc[u][j] = fma(a[u], bb[j], acc[u][j]);
    }
  }
#pragma unroll
  for (int u = 0; u < 8; ++u) {
    int d = mx * 8 + u;
    double bi = (double)bin[d];
    double* Ap = A64 + ((size_t)(b * CD + d)) * T + t0 + nx * 4;
#pragma unroll
    for (int j = 0; j < 4; ++j) Ap[j] = acc[u][j] + bi;
  }
}

// ---------------------------------------------------------------------------
// z32 = fl32(A64 - P*qs64 - book*cvec) ; z16 = bf16(z32)
__global__ __launch_bounds__(256) void zproj32_kernel(const double* __restrict__ A64,
                                                      const double* __restrict__ qs64,
                                                      const double* __restrict__ P64t,
                                                      const double* __restrict__ cvec64,
                                                      float* __restrict__ z32,
                                                      unsigned short* __restrict__ z16,
                                                      int book) {
  __shared__ double Q[16][64];
  const int tid = threadIdx.x;
  const int tok0 = blockIdx.x * 64;
  const int b = tok0 >> 12, tloc = tok0 & (T - 1);
  const int d = tid & 127, h = tid >> 7;
  double acc[32];
  const double* Ap = A64 + ((size_t)(b * CD + d)) * T + tloc + h * 32;
#pragma unroll
  for (int j = 0; j < 32; ++j) acc[j] = Ap[j];
  if (book > 0) {
    for (int kc = 0; kc < 8; ++kc) {
      __syncthreads();
#pragma unroll
      for (int rep = 0; rep < 4; ++rep) {
        int idx = rep * 256 + tid;
        int kkk = idx >> 6, tt = idx & 63;
        Q[kkk][tt] = qs64[(size_t)(kc * 16 + kkk) * NTOK + tok0 + tt];
      }
      __syncthreads();
#pragma unroll
      for (int kk = 0; kk < 16; ++kk) {
        double p = P64t[(size_t)(kc * 16 + kk) * CD + d];
#pragma unroll
        for (int j = 0; j < 32; ++j) acc[j] = fma(-p, Q[kk][h * 32 + j], acc[j]);
      }
    }
    double cv = (double)book * cvec64[d];
#pragma unroll
    for (int j = 0; j < 32; ++j) acc[j] -= cv;
  }
  float* zp = z32 + (size_t)d * NTOK + tok0 + h * 32;
  unsigned short* hp = z16 + (size_t)d * NTOK + tok0 + h * 32;
#pragma unroll
  for (int j = 0; j < 32; ++j) {
    float f = (float)acc[j];
    zp[j] = f;
    hp[j] = f2bf(f);
  }
}

// ---------------------------------------------------------------------------
// bf16 MFMA approx scores, TWO-PASS:
//   pass A: per-token global min over all 1024 codes (no flags)
//   pass B: recompute (bitwise-identical MFMA) and flag d2a <= gmin + MARGIN
__global__ __launch_bounds__(256) void score_mfma_kernel(
    const unsigned short* __restrict__ z16,
    const unsigned short* __restrict__ cb16b,
    const float* __restrict__ cbn32b,
    unsigned short* __restrict__ fgl,
    int* __restrict__ fcg,
    float* __restrict__ dump,
    int book) {
  __shared__ unsigned short cbL[128][136];
  __shared__ unsigned short ZtT[64][136];
  __shared__ float Cna[1024];
  __shared__ float gmin[64];
  __shared__ float wmin[4][64];
  __shared__ int   fcnt[64];
  __shared__ unsigned short fls[64][FCAP];
  const int tid = threadIdx.x;
  const int tok0 = blockIdx.x * 64;
  const int wv = tid >> 6, ln = tid & 63;
  const int lr = ln & 15, lg = ln >> 4;

  for (int rep = 0; rep < 4; ++rep) {           // z16 [k][tok] -> LDS [t][k]
    int idx = rep * 256 + tid;
    int k = idx >> 3, tg = idx & 7;
    bf16x8 v = *reinterpret_cast<const bf16x8*>(z16 + (size_t)k * NTOK + tok0 + tg * 8);
#pragma unroll
    for (int e = 0; e < 8; ++e) ZtT[tg * 8 + e][k] = (unsigned short)v[e];
  }
#pragma unroll
  for (int rep = 0; rep < 4; ++rep) Cna[rep * 256 + tid] = cbn32b[rep * 256 + tid];
  if (tid < 64) { gmin[tid] = 3.4e38f; fcnt[tid] = 0; }

  // ======== PASS A: exact global min of d2a ========
  for (int c = 0; c < 8; ++c) {
    __syncthreads();
    for (int rep = 0; rep < 8; ++rep) {
      int idx = rep * 256 + tid;
      int s = idx >> 4, q = idx & 15;
      *reinterpret_cast<bf16x8*>(&cbL[s][q * 8]) =
          *reinterpret_cast<const bf16x8*>(cb16b + (size_t)(c * 128 + s) * 128 + q * 8);
    }
    __syncthreads();

    f32x4 acc[2][4];
#pragma unroll
    for (int ss = 0; ss < 2; ++ss)
#pragma unroll
      for (int ts = 0; ts < 4; ++ts) acc[ss][ts] = (f32x4){0.f, 0.f, 0.f, 0.f};
#pragma unroll
    for (int ks = 0; ks < 4; ++ks) {
      bf16x8 a0 = *reinterpret_cast<const bf16x8*>(&cbL[wv * 32 + lr][ks * 32 + lg * 8]);
      bf16x8 a1 = *reinterpret_cast<const bf16x8*>(&cbL[wv * 32 + 16 + lr][ks * 32 + lg * 8]);
      bf16x8 b0 = *reinterpret_cast<const bf16x8*>(&ZtT[lr][ks * 32 + lg * 8]);
      bf16x8 b1 = *reinterpret_cast<const bf16x8*>(&ZtT[16 + lr][ks * 32 + lg * 8]);
      bf16x8 b2 = *reinterpret_cast<const bf16x8*>(&ZtT[32 + lr][ks * 32 + lg * 8]);
      bf16x8 b3 = *reinterpret_cast<const bf16x8*>(&ZtT[48 + lr][ks * 32 + lg * 8]);
      acc[0][0] = __builtin_amdgcn_mfma_f32_16x16x32_bf16(a0, b0, acc[0][0], 0, 0, 0);
      acc[0][1] = __builtin_amdgcn_mfma_f32_16x16x32_bf16(a0, b1, acc[0][1], 0, 0, 0);
      acc[0][2] = __builtin_amdgcn_mfma_f32_16x16x32_bf16(a0, b2, acc[0][2], 0, 0, 0);
      acc[0][3] = __builtin_amdgcn_mfma_f32_16x16x32_bf16(a0, b3, acc[0][3], 0, 0, 0);
      acc[1][0] = __builtin_amdgcn_mfma_f32_16x16x32_bf16(a1, b0, acc[1][0], 0, 0, 0);
      acc[1][1] = __builtin_amdgcn_mfma_f32_16x16x32_bf16(a1, b1, acc[1][1], 0, 0, 0);
      acc[1][2] = __builtin_amdgcn_mfma_f32_16x16x32_bf16(a1, b2, acc[1][2], 0, 0, 0);
      acc[1][3] = __builtin_amdgcn_mfma_f32_16x16x32_bf16(a1, b3, acc[1][3], 0, 0, 0);
    }
    // d2a = cbn - 2*E  (C layout: col=lane&15 -> t, row=(lane>>4)*4+reg -> s)
#pragma unroll
    for (int ss = 0; ss < 2; ++ss)
#pragma unroll
      for (int ts = 0; ts < 4; ++ts)
#pragma unroll
        for (int r = 0; r < 4; ++r)
          acc[ss][ts][r] = fmaf(-2.f, acc[ss][ts][r],
                                Cna[c * 128 + wv * 32 + ss * 16 + lg * 4 + r]);
    float mts[4];
#pragma unroll
    for (int ts = 0; ts < 4; ++ts) {
      float m = acc[0][ts][0];
#pragma unroll
      for (int r = 1; r < 4; ++r) m = fminf(m, acc[0][ts][r]);
#pragma unroll
      for (int r = 0; r < 4; ++r) m = fminf(m, acc[1][ts][r]);
      m = fminf(m, __shfl_xor(m, 16));
      m = fminf(m, __shfl_xor(m, 32));
      mts[ts] = m;
    }
    if (lg == 0) {
#pragma unroll
      for (int ts = 0; ts < 4; ++ts) wmin[wv][ts * 16 + lr] = mts[ts];
    }
    __syncthreads();
    if (tid < 64) {
      float g = fminf(fminf(wmin[0][tid], wmin[1][tid]), fminf(wmin[2][tid], wmin[3][tid]));
      gmin[tid] = fminf(gmin[tid], g);
    }
  }
  __syncthreads();   // gmin final; read-only below

  // ======== PASS B: recompute, flag vs global min ========
  for (int c = 0; c < 8; ++c) {
    __syncthreads();
    for (int rep = 0; rep < 8; ++rep) {
      int idx = rep * 256 + tid;
      int s = idx >> 4, q = idx & 15;
      *reinterpret_cast<bf16x8*>(&cbL[s][q * 8]) =
          *reinterpret_cast<const bf16x8*>(cb16b + (size_t)(c * 128 + s) * 128 + q * 8);
    }
    __syncthreads();

    f32x4 acc[2][4];
#pragma unroll
    for (int ss = 0; ss < 2; ++ss)
#pragma unroll
      for (int ts = 0; ts < 4; ++ts) acc[ss][ts] = (f32x4){0.f, 0.f, 0.f, 0.f};
#pragma unroll
    for (int ks = 0; ks < 4; ++ks) {
      bf16x8 a0 = *reinterpret_cast<const bf16x8*>(&cbL[wv * 32 + lr][ks * 32 + lg * 8]);
      bf16x8 a1 = *reinterpret_cast<const bf16x8*>(&cbL[wv * 32 + 16 + lr][ks * 32 + lg * 8]);
      bf16x8 b0 = *reinterpret_cast<const bf16x8*>(&ZtT[lr][ks * 32 + lg * 8]);
      bf16x8 b1 = *reinterpret_cast<const bf16x8*>(&ZtT[16 + lr][ks * 32 + lg * 8]);
      bf16x8 b2 = *reinterpret_cast<const bf16x8*>(&ZtT[32 + lr][ks * 32 + lg * 8]);
      bf16x8 b3 = *reinterpret_cast<const bf16x8*>(&ZtT[48 + lr][ks * 32 + lg * 8]);
      acc[0][0] = __builtin_amdgcn_mfma_f32_16x16x32_bf16(a0, b0, acc[0][0], 0, 0, 0);
      acc[0][1] = __builtin_amdgcn_mfma_f32_16x16x32_bf16(a0, b1, acc[0][1], 0, 0, 0);
      acc[0][2] = __builtin_amdgcn_mfma_f32_16x16x32_bf16(a0, b2, acc[0][2], 0, 0, 0);
      acc[0][3] = __builtin_amdgcn_mfma_f32_16x16x32_bf16(a0, b3, acc[0][3], 0, 0, 0);
      acc[1][0] = __builtin_amdgcn_mfma_f32_16x16x32_bf16(a1, b0, acc[1][0], 0, 0, 0);
      acc[1][1] = __builtin_amdgcn_mfma_f32_16x16x32_bf16(a1, b1, acc[1][1], 0, 0, 0);
      acc[1][2] = __builtin_amdgcn_mfma_f32_16x16x32_bf16(a1, b2, acc[1][2], 0, 0, 0);
      acc[1][3] = __builtin_amdgcn_mfma_f32_16x16x32_bf16(a1, b3, acc[1][3], 0, 0, 0);
    }
#pragma unroll
    for (int ss = 0; ss < 2; ++ss)
#pragma unroll
      for (int ts = 0; ts < 4; ++ts)
#pragma unroll
        for (int r = 0; r < 4; ++r)
          acc[ss][ts][r] = fmaf(-2.f, acc[ss][ts][r],
                                Cna[c * 128 + wv * 32 + ss * 16 + lg * 4 + r]);
#pragma unroll
    for (int ts = 0; ts < 4; ++ts) {
      int t = ts * 16 + lr;
      float thr = gmin[t] + MARGIN;
#pragma unroll
      for (int ss = 0; ss < 2; ++ss)
#pragma unroll
        for (int r = 0; r < 4; ++r) {
          float v = acc[ss][ts][r];
          int s = c * 128 + wv * 32 + ss * 16 + lg * 4 + r;
          if (book == 0 && blockIdx.x == 0 && c == 0)
            dump[(size_t)(wv * 32 + ss * 16 + lg * 4 + r) * 64 + t] = v;
          if (v <= thr) {
            int pos = atomicAdd(&fcnt[t], 1);
            if (pos < FCAP) fls[t][pos] = (unsigned short)s;
          }
        }
    }
  }
  __syncthreads();
  if (tid < 64) fcg[tok0 + tid] = fcnt[tid];
  for (int idx = tid; idx < 64 * FCAP; idx += 256) {
    int t = idx / FCAP, i = idx - t * FCAP;
    fgl[(size_t)(tok0 + t) * FCAP + i] = fls[t][i];
  }
}

// ---------------------------------------------------------------------------
// Verify MFMA layout: dump tile vs fp64 recompute of bf16-dequantized inputs.
__global__ __launch_bounds__(256) void probe_kernel(const unsigned short* __restrict__ z16,
                                                    const unsigned short* __restrict__ cb16,
                                                    const float* __restrict__ cbn32,
                                                    const float* __restrict__ dump,
                                                    int* __restrict__ probe_ok) {
  __shared__ float red[256];
  const int tid = threadIdx.x;
  float mx = 0.f;
  for (int p = tid; p < 8192; p += 256) {
    int s = p >> 6, t = p & 63;
    double e = 0.0;
    for (int d = 0; d < 128; ++d)
      e += (double)bf2f(cb16[(size_t)s * 128 + d]) * (double)bf2f(z16[(size_t)d * NTOK + t]);
    float ref = fmaf(-2.f, (float)e, cbn32[s]);
    mx = fmaxf(mx, fabsf(ref - dump[p]));
  }
  red[tid] = mx;
  __syncthreads();
  for (int off = 128; off; off >>= 1) {
    if (tid < off) red[tid] = fmaxf(red[tid], red[tid + off]);
    __syncthreads();
  }
  if (tid == 0) *probe_ok = (red[0] < 1e-4f) ? 1 : 0;
}

// ---------------------------------------------------------------------------
// Exact (bitwise round-6) evaluation of flagged candidates; first-index ties.
// Overflow tokens (cnt > FCAP) are handled BLOCK-COOPERATIVELY: all 256
// threads scan the 1024 codes (4 interleaved, internally-sequential fp64
// chains per thread) + (value,index) tree reduce — bitwise-same result as
// the serial scan, ~100x faster.
__global__ __launch_bounds__(256) void refine_kernel(const float* __restrict__ z32,
                                                     const float* __restrict__ cbb,
                                                     const float* __restrict__ cbn32b,
                                                     const unsigned short* __restrict__ fgl,
                                                     const int* __restrict__ fcg,
                                                     const int* __restrict__ probe_ok,
                                                     int* __restrict__ codes,
                                                     double* __restrict__ lpartF,
                                                     int book) {
  if (!*probe_ok) return;
  __shared__ float Zl[128][64];
  __shared__ double znp[4][64];
  __shared__ float znl[64];
  __shared__ float bestv[4][64];
  __shared__ int   bests[4][64];
  __shared__ double lred[64];
  __shared__ float rm[256];
  __shared__ int   ri[256];
  __shared__ int   ovl[64];
  __shared__ int   ovn;
  __shared__ unsigned char ovf[64];
  const int tid = threadIdx.x;
  const int tok0 = blockIdx.x * 64;
  const int b = tok0 >> 12;
  const int tl = tid & 63, h = tid >> 6;
  if (tid == 0) ovn = 0;
  for (int rep = 0; rep < 8; ++rep) {
    int idx = rep * 256 + tid;
    int d = idx >> 4, q = idx & 15;
    float4 v = *reinterpret_cast<const float4*>(z32 + (size_t)d * NTOK + tok0 + q * 4);
    Zl[d][q * 4 + 0] = v.x; Zl[d][q * 4 + 1] = v.y;
    Zl[d][q * 4 + 2] = v.z; Zl[d][q * 4 + 3] = v.w;
  }
  __syncthreads();
  { // zn: bitwise-identical to round-6 path
    double s = 0.0;
#pragma unroll
    for (int dd = 0; dd < 32; ++dd) { double v = (double)Zl[h * 32 + dd][tl]; s += v * v; }
    znp[h][tl] = s;
  }
  __syncthreads();
  if (tid < 64) znl[tid] = (float)(((znp[0][tid] + znp[1][tid]) + znp[2][tid]) + znp[3][tid]);
  __syncthreads();
  const float zn = znl[tl];
  const int tok = tok0 + tl;
  const int cnt = fcg[tok];
  float bm = 3.4e38f; int bi = 0x7fffffff;
  if (cnt <= FCAP) {
    if (h == 0) ovf[tl] = 0;
    for (int i = h; i < cnt; i += 4) {
      int s = fgl[(size_t)tok * FCAP + i];
      const float* cr = cbb + (size_t)s * CD;
      double e = 0.0;
      for (int d = 0; d < CD; ++d) e = fma((double)cr[d], (double)Zl[d][tl], e);
      float M = (float)e;
      float d2 = __fadd_rn(__fsub_rn(zn, __fmul_rn(2.f, M)), cbn32b[s]);
      if (d2 < bm || (d2 == bm && s < bi)) { bm = d2; bi = s; }
    }
  } else {
    if (h == 0) { int p = atomicAdd(&ovn, 1); ovl[p] = tl; ovf[tl] = 1; }
  }
  bestv[h][tl] = bm; bests[h][tl] = bi;
  __syncthreads();
  if (tid < 64 && !ovf[tid]) {
    float fv = bestv[0][tid]; int fs = bests[0][tid];
#pragma unroll
    for (int x = 1; x < 4; ++x) {
      float v = bestv[x][tid]; int s = bests[x][tid];
      if (v < fv || (v == fv && s < fs)) { fv = v; fs = s; }
    }
    codes[((size_t)b * NB + book) * T + ((tok0 + tid) & (T - 1))] = fs;
    lred[tid] = (double)fv;
  }
  __syncthreads();
  const int no = ovn;
  for (int e = 0; e < no; ++e) {
    const int tt = ovl[e];
    const float zn2 = znl[tt];
    // 4 interleaved dots; each chain internally sequential ascending d
    double e0 = 0.0, e1 = 0.0, e2 = 0.0, e3 = 0.0;
    const float* c0 = cbb + (size_t)(tid      ) * CD;
    const float* c1 = cbb + (size_t)(tid + 256) * CD;
    const float* c2 = cbb + (size_t)(tid + 512) * CD;
    const float* c3 = cbb + (size_t)(tid + 768) * CD;
    for (int d = 0; d < CD; ++d) {
      double zv = (double)Zl[d][tt];
      e0 = fma((double)c0[d], zv, e0);
      e1 = fma((double)c1[d], zv, e1);
      e2 = fma((double)c2[d], zv, e2);
      e3 = fma((double)c3[d], zv, e3);
    }
    float bm2 = 3.4e38f; int bi2 = 0x7fffffff;
    {
      float d2;
      d2 = __fadd_rn(__fsub_rn(zn2, __fmul_rn(2.f, (float)e0)), cbn32b[tid]);
      if (d2 < bm2) { bm2 = d2; bi2 = tid; }
      d2 = __fadd_rn(__fsub_rn(zn2, __fmul_rn(2.f, (float)e1)), cbn32b[tid + 256]);
      if (d2 < bm2) { bm2 = d2; bi2 = tid + 256; }
      d2 = __fadd_rn(__fsub_rn(zn2, __fmul_rn(2.f, (float)e2)), cbn32b[tid + 512]);
      if (d2 < bm2) { bm2 = d2; bi2 = tid + 512; }
      d2 = __fadd_rn(__fsub_rn(zn2, __fmul_rn(2.f, (float)e3)), cbn32b[tid + 768]);
      if (d2 < bm2) { bm2 = d2; bi2 = tid + 768; }
    }
    rm[tid] = bm2; ri[tid] = bi2;
    __syncthreads();
    for (int off = 128; off; off >>= 1) {
      if (tid < off) {
        float om = rm[tid + off]; int oi = ri[tid + off];
        if (om < rm[tid] || (om == rm[tid] && oi < ri[tid])) { rm[tid] = om; ri[tid] = oi; }
      }
      __syncthreads();
    }
    if (tid == 0) {
      codes[((size_t)b * NB + book) * T + ((tok0 + tt) & (T - 1))] = ri[0];
      lred[tt] = (double)rm[0];
    }
    __syncthreads();
  }
  if (tid == 0) {
    double sum = 0.0;
    for (int i = 0; i < 64; ++i) sum += lred[i];
    lpartF[(size_t)book * 1024 + blockIdx.x] = sum;
  }
}

// ---------------------------------------------------------------------------
// FALLBACK: round-6 proven score kernel, active only if probe failed.
__global__ __launch_bounds__(256) void score_fb_kernel(const float* __restrict__ z32,
                                                       const float* __restrict__ cb,
                                                       const float* __restrict__ cbn32b,
                                                       int* __restrict__ codes,
                                                       double* __restrict__ lpart,
                                                       const int* __restrict__ probe_ok,
                                                       int book) {
  if (*probe_ok) return;
  __shared__ __align__(16) float Zl[128][68];
  __shared__ __align__(16) float Al[32][132];
  __shared__ float Cn[128];
  __shared__ double znp[4][64];
  __shared__ float zn[64];
  __shared__ double lred[16];
  const int tid = threadIdx.x;
  const int t0 = blockIdx.x * 64;
  const int b  = blockIdx.y;
  const int mx = tid & 15, nx = tid >> 4;
  const size_t tokbase = (size_t)b * T + t0;
  float* Rm1 = &Al[0][0];
  int*   Ri  = reinterpret_cast<int*>(&Al[0][0]) + 1024;
#pragma unroll
  for (int rep = 0; rep < 8; ++rep) {
    int idx = rep * 256 + tid;
    int d = idx >> 4, q = idx & 15;
    float4 v = *reinterpret_cast<const float4*>(z32 + (size_t)d * NTOK + tokbase + q * 4);
    *reinterpret_cast<float4*>(&Zl[d][q * 4]) = v;
  }
  __syncthreads();
  {
    int tt = tid & 63, part = tid >> 6;
    double s = 0.0;
#pragma unroll
    for (int dd = 0; dd < 32; ++dd) { double v = (double)Zl[part * 32 + dd][tt]; s += v * v; }
    znp[part][tt] = s;
  }
  __syncthreads();
  if (tid < 64) zn[tid] = (float)(((znp[0][tid] + znp[1][tid]) + znp[2][tid]) + znp[3][tid]);
  const float INF = 3.4e38f;
  float gm1[4] = {INF, INF, INF, INF};
  int   gi1[4] = {0, 0, 0, 0};
  for (int c = 0; c < 8; ++c) {
    double acc[8][4] = {};
    for (int kc = 0; kc < 4; ++kc) {
      __syncthreads();
      if (kc == 0 && tid < 128) Cn[tid] = cbn32b[c * 128 + tid];
#pragma unroll
      for (int rep = 0; rep < 4; ++rep) {
        int idx = rep * 256 + tid;
        int r = idx >> 3, q = idx & 7;
        float4 v = reinterpret_cast<const float4*>(cb)[(size_t)(c * 128 + r) * 32 + kc * 8 + q];
        Al[q * 4 + 0][r] = v.x; Al[q * 4 + 1][r] = v.y;
        Al[q * 4 + 2][r] = v.z; Al[q * 4 + 3][r] = v.w;
      }
      __syncthreads();
#pragma unroll
      for (int kk = 0; kk < 32; ++kk) {
        float4 a0 = *reinterpret_cast<const float4*>(&Al[kk][mx * 8]);
        float4 a1 = *reinterpret_cast<const float4*>(&Al[kk][mx * 8 + 4]);
        float4 bv = *reinterpret_cast<const float4*>(&Zl[kc * 32 + kk][nx * 4]);
        double a[8] = {a0.x, a0.y, a0.z, a0.w, a1.x, a1.y, a1.z, a1.w};
        double bb[4] = {bv.x, bv.y, bv.z, bv.w};
#pragma unroll
        for (int u = 0; u < 8; ++u)
#pragma unroll
          for (int j = 0; j < 4; ++j) acc[u][j] = fma(a[u], bb[j], acc[u][j]);
      }
    }
    float tm1[4]; int ti1[4];
#pragma unroll
    for (int j = 0; j < 4; ++j) {
      float m1 = INF; int i1 = 0;
      float znj = zn[nx * 4 + j];
#pragma unroll
      for (int u = 0; u < 8; ++u) {
        float M  = (float)acc[u][j];
        float dv = __fsub_rn(znj, __fmul_rn(2.0f, M));
        float d2 = __fadd_rn(dv, Cn[mx * 8 + u]);
        if (d2 < m1) { m1 = d2; i1 = c * 128 + mx * 8 + u; }
      }
      tm1[j] = m1; ti1[j] = i1;
    }
    __syncthreads();
#pragma unroll
    for (int j = 0; j < 4; ++j) {
      int slot = j * 256 + nx * 16 + mx;
      Rm1[slot] = tm1[j]; Ri[slot] = ti1[j];
    }
    __syncthreads();
    if (mx == 0) {
#pragma unroll
      for (int j = 0; j < 4; ++j) {
        float m1 = INF; int i1 = 0;
        for (int x = 0; x < 16; ++x) {
          int slot = j * 256 + nx * 16 + x;
          float am = Rm1[slot];
          if (am < m1) { m1 = am; i1 = Ri[slot]; }
        }
        if (m1 < gm1[j]) { gm1[j] = m1; gi1[j] = i1; }
      }
    }
  }
  if (mx == 0) {
    double lp = 0.0;
#pragma unroll
    for (int j = 0; j < 4; ++j) {
      codes[((size_t)b * NB + book) * T + t0 + nx * 4 + j] = gi1[j];
      lp += (double)gm1[j];
    }
    lred[nx] = lp;
  }
  __syncthreads();
  if (tid == 0) {
    double s = 0.0;
#pragma unroll
    for (int i = 0; i < 16; ++i) s += lred[i];
    lpart[(size_t)book * 1024 + b * 64 + blockIdx.x] = s;
  }
}

// ---------------------------------------------------------------------------
__global__ __launch_bounds__(256) void qsum64_kernel(double* __restrict__ qs64,
                                                     const float* __restrict__ cb,
                                                     const int* __restrict__ codes,
                                                     int book) {
  int tok = blockIdx.x * 256 + threadIdx.x;
  int b = tok >> 12, t = tok & (T - 1);
  int code = codes[((size_t)b * NB + book) * T + t];
  const float* row = cb + (size_t)code * CD;
  for (int k = 0; k < CD; ++k)
    qs64[(size_t)k * NTOK + tok] += (double)row[k];
}

// ---------------------------------------------------------------------------
__global__ __launch_bounds__(256) void final64_kernel(const double* __restrict__ qs64,
                                                      const float* __restrict__ Wout,
                                                      const float* __restrict__ bout,
                                                      float* __restrict__ out) {
  __shared__ __align__(16) float Al[32][132];
  __shared__ double Bl64[32][65];
  const int tid = threadIdx.x;
  const int t0 = blockIdx.x * 64;
  const int Dg = blockIdx.y;
  const int b  = blockIdx.z;
  const int mx = tid & 15, nx = tid >> 4;
  const size_t tokbase = (size_t)b * T + t0;
  double acc[8][4] = {};
  for (int kc = 0; kc < 4; ++kc) {
    __syncthreads();
#pragma unroll
    for (int rep = 0; rep < 4; ++rep) {
      int idx = rep * 256 + tid;
      int r = idx >> 3, q = idx & 7;
      float4 v = reinterpret_cast<const float4*>(Wout)[(size_t)(Dg * 128 + r) * 32 + kc * 8 + q];
      Al[q * 4 + 0][r] = v.x; Al[q * 4 + 1][r] = v.y;
      Al[q * 4 + 2][r] = v.z; Al[q * 4 + 3][r] = v.w;
    }
#pragma unroll
    for (int rep = 0; rep < 8; ++rep) {
      int idx = rep * 256 + tid;
      int kk = idx >> 6, tt = idx & 63;
      Bl64[kk][tt] = qs64[(size_t)(kc * 32 + kk) * NTOK + tokbase + tt];
    }
    __syncthreads();
#pragma unroll
    for (int kk = 0; kk < 32; ++kk) {
      double a[8];
#pragma unroll
      for (int u = 0; u < 8; ++u) a[u] = (double)Al[kk][mx * 8 + u];
#pragma unroll
      for (int j = 0; j < 4; ++j) {
        double bb = Bl64[kk][nx * 4 + j];
#pragma unroll
        for (int u = 0; u < 8; ++u) acc[u][j] = fma(a[u], bb, acc[u][j]);
      }
    }
  }
#pragma unroll
  for (int u = 0; u < 8; ++u) {
    int D = Dg * 128 + mx * 8 + u;
    double bo = 8.0 * (double)bout[D];
    float4 o = make_float4((float)(acc[u][0] + bo), (float)(acc[u][1] + bo),
                           (float)(acc[u][2] + bo), (float)(acc[u][3] + bo));
    reinterpret_cast<float4*>(out + ((size_t)b * DIN + D) * T + t0)[nx] = o;
  }
}

// ---------------------------------------------------------------------------
__global__ __launch_bounds__(256) void codes_out_kernel(const int* __restrict__ codes,
                                                        float* __restrict__ out) {
  int k = blockIdx.x * 256 + threadIdx.x;
  if (k < BATCH * NB * T)
    out[(size_t)BATCH * DIN * T + k] = (float)codes[k];
}

__global__ __launch_bounds__(256) void loss_out_kernel(const double* __restrict__ lpF,
                                                       const double* __restrict__ lpS,
                                                       const int* __restrict__ probe_ok,
                                                       float* __restrict__ out) {
  __shared__ double red[256];
  const double* lp = (*probe_ok) ? lpF : lpS;
  double s = 0.0;
  for (int i = threadIdx.x; i < NB * 1024; i += 256) s += lp[i];
  red[threadIdx.x] = s;
  __syncthreads();
  for (int off = 128; off; off >>= 1) {
    if (threadIdx.x < off) red[threadIdx.x] += red[threadIdx.x + off];
    __syncthreads();
  }
  if (threadIdx.x == 0)
    out[(size_t)BATCH * DIN * T + (size_t)BATCH * NB * T] =
        (float)(red[0] * 1.25 / 8388608.0);
}

// ---------------------------------------------------------------------------
extern "C" void kernel_launch(void* const* d_in, const int* in_sizes, int n_in,
                              void* d_out, int out_size, void* d_ws, size_t ws_size,
                              hipStream_t stream) {
  (void)in_sizes; (void)n_in; (void)out_size; (void)ws_size;
  const float* z    = (const float*)d_in[0];
  const float* Win  = (const float*)d_in[1];
  const float* bin  = (const float*)d_in[2];
  const float* Wout = (const float*)d_in[3];
  const float* bout = (const float*)d_in[4];
  const float* cbs  = (const float*)d_in[5];
  float* out = (float*)d_out;
  double* A64 = (double*)d_out;   // aliases z_q region; overwritten by final64

  char* w = (char*)d_ws;
  double* qs64  = (double*)w;  w += (size_t)CD * NTOK * 8;        // 67.1 MB
  double* P64t  = (double*)w;  w += (size_t)CD * CD * 8;
  double* cvec64= (double*)w;  w += CD * 8;
  double* lpartF= (double*)w;  w += (size_t)NB * 1024 * 8;
  double* lpartS= (double*)w;  w += (size_t)NB * 1024 * 8;
  float*  z32   = (float*)w;   w += (size_t)CD * NTOK * 4;        // 33.6 MB
  float*  cbn32 = (float*)w;   w += (size_t)NB * S * 4;
  float*  dump  = (float*)w;   w += 8192 * 4;
  unsigned short* z16  = (unsigned short*)w; w += (size_t)CD * NTOK * 2;   // 16.8 MB
  unsigned short* cb16 = (unsigned short*)w; w += (size_t)NB * S * CD * 2; // 2.1 MB
  unsigned short* fgl  = (unsigned short*)w; w += (size_t)NTOK * FCAP * 2; // 3.1 MB
  int*    fcg   = (int*)w;     w += (size_t)NTOK * 4;
  int*    codes = (int*)w;     w += (size_t)BATCH * NB * T * 4;
  int*    probe_ok = (int*)w;  w += 256;

  cbn32_kernel<<<(NB * S + 255) / 256, 256, 0, stream>>>(cbs, cbn32);
  cb16_kernel<<<(NB * S * CD + 255) / 256, 256, 0, stream>>>(cbs, cb16);
  p64t_kernel<<<64, 256, 0, stream>>>(Win, Wout, P64t);
  cvec64_kernel<<<1, 128, 0, stream>>>(Win, bout, cvec64);
  a64_kernel<<<dim3(T / 64, BATCH), 256, 0, stream>>>(z, Win, bin, A64);
  hipMemsetAsync(qs64, 0, (size_t)CD * NTOK * 8, stream);

  for (int book = 0; book < NB; ++book) {
    const float* cb = cbs + (size_t)book * S * CD;
    const unsigned short* cbh = cb16 + (size_t)book * S * CD;
    zproj32_kernel<<<NTOK / 64, 256, 0, stream>>>(A64, qs64, P64t, cvec64, z32, z16, book);
    score_mfma_kernel<<<NTOK / 64, 256, 0, stream>>>(z16, cbh, cbn32 + book * S,
                                                     fgl, fcg, dump, book);
    if (book == 0)
      probe_kernel<<<1, 256, 0, stream>>>(z16, cb16, cbn32, dump, probe_ok);
    refine_kernel<<<NTOK / 64, 256, 0, stream>>>(z32, cb, cbn32 + book * S,
                                                 fgl, fcg, probe_ok, codes, lpartF, book);
    score_fb_kernel<<<dim3(T / 64, BATCH), 256, 0, stream>>>(z32, cb, cbn32 + book * S,
                                                             codes, lpartS, probe_ok, book);
    qsum64_kernel<<<NTOK / 256, 256, 0, stream>>>(qs64, cb, codes, book);
  }
  final64_kernel<<<dim3(T / 64, DIN / 128, BATCH), 256, 0, stream>>>(qs64, Wout, bout, out);
  codes_out_kernel<<<(BATCH * NB * T + 255) / 256, 256, 0, stream>>>(codes, out);
  loss_out_kernel<<<1, 256, 0, stream>>>(lpartF, lpartS, probe_ok, out);
}

// Round 11
// 1832.289 us; speedup vs baseline: 5.6415x; 1.2480x over previous
//
#include <hip/hip_runtime.h>
#include <cstdint>

constexpr int NB   = 8;
constexpr int S    = 1024;
constexpr int CD   = 128;
constexpr int DIN  = 512;
constexpr int BATCH= 16;
constexpr int T    = 4096;
constexpr int NTOK = BATCH * T;        // 65536
constexpr int FCAP = 24;
constexpr float MARGIN = 4e-3f;        // > 2 * 1.3e-3 worst-case bf16 approx error

typedef __attribute__((ext_vector_type(8))) short bf16x8;
typedef __attribute__((ext_vector_type(4))) float f32x4;

__device__ __forceinline__ unsigned short f2bf(float f) {
  unsigned int u = __float_as_uint(f);
  return (unsigned short)((u + 0x7fffu + ((u >> 16) & 1u)) >> 16);
}
__device__ __forceinline__ float bf2f(unsigned short h) {
  return __uint_as_float((unsigned int)h << 16);
}

// ---------------------------------------------------------------------------
__global__ __launch_bounds__(256) void cbn32_kernel(const float* __restrict__ cbs,
                                                    float* __restrict__ cbn32) {
  int row = blockIdx.x * 256 + threadIdx.x;
  if (row >= NB * S) return;
  const float4* r4 = reinterpret_cast<const float4*>(cbs + (size_t)row * CD);
  double s = 0.0;
  for (int q = 0; q < 32; ++q) {
    float4 v = r4[q];
    s += (double)v.x * v.x + (double)v.y * v.y + (double)v.z * v.z + (double)v.w * v.w;
  }
  cbn32[row] = (float)s;
}

__global__ __launch_bounds__(256) void cb16_kernel(const float* __restrict__ cbs,
                                                   unsigned short* __restrict__ cb16) {
  int i = blockIdx.x * 256 + threadIdx.x;
  if (i < NB * S * CD) cb16[i] = f2bf(cbs[i]);
}

__global__ __launch_bounds__(256) void p64t_kernel(const float* __restrict__ Win,
                                                   const float* __restrict__ Wout,
                                                   double* __restrict__ P64t) {
  int n = blockIdx.x * 256 + threadIdx.x;   // 16384
  int k = n >> 7, d = n & 127;
  double s = 0.0;
  for (int D = 0; D < DIN; ++D)
    s = fma((double)Win[(size_t)d * DIN + D], (double)Wout[(size_t)D * CD + k], s);
  P64t[(size_t)k * CD + d] = s;
}

__global__ void cvec64_kernel(const float* __restrict__ Win,
                              const float* __restrict__ bout,
                              double* __restrict__ cvec64) {
  int d = threadIdx.x;  // 128
  double s = 0.0;
  for (int D = 0; D < DIN; ++D)
    s = fma((double)Win[(size_t)d * DIN + D], (double)bout[D], s);
  cvec64[d] = s;
}

// PCF64[book][s][d] = sum_k cb[book][s][k] * P64t[k][d] + cvec64[d]
__global__ void pcf_kernel(const float* __restrict__ cbs,
                           const double* __restrict__ P64t,
                           const double* __restrict__ cvec64,
                           double* __restrict__ PCF64) {
  const int s = blockIdx.x, book = blockIdx.y;
  const int d = threadIdx.x;   // 128
  const float* cr = cbs + ((size_t)book * S + s) * CD;
  double acc = 0.0;
  for (int k = 0; k < CD; ++k)
    acc = fma((double)cr[k], P64t[(size_t)k * CD + d], acc);
  PCF64[((size_t)book * S + s) * CD + d] = acc + cvec64[d];
}

// ---------------------------------------------------------------------------
// Acur[d][tok] = fp64( sum_D Win[d,D]*z[b,D,t] + bin[d] )   — [d][tok] LAYOUT
// (tok = b*T + t; consumers zprojf/update_kernel assume this layout)
__global__ __launch_bounds__(256) void a64_kernel(const float* __restrict__ z,
                                                  const float* __restrict__ Win,
                                                  const float* __restrict__ bin,
                                                  double* __restrict__ A64) {
  __shared__ __align__(16) float Al[32][132];
  __shared__ __align__(16) float Bl[32][68];
  const int tid = threadIdx.x;
  const int t0 = blockIdx.x * 64;
  const int b  = blockIdx.y;
  const int mx = tid & 15, nx = tid >> 4;
  double acc[8][4] = {};
  for (int kc = 0; kc < 16; ++kc) {
    __syncthreads();
#pragma unroll
    for (int rep = 0; rep < 4; ++rep) {
      int idx = rep * 256 + tid;
      int r = idx >> 3, q = idx & 7;
      float4 v = reinterpret_cast<const float4*>(Win)[(size_t)r * 128 + kc * 8 + q];
      Al[q * 4 + 0][r] = v.x; Al[q * 4 + 1][r] = v.y;
      Al[q * 4 + 2][r] = v.z; Al[q * 4 + 3][r] = v.w;
    }
#pragma unroll
    for (int rep = 0; rep < 2; ++rep) {
      int idx = rep * 256 + tid;
      int kk = idx >> 4, q = idx & 15;
      float4 v = reinterpret_cast<const float4*>(z + ((size_t)(b * DIN + kc * 32 + kk)) * T + t0)[q];
      *reinterpret_cast<float4*>(&Bl[kk][q * 4]) = v;
    }
    __syncthreads();
#pragma unroll
    for (int kk = 0; kk < 32; ++kk) {
      float4 a0 = *reinterpret_cast<const float4*>(&Al[kk][mx * 8]);
      float4 a1 = *reinterpret_cast<const float4*>(&Al[kk][mx * 8 + 4]);
      float4 bv = *reinterpret_cast<const float4*>(&Bl[kk][nx * 4]);
      double a[8] = {a0.x, a0.y, a0.z, a0.w, a1.x, a1.y, a1.z, a1.w};
      double bb[4] = {bv.x, bv.y, bv.z, bv.w};
#pragma unroll
      for (int u = 0; u < 8; ++u)
#pragma unroll
        for (int j = 0; j < 4; ++j) acc[u][j] = fma(a[u], bb[j], acc[u][j]);
    }
  }
#pragma unroll
  for (int u = 0; u < 8; ++u) {
    int d = mx * 8 + u;
    double bi = (double)bin[d];
    // [d][tok] layout: d*NTOK + b*T + t
    double* Ap = A64 + (size_t)d * NTOK + (size_t)b * T + t0 + nx * 4;
#pragma unroll
    for (int j = 0; j < 4; ++j) Ap[j] = acc[u][j] + bi;
  }
}

// ---------------------------------------------------------------------------
// Streaming cast: z32 = fl32(Acur64), z16 = bf16(z32).  (flat [d][tok])
__global__ __launch_bounds__(256) void zprojf_kernel(const double* __restrict__ Acur,
                                                     float* __restrict__ z32,
                                                     unsigned short* __restrict__ z16) {
  const size_t i0 = ((size_t)blockIdx.x * 256 + threadIdx.x) * 8;
#pragma unroll
  for (int j = 0; j < 8; ++j) {
    float f = (float)Acur[i0 + j];
    z32[i0 + j] = f;
    z16[i0 + j] = f2bf(f);
  }
}

// ---------------------------------------------------------------------------
// Per-book state update (after codes are final):
//   qs32[k][tok] += cb[code][k]           (all books)
//   Acur64[d][tok] -= PCF64[code][d]      (books 0..6; book 7 skips)
template <bool LAST>
__global__ __launch_bounds__(256) void update_kernel(double* __restrict__ Acur,
                                                     float* __restrict__ qs32,
                                                     const double* __restrict__ PCFb,
                                                     const float* __restrict__ cbb,
                                                     const int* __restrict__ codes,
                                                     int book) {
  const int tid = threadIdx.x;
  const int tok0 = blockIdx.x * 64;
  const int tl = tid & 63, h = tid >> 6;
  const int tok = tok0 + tl;
  const int b = tok >> 12, t = tok & (T - 1);
  const int code = codes[((size_t)b * NB + book) * T + t];
  const float* cr = cbb + (size_t)code * CD + h * 32;
#pragma unroll
  for (int k = 0; k < 32; ++k)
    qs32[(size_t)(h * 32 + k) * NTOK + tok] += cr[k];
  if constexpr (!LAST) {
    const double* pr = PCFb + (size_t)code * CD + h * 32;
#pragma unroll
    for (int d = 0; d < 32; ++d)
      Acur[(size_t)(h * 32 + d) * NTOK + tok] -= pr[d];
  }
}

// ---------------------------------------------------------------------------
// bf16 MFMA approx scores, TWO-PASS (pass A: global min; pass B: flag).
__global__ __launch_bounds__(256) void score_mfma_kernel(
    const unsigned short* __restrict__ z16,
    const unsigned short* __restrict__ cb16b,
    const float* __restrict__ cbn32b,
    unsigned short* __restrict__ fgl,
    int* __restrict__ fcg,
    float* __restrict__ dump,
    int book) {
  __shared__ unsigned short cbL[128][136];
  __shared__ unsigned short ZtT[64][136];
  __shared__ float Cna[1024];
  __shared__ float gmin[64];
  __shared__ float wmin[4][64];
  __shared__ int   fcnt[64];
  __shared__ unsigned short fls[64][FCAP];
  const int tid = threadIdx.x;
  const int tok0 = blockIdx.x * 64;
  const int wv = tid >> 6, ln = tid & 63;
  const int lr = ln & 15, lg = ln >> 4;

  for (int rep = 0; rep < 4; ++rep) {           // z16 [k][tok] -> LDS [t][k]
    int idx = rep * 256 + tid;
    int k = idx >> 3, tg = idx & 7;
    bf16x8 v = *reinterpret_cast<const bf16x8*>(z16 + (size_t)k * NTOK + tok0 + tg * 8);
#pragma unroll
    for (int e = 0; e < 8; ++e) ZtT[tg * 8 + e][k] = (unsigned short)v[e];
  }
#pragma unroll
  for (int rep = 0; rep < 4; ++rep) Cna[rep * 256 + tid] = cbn32b[rep * 256 + tid];
  if (tid < 64) { gmin[tid] = 3.4e38f; fcnt[tid] = 0; }

  // ======== PASS A ========
  for (int c = 0; c < 8; ++c) {
    __syncthreads();
    for (int rep = 0; rep < 8; ++rep) {
      int idx = rep * 256 + tid;
      int s = idx >> 4, q = idx & 15;
      *reinterpret_cast<bf16x8*>(&cbL[s][q * 8]) =
          *reinterpret_cast<const bf16x8*>(cb16b + (size_t)(c * 128 + s) * 128 + q * 8);
    }
    __syncthreads();

    f32x4 acc[2][4];
#pragma unroll
    for (int ss = 0; ss < 2; ++ss)
#pragma unroll
      for (int ts = 0; ts < 4; ++ts) acc[ss][ts] = (f32x4){0.f, 0.f, 0.f, 0.f};
#pragma unroll
    for (int ks = 0; ks < 4; ++ks) {
      bf16x8 a0 = *reinterpret_cast<const bf16x8*>(&cbL[wv * 32 + lr][ks * 32 + lg * 8]);
      bf16x8 a1 = *reinterpret_cast<const bf16x8*>(&cbL[wv * 32 + 16 + lr][ks * 32 + lg * 8]);
      bf16x8 b0 = *reinterpret_cast<const bf16x8*>(&ZtT[lr][ks * 32 + lg * 8]);
      bf16x8 b1 = *reinterpret_cast<const bf16x8*>(&ZtT[16 + lr][ks * 32 + lg * 8]);
      bf16x8 b2 = *reinterpret_cast<const bf16x8*>(&ZtT[32 + lr][ks * 32 + lg * 8]);
      bf16x8 b3 = *reinterpret_cast<const bf16x8*>(&ZtT[48 + lr][ks * 32 + lg * 8]);
      acc[0][0] = __builtin_amdgcn_mfma_f32_16x16x32_bf16(a0, b0, acc[0][0], 0, 0, 0);
      acc[0][1] = __builtin_amdgcn_mfma_f32_16x16x32_bf16(a0, b1, acc[0][1], 0, 0, 0);
      acc[0][2] = __builtin_amdgcn_mfma_f32_16x16x32_bf16(a0, b2, acc[0][2], 0, 0, 0);
      acc[0][3] = __builtin_amdgcn_mfma_f32_16x16x32_bf16(a0, b3, acc[0][3], 0, 0, 0);
      acc[1][0] = __builtin_amdgcn_mfma_f32_16x16x32_bf16(a1, b0, acc[1][0], 0, 0, 0);
      acc[1][1] = __builtin_amdgcn_mfma_f32_16x16x32_bf16(a1, b1, acc[1][1], 0, 0, 0);
      acc[1][2] = __builtin_amdgcn_mfma_f32_16x16x32_bf16(a1, b2, acc[1][2], 0, 0, 0);
      acc[1][3] = __builtin_amdgcn_mfma_f32_16x16x32_bf16(a1, b3, acc[1][3], 0, 0, 0);
    }
#pragma unroll
    for (int ss = 0; ss < 2; ++ss)
#pragma unroll
      for (int ts = 0; ts < 4; ++ts)
#pragma unroll
        for (int r = 0; r < 4; ++r)
          acc[ss][ts][r] = fmaf(-2.f, acc[ss][ts][r],
                                Cna[c * 128 + wv * 32 + ss * 16 + lg * 4 + r]);
    float mts[4];
#pragma unroll
    for (int ts = 0; ts < 4; ++ts) {
      float m = acc[0][ts][0];
#pragma unroll
      for (int r = 1; r < 4; ++r) m = fminf(m, acc[0][ts][r]);
#pragma unroll
      for (int r = 0; r < 4; ++r) m = fminf(m, acc[1][ts][r]);
      m = fminf(m, __shfl_xor(m, 16));
      m = fminf(m, __shfl_xor(m, 32));
      mts[ts] = m;
    }
    if (lg == 0) {
#pragma unroll
      for (int ts = 0; ts < 4; ++ts) wmin[wv][ts * 16 + lr] = mts[ts];
    }
    __syncthreads();
    if (tid < 64) {
      float g = fminf(fminf(wmin[0][tid], wmin[1][tid]), fminf(wmin[2][tid], wmin[3][tid]));
      gmin[tid] = fminf(gmin[tid], g);
    }
  }
  __syncthreads();

  // ======== PASS B ========
  for (int c = 0; c < 8; ++c) {
    __syncthreads();
    for (int rep = 0; rep < 8; ++rep) {
      int idx = rep * 256 + tid;
      int s = idx >> 4, q = idx & 15;
      *reinterpret_cast<bf16x8*>(&cbL[s][q * 8]) =
          *reinterpret_cast<const bf16x8*>(cb16b + (size_t)(c * 128 + s) * 128 + q * 8);
    }
    __syncthreads();

    f32x4 acc[2][4];
#pragma unroll
    for (int ss = 0; ss < 2; ++ss)
#pragma unroll
      for (int ts = 0; ts < 4; ++ts) acc[ss][ts] = (f32x4){0.f, 0.f, 0.f, 0.f};
#pragma unroll
    for (int ks = 0; ks < 4; ++ks) {
      bf16x8 a0 = *reinterpret_cast<const bf16x8*>(&cbL[wv * 32 + lr][ks * 32 + lg * 8]);
      bf16x8 a1 = *reinterpret_cast<const bf16x8*>(&cbL[wv * 32 + 16 + lr][ks * 32 + lg * 8]);
      bf16x8 b0 = *reinterpret_cast<const bf16x8*>(&ZtT[lr][ks * 32 + lg * 8]);
      bf16x8 b1 = *reinterpret_cast<const bf16x8*>(&ZtT[16 + lr][ks * 32 + lg * 8]);
      bf16x8 b2 = *reinterpret_cast<const bf16x8*>(&ZtT[32 + lr][ks * 32 + lg * 8]);
      bf16x8 b3 = *reinterpret_cast<const bf16x8*>(&ZtT[48 + lr][ks * 32 + lg * 8]);
      acc[0][0] = __builtin_amdgcn_mfma_f32_16x16x32_bf16(a0, b0, acc[0][0], 0, 0, 0);
      acc[0][1] = __builtin_amdgcn_mfma_f32_16x16x32_bf16(a0, b1, acc[0][1], 0, 0, 0);
      acc[0][2] = __builtin_amdgcn_mfma_f32_16x16x32_bf16(a0, b2, acc[0][2], 0, 0, 0);
      acc[0][3] = __builtin_amdgcn_mfma_f32_16x16x32_bf16(a0, b3, acc[0][3], 0, 0, 0);
      acc[1][0] = __builtin_amdgcn_mfma_f32_16x16x32_bf16(a1, b0, acc[1][0], 0, 0, 0);
      acc[1][1] = __builtin_amdgcn_mfma_f32_16x16x32_bf16(a1, b1, acc[1][1], 0, 0, 0);
      acc[1][2] = __builtin_amdgcn_mfma_f32_16x16x32_bf16(a1, b2, acc[1][2], 0, 0, 0);
      acc[1][3] = __builtin_amdgcn_mfma_f32_16x16x32_bf16(a1, b3, acc[1][3], 0, 0, 0);
    }
#pragma unroll
    for (int ss = 0; ss < 2; ++ss)
#pragma unroll
      for (int ts = 0; ts < 4; ++ts)
#pragma unroll
        for (int r = 0; r < 4; ++r)
          acc[ss][ts][r] = fmaf(-2.f, acc[ss][ts][r],
                                Cna[c * 128 + wv * 32 + ss * 16 + lg * 4 + r]);
#pragma unroll
    for (int ts = 0; ts < 4; ++ts) {
      int t = ts * 16 + lr;
      float thr = gmin[t] + MARGIN;
#pragma unroll
      for (int ss = 0; ss < 2; ++ss)
#pragma unroll
        for (int r = 0; r < 4; ++r) {
          float v = acc[ss][ts][r];
          int s = c * 128 + wv * 32 + ss * 16 + lg * 4 + r;
          if (book == 0 && blockIdx.x == 0 && c == 0)
            dump[(size_t)(wv * 32 + ss * 16 + lg * 4 + r) * 64 + t] = v;
          if (v <= thr) {
            int pos = atomicAdd(&fcnt[t], 1);
            if (pos < FCAP) fls[t][pos] = (unsigned short)s;
          }
        }
    }
  }
  __syncthreads();
  if (tid < 64) fcg[tok0 + tid] = fcnt[tid];
  for (int idx = tid; idx < 64 * FCAP; idx += 256) {
    int t = idx / FCAP, i = idx - t * FCAP;
    fgl[(size_t)(tok0 + t) * FCAP + i] = fls[t][i];
  }
}

// ---------------------------------------------------------------------------
__global__ __launch_bounds__(256) void probe_kernel(const unsigned short* __restrict__ z16,
                                                    const unsigned short* __restrict__ cb16,
                                                    const float* __restrict__ cbn32,
                                                    const float* __restrict__ dump,
                                                    int* __restrict__ probe_ok) {
  __shared__ float red[256];
  const int tid = threadIdx.x;
  float mx = 0.f;
  for (int p = tid; p < 8192; p += 256) {
    int s = p >> 6, t = p & 63;
    double e = 0.0;
    for (int d = 0; d < 128; ++d)
      e += (double)bf2f(cb16[(size_t)s * 128 + d]) * (double)bf2f(z16[(size_t)d * NTOK + t]);
    float ref = fmaf(-2.f, (float)e, cbn32[s]);
    mx = fmaxf(mx, fabsf(ref - dump[p]));
  }
  red[tid] = mx;
  __syncthreads();
  for (int off = 128; off; off >>= 1) {
    if (tid < off) red[tid] = fmaxf(red[tid], red[tid + off]);
    __syncthreads();
  }
  if (tid == 0) *probe_ok = (red[0] < 1e-4f) ? 1 : 0;
}

// ---------------------------------------------------------------------------
// Exact candidate evaluation (bitwise round-6 numerics); block-cooperative
// full scan for FCAP overflow tokens.
__global__ __launch_bounds__(256) void refine_kernel(const float* __restrict__ z32,
                                                     const float* __restrict__ cbb,
                                                     const float* __restrict__ cbn32b,
                                                     const unsigned short* __restrict__ fgl,
                                                     const int* __restrict__ fcg,
                                                     const int* __restrict__ probe_ok,
                                                     int* __restrict__ codes,
                                                     double* __restrict__ lpartF,
                                                     int book) {
  if (!*probe_ok) return;
  __shared__ float Zl[128][64];
  __shared__ double znp[4][64];
  __shared__ float znl[64];
  __shared__ float bestv[4][64];
  __shared__ int   bests[4][64];
  __shared__ double lred[64];
  __shared__ float rm[256];
  __shared__ int   ri[256];
  __shared__ int   ovl[64];
  __shared__ int   ovn;
  __shared__ unsigned char ovf[64];
  const int tid = threadIdx.x;
  const int tok0 = blockIdx.x * 64;
  const int b = tok0 >> 12;
  const int tl = tid & 63, h = tid >> 6;
  if (tid == 0) ovn = 0;
  for (int rep = 0; rep < 8; ++rep) {
    int idx = rep * 256 + tid;
    int d = idx >> 4, q = idx & 15;
    float4 v = *reinterpret_cast<const float4*>(z32 + (size_t)d * NTOK + tok0 + q * 4);
    Zl[d][q * 4 + 0] = v.x; Zl[d][q * 4 + 1] = v.y;
    Zl[d][q * 4 + 2] = v.z; Zl[d][q * 4 + 3] = v.w;
  }
  __syncthreads();
  {
    double s = 0.0;
#pragma unroll
    for (int dd = 0; dd < 32; ++dd) { double v = (double)Zl[h * 32 + dd][tl]; s += v * v; }
    znp[h][tl] = s;
  }
  __syncthreads();
  if (tid < 64) znl[tid] = (float)(((znp[0][tid] + znp[1][tid]) + znp[2][tid]) + znp[3][tid]);
  __syncthreads();
  const float zn = znl[tl];
  const int tok = tok0 + tl;
  const int cnt = fcg[tok];
  float bm = 3.4e38f; int bi = 0x7fffffff;
  if (cnt <= FCAP) {
    if (h == 0) ovf[tl] = 0;
    for (int i = h; i < cnt; i += 4) {
      int s = fgl[(size_t)tok * FCAP + i];
      const float* cr = cbb + (size_t)s * CD;
      double e = 0.0;
      for (int d = 0; d < CD; ++d) e = fma((double)cr[d], (double)Zl[d][tl], e);
      float M = (float)e;
      float d2 = __fadd_rn(__fsub_rn(zn, __fmul_rn(2.f, M)), cbn32b[s]);
      if (d2 < bm || (d2 == bm && s < bi)) { bm = d2; bi = s; }
    }
  } else {
    if (h == 0) { int p = atomicAdd(&ovn, 1); ovl[p] = tl; ovf[tl] = 1; }
  }
  bestv[h][tl] = bm; bests[h][tl] = bi;
  __syncthreads();
  if (tid < 64 && !ovf[tid]) {
    float fv = bestv[0][tid]; int fs = bests[0][tid];
#pragma unroll
    for (int x = 1; x < 4; ++x) {
      float v = bestv[x][tid]; int s = bests[x][tid];
      if (v < fv || (v == fv && s < fs)) { fv = v; fs = s; }
    }
    codes[((size_t)b * NB + book) * T + ((tok0 + tid) & (T - 1))] = fs;
    lred[tid] = (double)fv;
  }
  __syncthreads();
  const int no = ovn;
  for (int e = 0; e < no; ++e) {
    const int tt = ovl[e];
    const float zn2 = znl[tt];
    double e0 = 0.0, e1 = 0.0, e2 = 0.0, e3 = 0.0;
    const float* c0 = cbb + (size_t)(tid      ) * CD;
    const float* c1 = cbb + (size_t)(tid + 256) * CD;
    const float* c2 = cbb + (size_t)(tid + 512) * CD;
    const float* c3 = cbb + (size_t)(tid + 768) * CD;
    for (int d = 0; d < CD; ++d) {
      double zv = (double)Zl[d][tt];
      e0 = fma((double)c0[d], zv, e0);
      e1 = fma((double)c1[d], zv, e1);
      e2 = fma((double)c2[d], zv, e2);
      e3 = fma((double)c3[d], zv, e3);
    }
    float bm2 = 3.4e38f; int bi2 = 0x7fffffff;
    {
      float d2;
      d2 = __fadd_rn(__fsub_rn(zn2, __fmul_rn(2.f, (float)e0)), cbn32b[tid]);
      if (d2 < bm2) { bm2 = d2; bi2 = tid; }
      d2 = __fadd_rn(__fsub_rn(zn2, __fmul_rn(2.f, (float)e1)), cbn32b[tid + 256]);
      if (d2 < bm2) { bm2 = d2; bi2 = tid + 256; }
      d2 = __fadd_rn(__fsub_rn(zn2, __fmul_rn(2.f, (float)e2)), cbn32b[tid + 512]);
      if (d2 < bm2) { bm2 = d2; bi2 = tid + 512; }
      d2 = __fadd_rn(__fsub_rn(zn2, __fmul_rn(2.f, (float)e3)), cbn32b[tid + 768]);
      if (d2 < bm2) { bm2 = d2; bi2 = tid + 768; }
    }
    rm[tid] = bm2; ri[tid] = bi2;
    __syncthreads();
    for (int off = 128; off; off >>= 1) {
      if (tid < off) {
        float om = rm[tid + off]; int oi = ri[tid + off];
        if (om < rm[tid] || (om == rm[tid] && oi < ri[tid])) { rm[tid] = om; ri[tid] = oi; }
      }
      __syncthreads();
    }
    if (tid == 0) {
      codes[((size_t)b * NB + book) * T + ((tok0 + tt) & (T - 1))] = ri[0];
      lred[tt] = (double)rm[0];
    }
    __syncthreads();
  }
  if (tid == 0) {
    double sum = 0.0;
    for (int i = 0; i < 64; ++i) sum += lred[i];
    lpartF[(size_t)book * 1024 + blockIdx.x] = sum;
  }
}

// ---------------------------------------------------------------------------
// FALLBACK: round-6 proven score kernel, active only if probe failed.
__global__ __launch_bounds__(256) void score_fb_kernel(const float* __restrict__ z32,
                                                       const float* __restrict__ cb,
                                                       const float* __restrict__ cbn32b,
                                                       int* __restrict__ codes,
                                                       double* __restrict__ lpart,
                                                       const int* __restrict__ probe_ok,
                                                       int book) {
  if (*probe_ok) return;
  __shared__ __align__(16) float Zl[128][68];
  __shared__ __align__(16) float Al[32][132];
  __shared__ float Cn[128];
  __shared__ double znp[4][64];
  __shared__ float zn[64];
  __shared__ double lred[16];
  const int tid = threadIdx.x;
  const int t0 = blockIdx.x * 64;
  const int b  = blockIdx.y;
  const int mx = tid & 15, nx = tid >> 4;
  const size_t tokbase = (size_t)b * T + t0;
  float* Rm1 = &Al[0][0];
  int*   Ri  = reinterpret_cast<int*>(&Al[0][0]) + 1024;
#pragma unroll
  for (int rep = 0; rep < 8; ++rep) {
    int idx = rep * 256 + tid;
    int d = idx >> 4, q = idx & 15;
    float4 v = *reinterpret_cast<const float4*>(z32 + (size_t)d * NTOK + tokbase + q * 4);
    *reinterpret_cast<float4*>(&Zl[d][q * 4]) = v;
  }
  __syncthreads();
  {
    int tt = tid & 63, part = tid >> 6;
    double s = 0.0;
#pragma unroll
    for (int dd = 0; dd < 32; ++dd) { double v = (double)Zl[part * 32 + dd][tt]; s += v * v; }
    znp[part][tt] = s;
  }
  __syncthreads();
  if (tid < 64) zn[tid] = (float)(((znp[0][tid] + znp[1][tid]) + znp[2][tid]) + znp[3][tid]);
  const float INF = 3.4e38f;
  float gm1[4] = {INF, INF, INF, INF};
  int   gi1[4] = {0, 0, 0, 0};
  for (int c = 0; c < 8; ++c) {
    double acc[8][4] = {};
    for (int kc = 0; kc < 4; ++kc) {
      __syncthreads();
      if (kc == 0 && tid < 128) Cn[tid] = cbn32b[c * 128 + tid];
#pragma unroll
      for (int rep = 0; rep < 4; ++rep) {
        int idx = rep * 256 + tid;
        int r = idx >> 3, q = idx & 7;
        float4 v = reinterpret_cast<const float4*>(cb)[(size_t)(c * 128 + r) * 32 + kc * 8 + q];
        Al[q * 4 + 0][r] = v.x; Al[q * 4 + 1][r] = v.y;
        Al[q * 4 + 2][r] = v.z; Al[q * 4 + 3][r] = v.w;
      }
      __syncthreads();
#pragma unroll
      for (int kk = 0; kk < 32; ++kk) {
        float4 a0 = *reinterpret_cast<const float4*>(&Al[kk][mx * 8]);
        float4 a1 = *reinterpret_cast<const float4*>(&Al[kk][mx * 8 + 4]);
        float4 bv = *reinterpret_cast<const float4*>(&Zl[kc * 32 + kk][nx * 4]);
        double a[8] = {a0.x, a0.y, a0.z, a0.w, a1.x, a1.y, a1.z, a1.w};
        double bb[4] = {bv.x, bv.y, bv.z, bv.w};
#pragma unroll
        for (int u = 0; u < 8; ++u)
#pragma unroll
          for (int j = 0; j < 4; ++j) acc[u][j] = fma(a[u], bb[j], acc[u][j]);
      }
    }
    float tm1[4]; int ti1[4];
#pragma unroll
    for (int j = 0; j < 4; ++j) {
      float m1 = INF; int i1 = 0;
      float znj = zn[nx * 4 + j];
#pragma unroll
      for (int u = 0; u < 8; ++u) {
        float M  = (float)acc[u][j];
        float dv = __fsub_rn(znj, __fmul_rn(2.0f, M));
        float d2 = __fadd_rn(dv, Cn[mx * 8 + u]);
        if (d2 < m1) { m1 = d2; i1 = c * 128 + mx * 8 + u; }
      }
      tm1[j] = m1; ti1[j] = i1;
    }
    __syncthreads();
#pragma unroll
    for (int j = 0; j < 4; ++j) {
      int slot = j * 256 + nx * 16 + mx;
      Rm1[slot] = tm1[j]; Ri[slot] = ti1[j];
    }
    __syncthreads();
    if (mx == 0) {
#pragma unroll
      for (int j = 0; j < 4; ++j) {
        float m1 = INF; int i1 = 0;
        for (int x = 0; x < 16; ++x) {
          int slot = j * 256 + nx * 16 + x;
          float am = Rm1[slot];
          if (am < m1) { m1 = am; i1 = Ri[slot]; }
        }
        if (m1 < gm1[j]) { gm1[j] = m1; gi1[j] = i1; }
      }
    }
  }
  if (mx == 0) {
    double lp = 0.0;
#pragma unroll
    for (int j = 0; j < 4; ++j) {
      codes[((size_t)b * NB + book) * T + t0 + nx * 4 + j] = gi1[j];
      lp += (double)gm1[j];
    }
    lred[nx] = lp;
  }
  __syncthreads();
  if (tid == 0) {
    double s = 0.0;
#pragma unroll
    for (int i = 0; i < 16; ++i) s += lred[i];
    lpart[(size_t)book * 1024 + b * 64 + blockIdx.x] = s;
  }
}

// ---------------------------------------------------------------------------
// z_q (fp32, 2% tolerance): out[b][D][t] = sum_k Wout[D][k]*qs32[k][tok] + 8*bout[D]
__global__ __launch_bounds__(256) void final32_kernel(const float* __restrict__ qs32,
                                                      const float* __restrict__ Wout,
                                                      const float* __restrict__ bout,
                                                      float* __restrict__ out) {
  __shared__ __align__(16) float Al[32][132];
  __shared__ __align__(16) float Bl[32][68];
  const int tid = threadIdx.x;
  const int t0 = blockIdx.x * 64;
  const int Dg = blockIdx.y;
  const int b  = blockIdx.z;
  const int mx = tid & 15, nx = tid >> 4;
  const size_t tokbase = (size_t)b * T + t0;
  float acc[8][4] = {};
  for (int kc = 0; kc < 4; ++kc) {
    __syncthreads();
#pragma unroll
    for (int rep = 0; rep < 4; ++rep) {
      int idx = rep * 256 + tid;
      int r = idx >> 3, q = idx & 7;
      float4 v = reinterpret_cast<const float4*>(Wout)[(size_t)(Dg * 128 + r) * 32 + kc * 8 + q];
      Al[q * 4 + 0][r] = v.x; Al[q * 4 + 1][r] = v.y;
      Al[q * 4 + 2][r] = v.z; Al[q * 4 + 3][r] = v.w;
    }
#pragma unroll
    for (int rep = 0; rep < 2; ++rep) {
      int idx = rep * 256 + tid;
      int kk = idx >> 4, q = idx & 15;
      *reinterpret_cast<float4*>(&Bl[kk][q * 4]) =
          *reinterpret_cast<const float4*>(qs32 + (size_t)(kc * 32 + kk) * NTOK + tokbase + q * 4);
    }
    __syncthreads();
#pragma unroll
    for (int kk = 0; kk < 32; ++kk) {
      float4 a0 = *reinterpret_cast<const float4*>(&Al[kk][mx * 8]);
      float4 a1 = *reinterpret_cast<const float4*>(&Al[kk][mx * 8 + 4]);
      float4 bv = *reinterpret_cast<const float4*>(&Bl[kk][nx * 4]);
      float a[8] = {a0.x, a0.y, a0.z, a0.w, a1.x, a1.y, a1.z, a1.w};
      float bb[4] = {bv.x, bv.y, bv.z, bv.w};
#pragma unroll
      for (int u = 0; u < 8; ++u)
#pragma unroll
        for (int j = 0; j < 4; ++j) acc[u][j] = fmaf(a[u], bb[j], acc[u][j]);
    }
  }
#pragma unroll
  for (int u = 0; u < 8; ++u) {
    int D = Dg * 128 + mx * 8 + u;
    float bo = 8.0f * bout[D];
    float4 o = make_float4(acc[u][0] + bo, acc[u][1] + bo, acc[u][2] + bo, acc[u][3] + bo);
    reinterpret_cast<float4*>(out + ((size_t)b * DIN + D) * T + t0)[nx] = o;
  }
}

// ---------------------------------------------------------------------------
__global__ __launch_bounds__(256) void codes_out_kernel(const int* __restrict__ codes,
                                                        float* __restrict__ out) {
  int k = blockIdx.x * 256 + threadIdx.x;
  if (k < BATCH * NB * T)
    out[(size_t)BATCH * DIN * T + k] = (float)codes[k];
}

__global__ __launch_bounds__(256) void loss_out_kernel(const double* __restrict__ lpF,
                                                       const double* __restrict__ lpS,
                                                       const int* __restrict__ probe_ok,
                                                       float* __restrict__ out) {
  __shared__ double red[256];
  const double* lp = (*probe_ok) ? lpF : lpS;
  double s = 0.0;
  for (int i = threadIdx.x; i < NB * 1024; i += 256) s += lp[i];
  red[threadIdx.x] = s;
  __syncthreads();
  for (int off = 128; off; off >>= 1) {
    if (threadIdx.x < off) red[threadIdx.x] += red[threadIdx.x + off];
    __syncthreads();
  }
  if (threadIdx.x == 0)
    out[(size_t)BATCH * DIN * T + (size_t)BATCH * NB * T] =
        (float)(red[0] * 1.25 / 8388608.0);
}

// ---------------------------------------------------------------------------
extern "C" void kernel_launch(void* const* d_in, const int* in_sizes, int n_in,
                              void* d_out, int out_size, void* d_ws, size_t ws_size,
                              hipStream_t stream) {
  (void)in_sizes; (void)n_in; (void)out_size; (void)ws_size;
  const float* z    = (const float*)d_in[0];
  const float* Win  = (const float*)d_in[1];
  const float* bin  = (const float*)d_in[2];
  const float* Wout = (const float*)d_in[3];
  const float* bout = (const float*)d_in[4];
  const float* cbs  = (const float*)d_in[5];
  float* out = (float*)d_out;
  double* Acur = (double*)d_out;   // running A [d][tok], aliases z_q region

  char* w = (char*)d_ws;
  double* PCF64 = (double*)w;  w += (size_t)NB * S * CD * 8;      // 8.4 MB
  double* P64t  = (double*)w;  w += (size_t)CD * CD * 8;
  double* cvec64= (double*)w;  w += CD * 8;
  double* lpartF= (double*)w;  w += (size_t)NB * 1024 * 8;
  double* lpartS= (double*)w;  w += (size_t)NB * 1024 * 8;
  float*  z32   = (float*)w;   w += (size_t)CD * NTOK * 4;        // 33.6 MB
  float*  qs32  = (float*)w;   w += (size_t)CD * NTOK * 4;        // 33.6 MB
  float*  cbn32 = (float*)w;   w += (size_t)NB * S * 4;
  float*  dump  = (float*)w;   w += 8192 * 4;
  unsigned short* z16  = (unsigned short*)w; w += (size_t)CD * NTOK * 2;   // 16.8 MB
  unsigned short* cb16 = (unsigned short*)w; w += (size_t)NB * S * CD * 2; // 2.1 MB
  unsigned short* fgl  = (unsigned short*)w; w += (size_t)NTOK * FCAP * 2; // 3.1 MB
  int*    fcg   = (int*)w;     w += (size_t)NTOK * 4;
  int*    codes = (int*)w;     w += (size_t)BATCH * NB * T * 4;
  int*    probe_ok = (int*)w;  w += 256;

  cbn32_kernel<<<(NB * S + 255) / 256, 256, 0, stream>>>(cbs, cbn32);
  cb16_kernel<<<(NB * S * CD + 255) / 256, 256, 0, stream>>>(cbs, cb16);
  p64t_kernel<<<64, 256, 0, stream>>>(Win, Wout, P64t);
  cvec64_kernel<<<1, 128, 0, stream>>>(Win, bout, cvec64);
  pcf_kernel<<<dim3(S, NB), 128, 0, stream>>>(cbs, P64t, cvec64, PCF64);
  a64_kernel<<<dim3(T / 64, BATCH), 256, 0, stream>>>(z, Win, bin, Acur);
  hipMemsetAsync(qs32, 0, (size_t)CD * NTOK * 4, stream);

  for (int book = 0; book < NB; ++book) {
    const float* cb = cbs + (size_t)book * S * CD;
    const unsigned short* cbh = cb16 + (size_t)book * S * CD;
    zprojf_kernel<<<(CD * NTOK) / 2048, 256, 0, stream>>>(Acur, z32, z16);
    score_mfma_kernel<<<NTOK / 64, 256, 0, stream>>>(z16, cbh, cbn32 + book * S,
                                                     fgl, fcg, dump, book);
    if (book == 0)
      probe_kernel<<<1, 256, 0, stream>>>(z16, cb16, cbn32, dump, probe_ok);
    refine_kernel<<<NTOK / 64, 256, 0, stream>>>(z32, cb, cbn32 + book * S,
                                                 fgl, fcg, probe_ok, codes, lpartF, book);
    score_fb_kernel<<<dim3(T / 64, BATCH), 256, 0, stream>>>(z32, cb, cbn32 + book * S,
                                                             codes, lpartS, probe_ok, book);
    if (book < NB - 1)
      update_kernel<false><<<NTOK / 64, 256, 0, stream>>>(
          Acur, qs32, PCF64 + (size_t)book * S * CD, cb, codes, book);
    else
      update_kernel<true><<<NTOK / 64, 256, 0, stream>>>(
          Acur, qs32, PCF64 + (size_t)book * S * CD, cb, codes, book);
  }
  final32_kernel<<<dim3(T / 64, DIN / 128, BATCH), 256, 0, stream>>>(qs32, Wout, bout, out);
  codes_out_kernel<<<(BATCH * NB * T + 255) / 256, 256, 0, stream>>>(codes, out);
  loss_out_kernel<<<1, 256, 0, stream>>>(lpartF, lpartS, probe_ok, out);
}

// Round 12
// 1487.322 us; speedup vs baseline: 6.9500x; 1.2319x over previous
//
#include <hip/hip_runtime.h>
#include <cstdint>

constexpr int NB   = 8;
constexpr int S    = 1024;
constexpr int CD   = 128;
constexpr int DIN  = 512;
constexpr int BATCH= 16;
constexpr int T    = 4096;
constexpr int NTOK = BATCH * T;        // 65536
constexpr int FCAP = 24;
constexpr float MARGIN = 4e-3f;        // > 2 * 1.3e-3 worst-case bf16 approx error

typedef __attribute__((ext_vector_type(8))) short bf16x8;
typedef __attribute__((ext_vector_type(4))) float f32x4;

__device__ __forceinline__ unsigned short f2bf(float f) {
  unsigned int u = __float_as_uint(f);
  return (unsigned short)((u + 0x7fffu + ((u >> 16) & 1u)) >> 16);
}
__device__ __forceinline__ float bf2f(unsigned short h) {
  return __uint_as_float((unsigned int)h << 16);
}

// ---------------------------------------------------------------------------
__global__ __launch_bounds__(256) void cbn32_kernel(const float* __restrict__ cbs,
                                                    float* __restrict__ cbn32) {
  int row = blockIdx.x * 256 + threadIdx.x;
  if (row >= NB * S) return;
  const float4* r4 = reinterpret_cast<const float4*>(cbs + (size_t)row * CD);
  double s = 0.0;
  for (int q = 0; q < 32; ++q) {
    float4 v = r4[q];
    s += (double)v.x * v.x + (double)v.y * v.y + (double)v.z * v.z + (double)v.w * v.w;
  }
  cbn32[row] = (float)s;
}

__global__ __launch_bounds__(256) void cb16_kernel(const float* __restrict__ cbs,
                                                   unsigned short* __restrict__ cb16) {
  int i = blockIdx.x * 256 + threadIdx.x;
  if (i < NB * S * CD) cb16[i] = f2bf(cbs[i]);
}

__global__ __launch_bounds__(256) void p64t_kernel(const float* __restrict__ Win,
                                                   const float* __restrict__ Wout,
                                                   double* __restrict__ P64t) {
  int n = blockIdx.x * 256 + threadIdx.x;   // 16384
  int k = n >> 7, d = n & 127;
  double s = 0.0;
  for (int D = 0; D < DIN; ++D)
    s = fma((double)Win[(size_t)d * DIN + D], (double)Wout[(size_t)D * CD + k], s);
  P64t[(size_t)k * CD + d] = s;
}

__global__ void cvec64_kernel(const float* __restrict__ Win,
                              const float* __restrict__ bout,
                              double* __restrict__ cvec64) {
  int d = threadIdx.x;  // 128
  double s = 0.0;
  for (int D = 0; D < DIN; ++D)
    s = fma((double)Win[(size_t)d * DIN + D], (double)bout[D], s);
  cvec64[d] = s;
}

// PCF32[book][s][d] = fl32( sum_k cb[book][s][k] * P64t[k][d] + cvec64[d] )
__global__ void pcf_kernel(const float* __restrict__ cbs,
                           const double* __restrict__ P64t,
                           const double* __restrict__ cvec64,
                           float* __restrict__ PCF32) {
  const int s = blockIdx.x, book = blockIdx.y;
  const int d = threadIdx.x;   // 128
  const float* cr = cbs + ((size_t)book * S + s) * CD;
  double acc = 0.0;
  for (int k = 0; k < CD; ++k)
    acc = fma((double)cr[k], P64t[(size_t)k * CD + d], acc);
  PCF32[((size_t)book * S + s) * CD + d] = (float)(acc + cvec64[d]);
}

// ---------------------------------------------------------------------------
// Acur[d][tok] = fp32( sum_D Win[d,D]*z[b,D,t] + bin[d] ); also z16 = bf16().
__global__ __launch_bounds__(256) void a32_kernel(const float* __restrict__ z,
                                                  const float* __restrict__ Win,
                                                  const float* __restrict__ bin,
                                                  float* __restrict__ Acur,
                                                  unsigned short* __restrict__ z16) {
  __shared__ __align__(16) float Al[32][132];
  __shared__ __align__(16) float Bl[32][68];
  const int tid = threadIdx.x;
  const int t0 = blockIdx.x * 64;
  const int b  = blockIdx.y;
  const int mx = tid & 15, nx = tid >> 4;
  float acc[8][4] = {};
  for (int kc = 0; kc < 16; ++kc) {
    __syncthreads();
#pragma unroll
    for (int rep = 0; rep < 4; ++rep) {
      int idx = rep * 256 + tid;
      int r = idx >> 3, q = idx & 7;
      float4 v = reinterpret_cast<const float4*>(Win)[(size_t)r * 128 + kc * 8 + q];
      Al[q * 4 + 0][r] = v.x; Al[q * 4 + 1][r] = v.y;
      Al[q * 4 + 2][r] = v.z; Al[q * 4 + 3][r] = v.w;
    }
#pragma unroll
    for (int rep = 0; rep < 2; ++rep) {
      int idx = rep * 256 + tid;
      int kk = idx >> 4, q = idx & 15;
      float4 v = reinterpret_cast<const float4*>(z + ((size_t)(b * DIN + kc * 32 + kk)) * T + t0)[q];
      *reinterpret_cast<float4*>(&Bl[kk][q * 4]) = v;
    }
    __syncthreads();
#pragma unroll
    for (int kk = 0; kk < 32; ++kk) {
      float4 a0 = *reinterpret_cast<const float4*>(&Al[kk][mx * 8]);
      float4 a1 = *reinterpret_cast<const float4*>(&Al[kk][mx * 8 + 4]);
      float4 bv = *reinterpret_cast<const float4*>(&Bl[kk][nx * 4]);
      float a[8] = {a0.x, a0.y, a0.z, a0.w, a1.x, a1.y, a1.z, a1.w};
      float bb[4] = {bv.x, bv.y, bv.z, bv.w};
#pragma unroll
      for (int u = 0; u < 8; ++u)
#pragma unroll
        for (int j = 0; j < 4; ++j) acc[u][j] = fmaf(a[u], bb[j], acc[u][j]);
    }
  }
#pragma unroll
  for (int u = 0; u < 8; ++u) {
    int d = mx * 8 + u;
    float bi = bin[d];
    size_t base = (size_t)d * NTOK + (size_t)b * T + t0 + nx * 4;
    float4 o = make_float4(acc[u][0] + bi, acc[u][1] + bi, acc[u][2] + bi, acc[u][3] + bi);
    *reinterpret_cast<float4*>(Acur + base) = o;
    unsigned int b0 = f2bf(o.x), b1 = f2bf(o.y), b2 = f2bf(o.z), b3 = f2bf(o.w);
    uint2 h; h.x = b0 | (b1 << 16); h.y = b2 | (b3 << 16);
    *reinterpret_cast<uint2*>(z16 + base) = h;
  }
}

// ---------------------------------------------------------------------------
// Per-book state advance (books 0..6, after codes final):
//   Acur[d][tok] -= PCF32[code][d];  z16 = bf16(new value)
__global__ __launch_bounds__(256) void advance_kernel(float* __restrict__ Acur,
                                                      unsigned short* __restrict__ z16,
                                                      const float* __restrict__ PCFb,
                                                      const int* __restrict__ codes,
                                                      int book) {
  const int tid = threadIdx.x;
  const int tok0 = blockIdx.x * 64;
  const int tl = tid & 63, h = tid >> 6;
  const int tok = tok0 + tl;
  const int b = tok >> 12, t = tok & (T - 1);
  const int code = codes[((size_t)b * NB + book) * T + t];
  const float* pr = PCFb + (size_t)code * CD + h * 32;
#pragma unroll
  for (int d = 0; d < 32; ++d) {
    size_t idx = (size_t)(h * 32 + d) * NTOK + tok;
    float v = Acur[idx] - pr[d];
    Acur[idx] = v;
    z16[idx] = f2bf(v);
  }
}

// ---------------------------------------------------------------------------
// qs32[k][tok] = sum_books cb[book][code_book(tok)][k]   (fp32, z_q only)
__global__ __launch_bounds__(256) void qsgather_kernel(const float* __restrict__ cbs,
                                                       const int* __restrict__ codes,
                                                       float* __restrict__ qs32) {
  __shared__ int cds[64][8];
  const int tid = threadIdx.x;
  const int tok0 = blockIdx.x * 64;
  const int tl = tid & 63, h = tid >> 6;
  if (tid < 64) {
    int tok = tok0 + tid, b = tok >> 12, t = tok & (T - 1);
#pragma unroll
    for (int book = 0; book < NB; ++book)
      cds[tid][book] = codes[((size_t)b * NB + book) * T + t];
  }
  __syncthreads();
  const int tok = tok0 + tl;
  float acc[32] = {};
#pragma unroll
  for (int book = 0; book < NB; ++book) {
    const float* cr = cbs + ((size_t)book * S + cds[tl][book]) * CD + h * 32;
#pragma unroll
    for (int k = 0; k < 32; ++k) acc[k] += cr[k];
  }
#pragma unroll
  for (int k = 0; k < 32; ++k)
    qs32[(size_t)(h * 32 + k) * NTOK + tok] = acc[k];
}

// ---------------------------------------------------------------------------
// bf16 MFMA approx scores, TWO-PASS (pass A: global min; pass B: flag).
__global__ __launch_bounds__(256) void score_mfma_kernel(
    const unsigned short* __restrict__ z16,
    const unsigned short* __restrict__ cb16b,
    const float* __restrict__ cbn32b,
    unsigned short* __restrict__ fgl,
    int* __restrict__ fcg,
    float* __restrict__ dump,
    int book) {
  __shared__ unsigned short cbL[128][136];
  __shared__ unsigned short ZtT[64][136];
  __shared__ float Cna[1024];
  __shared__ float gmin[64];
  __shared__ float wmin[4][64];
  __shared__ int   fcnt[64];
  __shared__ unsigned short fls[64][FCAP];
  const int tid = threadIdx.x;
  const int tok0 = blockIdx.x * 64;
  const int wv = tid >> 6, ln = tid & 63;
  const int lr = ln & 15, lg = ln >> 4;

  for (int rep = 0; rep < 4; ++rep) {           // z16 [k][tok] -> LDS [t][k]
    int idx = rep * 256 + tid;
    int k = idx >> 3, tg = idx & 7;
    bf16x8 v = *reinterpret_cast<const bf16x8*>(z16 + (size_t)k * NTOK + tok0 + tg * 8);
#pragma unroll
    for (int e = 0; e < 8; ++e) ZtT[tg * 8 + e][k] = (unsigned short)v[e];
  }
#pragma unroll
  for (int rep = 0; rep < 4; ++rep) Cna[rep * 256 + tid] = cbn32b[rep * 256 + tid];
  if (tid < 64) { gmin[tid] = 3.4e38f; fcnt[tid] = 0; }

  // ======== PASS A ========
  for (int c = 0; c < 8; ++c) {
    __syncthreads();
    for (int rep = 0; rep < 8; ++rep) {
      int idx = rep * 256 + tid;
      int s = idx >> 4, q = idx & 15;
      *reinterpret_cast<bf16x8*>(&cbL[s][q * 8]) =
          *reinterpret_cast<const bf16x8*>(cb16b + (size_t)(c * 128 + s) * 128 + q * 8);
    }
    __syncthreads();

    f32x4 acc[2][4];
#pragma unroll
    for (int ss = 0; ss < 2; ++ss)
#pragma unroll
      for (int ts = 0; ts < 4; ++ts) acc[ss][ts] = (f32x4){0.f, 0.f, 0.f, 0.f};
#pragma unroll
    for (int ks = 0; ks < 4; ++ks) {
      bf16x8 a0 = *reinterpret_cast<const bf16x8*>(&cbL[wv * 32 + lr][ks * 32 + lg * 8]);
      bf16x8 a1 = *reinterpret_cast<const bf16x8*>(&cbL[wv * 32 + 16 + lr][ks * 32 + lg * 8]);
      bf16x8 b0 = *reinterpret_cast<const bf16x8*>(&ZtT[lr][ks * 32 + lg * 8]);
      bf16x8 b1 = *reinterpret_cast<const bf16x8*>(&ZtT[16 + lr][ks * 32 + lg * 8]);
      bf16x8 b2 = *reinterpret_cast<const bf16x8*>(&ZtT[32 + lr][ks * 32 + lg * 8]);
      bf16x8 b3 = *reinterpret_cast<const bf16x8*>(&ZtT[48 + lr][ks * 32 + lg * 8]);
      acc[0][0] = __builtin_amdgcn_mfma_f32_16x16x32_bf16(a0, b0, acc[0][0], 0, 0, 0);
      acc[0][1] = __builtin_amdgcn_mfma_f32_16x16x32_bf16(a0, b1, acc[0][1], 0, 0, 0);
      acc[0][2] = __builtin_amdgcn_mfma_f32_16x16x32_bf16(a0, b2, acc[0][2], 0, 0, 0);
      acc[0][3] = __builtin_amdgcn_mfma_f32_16x16x32_bf16(a0, b3, acc[0][3], 0, 0, 0);
      acc[1][0] = __builtin_amdgcn_mfma_f32_16x16x32_bf16(a1, b0, acc[1][0], 0, 0, 0);
      acc[1][1] = __builtin_amdgcn_mfma_f32_16x16x32_bf16(a1, b1, acc[1][1], 0, 0, 0);
      acc[1][2] = __builtin_amdgcn_mfma_f32_16x16x32_bf16(a1, b2, acc[1][2], 0, 0, 0);
      acc[1][3] = __builtin_amdgcn_mfma_f32_16x16x32_bf16(a1, b3, acc[1][3], 0, 0, 0);
    }
#pragma unroll
    for (int ss = 0; ss < 2; ++ss)
#pragma unroll
      for (int ts = 0; ts < 4; ++ts)
#pragma unroll
        for (int r = 0; r < 4; ++r)
          acc[ss][ts][r] = fmaf(-2.f, acc[ss][ts][r],
                                Cna[c * 128 + wv * 32 + ss * 16 + lg * 4 + r]);
    float mts[4];
#pragma unroll
    for (int ts = 0; ts < 4; ++ts) {
      float m = acc[0][ts][0];
#pragma unroll
      for (int r = 1; r < 4; ++r) m = fminf(m, acc[0][ts][r]);
#pragma unroll
      for (int r = 0; r < 4; ++r) m = fminf(m, acc[1][ts][r]);
      m = fminf(m, __shfl_xor(m, 16));
      m = fminf(m, __shfl_xor(m, 32));
      mts[ts] = m;
    }
    if (lg == 0) {
#pragma unroll
      for (int ts = 0; ts < 4; ++ts) wmin[wv][ts * 16 + lr] = mts[ts];
    }
    __syncthreads();
    if (tid < 64) {
      float g = fminf(fminf(wmin[0][tid], wmin[1][tid]), fminf(wmin[2][tid], wmin[3][tid]));
      gmin[tid] = fminf(gmin[tid], g);
    }
  }
  __syncthreads();

  // ======== PASS B ========
  for (int c = 0; c < 8; ++c) {
    __syncthreads();
    for (int rep = 0; rep < 8; ++rep) {
      int idx = rep * 256 + tid;
      int s = idx >> 4, q = idx & 15;
      *reinterpret_cast<bf16x8*>(&cbL[s][q * 8]) =
          *reinterpret_cast<const bf16x8*>(cb16b + (size_t)(c * 128 + s) * 128 + q * 8);
    }
    __syncthreads();

    f32x4 acc[2][4];
#pragma unroll
    for (int ss = 0; ss < 2; ++ss)
#pragma unroll
      for (int ts = 0; ts < 4; ++ts) acc[ss][ts] = (f32x4){0.f, 0.f, 0.f, 0.f};
#pragma unroll
    for (int ks = 0; ks < 4; ++ks) {
      bf16x8 a0 = *reinterpret_cast<const bf16x8*>(&cbL[wv * 32 + lr][ks * 32 + lg * 8]);
      bf16x8 a1 = *reinterpret_cast<const bf16x8*>(&cbL[wv * 32 + 16 + lr][ks * 32 + lg * 8]);
      bf16x8 b0 = *reinterpret_cast<const bf16x8*>(&ZtT[lr][ks * 32 + lg * 8]);
      bf16x8 b1 = *reinterpret_cast<const bf16x8*>(&ZtT[16 + lr][ks * 32 + lg * 8]);
      bf16x8 b2 = *reinterpret_cast<const bf16x8*>(&ZtT[32 + lr][ks * 32 + lg * 8]);
      bf16x8 b3 = *reinterpret_cast<const bf16x8*>(&ZtT[48 + lr][ks * 32 + lg * 8]);
      acc[0][0] = __builtin_amdgcn_mfma_f32_16x16x32_bf16(a0, b0, acc[0][0], 0, 0, 0);
      acc[0][1] = __builtin_amdgcn_mfma_f32_16x16x32_bf16(a0, b1, acc[0][1], 0, 0, 0);
      acc[0][2] = __builtin_amdgcn_mfma_f32_16x16x32_bf16(a0, b2, acc[0][2], 0, 0, 0);
      acc[0][3] = __builtin_amdgcn_mfma_f32_16x16x32_bf16(a0, b3, acc[0][3], 0, 0, 0);
      acc[1][0] = __builtin_amdgcn_mfma_f32_16x16x32_bf16(a1, b0, acc[1][0], 0, 0, 0);
      acc[1][1] = __builtin_amdgcn_mfma_f32_16x16x32_bf16(a1, b1, acc[1][1], 0, 0, 0);
      acc[1][2] = __builtin_amdgcn_mfma_f32_16x16x32_bf16(a1, b2, acc[1][2], 0, 0, 0);
      acc[1][3] = __builtin_amdgcn_mfma_f32_16x16x32_bf16(a1, b3, acc[1][3], 0, 0, 0);
    }
#pragma unroll
    for (int ss = 0; ss < 2; ++ss)
#pragma unroll
      for (int ts = 0; ts < 4; ++ts)
#pragma unroll
        for (int r = 0; r < 4; ++r)
          acc[ss][ts][r] = fmaf(-2.f, acc[ss][ts][r],
                                Cna[c * 128 + wv * 32 + ss * 16 + lg * 4 + r]);
#pragma unroll
    for (int ts = 0; ts < 4; ++ts) {
      int t = ts * 16 + lr;
      float thr = gmin[t] + MARGIN;
#pragma unroll
      for (int ss = 0; ss < 2; ++ss)
#pragma unroll
        for (int r = 0; r < 4; ++r) {
          float v = acc[ss][ts][r];
          int s = c * 128 + wv * 32 + ss * 16 + lg * 4 + r;
          if (book == 0 && blockIdx.x == 0 && c == 0)
            dump[(size_t)(wv * 32 + ss * 16 + lg * 4 + r) * 64 + t] = v;
          if (v <= thr) {
            int pos = atomicAdd(&fcnt[t], 1);
            if (pos < FCAP) fls[t][pos] = (unsigned short)s;
          }
        }
    }
  }
  __syncthreads();
  if (tid < 64) fcg[tok0 + tid] = fcnt[tid];
  for (int idx = tid; idx < 64 * FCAP; idx += 256) {
    int t = idx / FCAP, i = idx - t * FCAP;
    fgl[(size_t)(tok0 + t) * FCAP + i] = fls[t][i];
  }
}

// ---------------------------------------------------------------------------
__global__ __launch_bounds__(256) void probe_kernel(const unsigned short* __restrict__ z16,
                                                    const unsigned short* __restrict__ cb16,
                                                    const float* __restrict__ cbn32,
                                                    const float* __restrict__ dump,
                                                    int* __restrict__ probe_ok) {
  __shared__ float red[256];
  const int tid = threadIdx.x;
  float mx = 0.f;
  for (int p = tid; p < 8192; p += 256) {
    int s = p >> 6, t = p & 63;
    double e = 0.0;
    for (int d = 0; d < 128; ++d)
      e += (double)bf2f(cb16[(size_t)s * 128 + d]) * (double)bf2f(z16[(size_t)d * NTOK + t]);
    float ref = fmaf(-2.f, (float)e, cbn32[s]);
    mx = fmaxf(mx, fabsf(ref - dump[p]));
  }
  red[tid] = mx;
  __syncthreads();
  for (int off = 128; off; off >>= 1) {
    if (tid < off) red[tid] = fmaxf(red[tid], red[tid + off]);
    __syncthreads();
  }
  if (tid == 0) *probe_ok = (red[0] < 1e-4f) ? 1 : 0;
}

// ---------------------------------------------------------------------------
// Exact candidate evaluation (bitwise round-6 numerics); block-cooperative
// full scan for FCAP overflow tokens.  z32 == Acur (fp32 [d][tok]).
__global__ __launch_bounds__(256) void refine_kernel(const float* __restrict__ z32,
                                                     const float* __restrict__ cbb,
                                                     const float* __restrict__ cbn32b,
                                                     const unsigned short* __restrict__ fgl,
                                                     const int* __restrict__ fcg,
                                                     const int* __restrict__ probe_ok,
                                                     int* __restrict__ codes,
                                                     double* __restrict__ lpartF,
                                                     int book) {
  if (!*probe_ok) return;
  __shared__ float Zl[128][64];
  __shared__ double znp[4][64];
  __shared__ float znl[64];
  __shared__ float bestv[4][64];
  __shared__ int   bests[4][64];
  __shared__ double lred[64];
  __shared__ float rm[256];
  __shared__ int   ri[256];
  __shared__ int   ovl[64];
  __shared__ int   ovn;
  __shared__ unsigned char ovf[64];
  const int tid = threadIdx.x;
  const int tok0 = blockIdx.x * 64;
  const int b = tok0 >> 12;
  const int tl = tid & 63, h = tid >> 6;
  if (tid == 0) ovn = 0;
  for (int rep = 0; rep < 8; ++rep) {
    int idx = rep * 256 + tid;
    int d = idx >> 4, q = idx & 15;
    float4 v = *reinterpret_cast<const float4*>(z32 + (size_t)d * NTOK + tok0 + q * 4);
    Zl[d][q * 4 + 0] = v.x; Zl[d][q * 4 + 1] = v.y;
    Zl[d][q * 4 + 2] = v.z; Zl[d][q * 4 + 3] = v.w;
  }
  __syncthreads();
  {
    double s = 0.0;
#pragma unroll
    for (int dd = 0; dd < 32; ++dd) { double v = (double)Zl[h * 32 + dd][tl]; s += v * v; }
    znp[h][tl] = s;
  }
  __syncthreads();
  if (tid < 64) znl[tid] = (float)(((znp[0][tid] + znp[1][tid]) + znp[2][tid]) + znp[3][tid]);
  __syncthreads();
  const float zn = znl[tl];
  const int tok = tok0 + tl;
  const int cnt = fcg[tok];
  float bm = 3.4e38f; int bi = 0x7fffffff;
  if (cnt <= FCAP) {
    if (h == 0) ovf[tl] = 0;
    for (int i = h; i < cnt; i += 4) {
      int s = fgl[(size_t)tok * FCAP + i];
      const float* cr = cbb + (size_t)s * CD;
      double e = 0.0;
      for (int d = 0; d < CD; ++d) e = fma((double)cr[d], (double)Zl[d][tl], e);
      float M = (float)e;
      float d2 = __fadd_rn(__fsub_rn(zn, __fmul_rn(2.f, M)), cbn32b[s]);
      if (d2 < bm || (d2 == bm && s < bi)) { bm = d2; bi = s; }
    }
  } else {
    if (h == 0) { int p = atomicAdd(&ovn, 1); ovl[p] = tl; ovf[tl] = 1; }
  }
  bestv[h][tl] = bm; bests[h][tl] = bi;
  __syncthreads();
  if (tid < 64 && !ovf[tid]) {
    float fv = bestv[0][tid]; int fs = bests[0][tid];
#pragma unroll
    for (int x = 1; x < 4; ++x) {
      float v = bestv[x][tid]; int s = bests[x][tid];
      if (v < fv || (v == fv && s < fs)) { fv = v; fs = s; }
    }
    codes[((size_t)b * NB + book) * T + ((tok0 + tid) & (T - 1))] = fs;
    lred[tid] = (double)fv;
  }
  __syncthreads();
  const int no = ovn;
  for (int e = 0; e < no; ++e) {
    const int tt = ovl[e];
    const float zn2 = znl[tt];
    double e0 = 0.0, e1 = 0.0, e2 = 0.0, e3 = 0.0;
    const float* c0 = cbb + (size_t)(tid      ) * CD;
    const float* c1 = cbb + (size_t)(tid + 256) * CD;
    const float* c2 = cbb + (size_t)(tid + 512) * CD;
    const float* c3 = cbb + (size_t)(tid + 768) * CD;
    for (int d = 0; d < CD; ++d) {
      double zv = (double)Zl[d][tt];
      e0 = fma((double)c0[d], zv, e0);
      e1 = fma((double)c1[d], zv, e1);
      e2 = fma((double)c2[d], zv, e2);
      e3 = fma((double)c3[d], zv, e3);
    }
    float bm2 = 3.4e38f; int bi2 = 0x7fffffff;
    {
      float d2;
      d2 = __fadd_rn(__fsub_rn(zn2, __fmul_rn(2.f, (float)e0)), cbn32b[tid]);
      if (d2 < bm2) { bm2 = d2; bi2 = tid; }
      d2 = __fadd_rn(__fsub_rn(zn2, __fmul_rn(2.f, (float)e1)), cbn32b[tid + 256]);
      if (d2 < bm2) { bm2 = d2; bi2 = tid + 256; }
      d2 = __fadd_rn(__fsub_rn(zn2, __fmul_rn(2.f, (float)e2)), cbn32b[tid + 512]);
      if (d2 < bm2) { bm2 = d2; bi2 = tid + 512; }
      d2 = __fadd_rn(__fsub_rn(zn2, __fmul_rn(2.f, (float)e3)), cbn32b[tid + 768]);
      if (d2 < bm2) { bm2 = d2; bi2 = tid + 768; }
    }
    rm[tid] = bm2; ri[tid] = bi2;
    __syncthreads();
    for (int off = 128; off; off >>= 1) {
      if (tid < off) {
        float om = rm[tid + off]; int oi = ri[tid + off];
        if (om < rm[tid] || (om == rm[tid] && oi < ri[tid])) { rm[tid] = om; ri[tid] = oi; }
      }
      __syncthreads();
    }
    if (tid == 0) {
      codes[((size_t)b * NB + book) * T + ((tok0 + tt) & (T - 1))] = ri[0];
      lred[tt] = (double)rm[0];
    }
    __syncthreads();
  }
  if (tid == 0) {
    double sum = 0.0;
    for (int i = 0; i < 64; ++i) sum += lred[i];
    lpartF[(size_t)book * 1024 + blockIdx.x] = sum;
  }
}

// ---------------------------------------------------------------------------
// FALLBACK: round-6 proven score kernel, active only if probe failed.
__global__ __launch_bounds__(256) void score_fb_kernel(const float* __restrict__ z32,
                                                       const float* __restrict__ cb,
                                                       const float* __restrict__ cbn32b,
                                                       int* __restrict__ codes,
                                                       double* __restrict__ lpart,
                                                       const int* __restrict__ probe_ok,
                                                       int book) {
  if (*probe_ok) return;
  __shared__ __align__(16) float Zl[128][68];
  __shared__ __align__(16) float Al[32][132];
  __shared__ float Cn[128];
  __shared__ double znp[4][64];
  __shared__ float zn[64];
  __shared__ double lred[16];
  const int tid = threadIdx.x;
  const int t0 = blockIdx.x * 64;
  const int b  = blockIdx.y;
  const int mx = tid & 15, nx = tid >> 4;
  const size_t tokbase = (size_t)b * T + t0;
  float* Rm1 = &Al[0][0];
  int*   Ri  = reinterpret_cast<int*>(&Al[0][0]) + 1024;
#pragma unroll
  for (int rep = 0; rep < 8; ++rep) {
    int idx = rep * 256 + tid;
    int d = idx >> 4, q = idx & 15;
    float4 v = *reinterpret_cast<const float4*>(z32 + (size_t)d * NTOK + tokbase + q * 4);
    *reinterpret_cast<float4*>(&Zl[d][q * 4]) = v;
  }
  __syncthreads();
  {
    int tt = tid & 63, part = tid >> 6;
    double s = 0.0;
#pragma unroll
    for (int dd = 0; dd < 32; ++dd) { double v = (double)Zl[part * 32 + dd][tt]; s += v * v; }
    znp[part][tt] = s;
  }
  __syncthreads();
  if (tid < 64) zn[tid] = (float)(((znp[0][tid] + znp[1][tid]) + znp[2][tid]) + znp[3][tid]);
  const float INF = 3.4e38f;
  float gm1[4] = {INF, INF, INF, INF};
  int   gi1[4] = {0, 0, 0, 0};
  for (int c = 0; c < 8; ++c) {
    double acc[8][4] = {};
    for (int kc = 0; kc < 4; ++kc) {
      __syncthreads();
      if (kc == 0 && tid < 128) Cn[tid] = cbn32b[c * 128 + tid];
#pragma unroll
      for (int rep = 0; rep < 4; ++rep) {
        int idx = rep * 256 + tid;
        int r = idx >> 3, q = idx & 7;
        float4 v = reinterpret_cast<const float4*>(cb)[(size_t)(c * 128 + r) * 32 + kc * 8 + q];
        Al[q * 4 + 0][r] = v.x; Al[q * 4 + 1][r] = v.y;
        Al[q * 4 + 2][r] = v.z; Al[q * 4 + 3][r] = v.w;
      }
      __syncthreads();
#pragma unroll
      for (int kk = 0; kk < 32; ++kk) {
        float4 a0 = *reinterpret_cast<const float4*>(&Al[kk][mx * 8]);
        float4 a1 = *reinterpret_cast<const float4*>(&Al[kk][mx * 8 + 4]);
        float4 bv = *reinterpret_cast<const float4*>(&Zl[kc * 32 + kk][nx * 4]);
        double a[8] = {a0.x, a0.y, a0.z, a0.w, a1.x, a1.y, a1.z, a1.w};
        double bb[4] = {bv.x, bv.y, bv.z, bv.w};
#pragma unroll
        for (int u = 0; u < 8; ++u)
#pragma unroll
          for (int j = 0; j < 4; ++j) acc[u][j] = fma(a[u], bb[j], acc[u][j]);
      }
    }
    float tm1[4]; int ti1[4];
#pragma unroll
    for (int j = 0; j < 4; ++j) {
      float m1 = INF; int i1 = 0;
      float znj = zn[nx * 4 + j];
#pragma unroll
      for (int u = 0; u < 8; ++u) {
        float M  = (float)acc[u][j];
        float dv = __fsub_rn(znj, __fmul_rn(2.0f, M));
        float d2 = __fadd_rn(dv, Cn[mx * 8 + u]);
        if (d2 < m1) { m1 = d2; i1 = c * 128 + mx * 8 + u; }
      }
      tm1[j] = m1; ti1[j] = i1;
    }
    __syncthreads();
#pragma unroll
    for (int j = 0; j < 4; ++j) {
      int slot = j * 256 + nx * 16 + mx;
      Rm1[slot] = tm1[j]; Ri[slot] = ti1[j];
    }
    __syncthreads();
    if (mx == 0) {
#pragma unroll
      for (int j = 0; j < 4; ++j) {
        float m1 = INF; int i1 = 0;
        for (int x = 0; x < 16; ++x) {
          int slot = j * 256 + nx * 16 + x;
          float am = Rm1[slot];
          if (am < m1) { m1 = am; i1 = Ri[slot]; }
        }
        if (m1 < gm1[j]) { gm1[j] = m1; gi1[j] = i1; }
      }
    }
  }
  if (mx == 0) {
    double lp = 0.0;
#pragma unroll
    for (int j = 0; j < 4; ++j) {
      codes[((size_t)b * NB + book) * T + t0 + nx * 4 + j] = gi1[j];
      lp += (double)gm1[j];
    }
    lred[nx] = lp;
  }
  __syncthreads();
  if (tid == 0) {
    double s = 0.0;
#pragma unroll
    for (int i = 0; i < 16; ++i) s += lred[i];
    lpart[(size_t)book * 1024 + b * 64 + blockIdx.x] = s;
  }
}

// ---------------------------------------------------------------------------
// z_q (fp32, 2% tolerance): out[b][D][t] = sum_k Wout[D][k]*qs32[k][tok] + 8*bout[D]
__global__ __launch_bounds__(256) void final32_kernel(const float* __restrict__ qs32,
                                                      const float* __restrict__ Wout,
                                                      const float* __restrict__ bout,
                                                      float* __restrict__ out) {
  __shared__ __align__(16) float Al[32][132];
  __shared__ __align__(16) float Bl[32][68];
  const int tid = threadIdx.x;
  const int t0 = blockIdx.x * 64;
  const int Dg = blockIdx.y;
  const int b  = blockIdx.z;
  const int mx = tid & 15, nx = tid >> 4;
  const size_t tokbase = (size_t)b * T + t0;
  float acc[8][4] = {};
  for (int kc = 0; kc < 4; ++kc) {
    __syncthreads();
#pragma unroll
    for (int rep = 0; rep < 4; ++rep) {
      int idx = rep * 256 + tid;
      int r = idx >> 3, q = idx & 7;
      float4 v = reinterpret_cast<const float4*>(Wout)[(size_t)(Dg * 128 + r) * 32 + kc * 8 + q];
      Al[q * 4 + 0][r] = v.x; Al[q * 4 + 1][r] = v.y;
      Al[q * 4 + 2][r] = v.z; Al[q * 4 + 3][r] = v.w;
    }
#pragma unroll
    for (int rep = 0; rep < 2; ++rep) {
      int idx = rep * 256 + tid;
      int kk = idx >> 4, q = idx & 15;
      *reinterpret_cast<float4*>(&Bl[kk][q * 4]) =
          *reinterpret_cast<const float4*>(qs32 + (size_t)(kc * 32 + kk) * NTOK + tokbase + q * 4);
    }
    __syncthreads();
#pragma unroll
    for (int kk = 0; kk < 32; ++kk) {
      float4 a0 = *reinterpret_cast<const float4*>(&Al[kk][mx * 8]);
      float4 a1 = *reinterpret_cast<const float4*>(&Al[kk][mx * 8 + 4]);
      float4 bv = *reinterpret_cast<const float4*>(&Bl[kk][nx * 4]);
      float a[8] = {a0.x, a0.y, a0.z, a0.w, a1.x, a1.y, a1.z, a1.w};
      float bb[4] = {bv.x, bv.y, bv.z, bv.w};
#pragma unroll
      for (int u = 0; u < 8; ++u)
#pragma unroll
        for (int j = 0; j < 4; ++j) acc[u][j] = fmaf(a[u], bb[j], acc[u][j]);
    }
  }
#pragma unroll
  for (int u = 0; u < 8; ++u) {
    int D = Dg * 128 + mx * 8 + u;
    float bo = 8.0f * bout[D];
    float4 o = make_float4(acc[u][0] + bo, acc[u][1] + bo, acc[u][2] + bo, acc[u][3] + bo);
    reinterpret_cast<float4*>(out + ((size_t)b * DIN + D) * T + t0)[nx] = o;
  }
}

// ---------------------------------------------------------------------------
__global__ __launch_bounds__(256) void codes_out_kernel(const int* __restrict__ codes,
                                                        float* __restrict__ out) {
  int k = blockIdx.x * 256 + threadIdx.x;
  if (k < BATCH * NB * T)
    out[(size_t)BATCH * DIN * T + k] = (float)codes[k];
}

__global__ __launch_bounds__(256) void loss_out_kernel(const double* __restrict__ lpF,
                                                       const double* __restrict__ lpS,
                                                       const int* __restrict__ probe_ok,
                                                       float* __restrict__ out) {
  __shared__ double red[256];
  const double* lp = (*probe_ok) ? lpF : lpS;
  double s = 0.0;
  for (int i = threadIdx.x; i < NB * 1024; i += 256) s += lp[i];
  red[threadIdx.x] = s;
  __syncthreads();
  for (int off = 128; off; off >>= 1) {
    if (threadIdx.x < off) red[threadIdx.x] += red[threadIdx.x + off];
    __syncthreads();
  }
  if (threadIdx.x == 0)
    out[(size_t)BATCH * DIN * T + (size_t)BATCH * NB * T] =
        (float)(red[0] * 1.25 / 8388608.0);
}

// ---------------------------------------------------------------------------
extern "C" void kernel_launch(void* const* d_in, const int* in_sizes, int n_in,
                              void* d_out, int out_size, void* d_ws, size_t ws_size,
                              hipStream_t stream) {
  (void)in_sizes; (void)n_in; (void)out_size; (void)ws_size;
  const float* z    = (const float*)d_in[0];
  const float* Win  = (const float*)d_in[1];
  const float* bin  = (const float*)d_in[2];
  const float* Wout = (const float*)d_in[3];
  const float* bout = (const float*)d_in[4];
  const float* cbs  = (const float*)d_in[5];
  float* out = (float*)d_out;
  float* Acur = out;   // fp32 running z_proj [d][tok] (33.6MB), aliases z_q region

  char* w = (char*)d_ws;
  double* P64t  = (double*)w;  w += (size_t)CD * CD * 8;
  double* cvec64= (double*)w;  w += CD * 8;
  double* lpartF= (double*)w;  w += (size_t)NB * 1024 * 8;
  double* lpartS= (double*)w;  w += (size_t)NB * 1024 * 8;
  float*  PCF32 = (float*)w;   w += (size_t)NB * S * CD * 4;      // 4.2 MB
  float*  qs32  = (float*)w;   w += (size_t)CD * NTOK * 4;        // 33.6 MB
  float*  cbn32 = (float*)w;   w += (size_t)NB * S * 4;
  float*  dump  = (float*)w;   w += 8192 * 4;
  unsigned short* z16  = (unsigned short*)w; w += (size_t)CD * NTOK * 2;   // 16.8 MB
  unsigned short* cb16 = (unsigned short*)w; w += (size_t)NB * S * CD * 2; // 2.1 MB
  unsigned short* fgl  = (unsigned short*)w; w += (size_t)NTOK * FCAP * 2; // 3.1 MB
  int*    fcg   = (int*)w;     w += (size_t)NTOK * 4;
  int*    codes = (int*)w;     w += (size_t)BATCH * NB * T * 4;
  int*    probe_ok = (int*)w;  w += 256;

  cbn32_kernel<<<(NB * S + 255) / 256, 256, 0, stream>>>(cbs, cbn32);
  cb16_kernel<<<(NB * S * CD + 255) / 256, 256, 0, stream>>>(cbs, cb16);
  p64t_kernel<<<64, 256, 0, stream>>>(Win, Wout, P64t);
  cvec64_kernel<<<1, 128, 0, stream>>>(Win, bout, cvec64);
  pcf_kernel<<<dim3(S, NB), 128, 0, stream>>>(cbs, P64t, cvec64, PCF32);
  a32_kernel<<<dim3(T / 64, BATCH), 256, 0, stream>>>(z, Win, bin, Acur, z16);

  for (int book = 0; book < NB; ++book) {
    const float* cb = cbs + (size_t)book * S * CD;
    const unsigned short* cbh = cb16 + (size_t)book * S * CD;
    score_mfma_kernel<<<NTOK / 64, 256, 0, stream>>>(z16, cbh, cbn32 + book * S,
                                                     fgl, fcg, dump, book);
    if (book == 0)
      probe_kernel<<<1, 256, 0, stream>>>(z16, cb16, cbn32, dump, probe_ok);
    refine_kernel<<<NTOK / 64, 256, 0, stream>>>(Acur, cb, cbn32 + book * S,
                                                 fgl, fcg, probe_ok, codes, lpartF, book);
    score_fb_kernel<<<dim3(T / 64, BATCH), 256, 0, stream>>>(Acur, cb, cbn32 + book * S,
                                                             codes, lpartS, probe_ok, book);
    if (book < NB - 1)
      advance_kernel<<<NTOK / 64, 256, 0, stream>>>(
          Acur, z16, PCF32 + (size_t)book * S * CD, codes, book);
  }
  qsgather_kernel<<<NTOK / 64, 256, 0, stream>>>(cbs, codes, qs32);
  final32_kernel<<<dim3(T / 64, DIN / 128, BATCH), 256, 0, stream>>>(qs32, Wout, bout, out);
  codes_out_kernel<<<(BATCH * NB * T + 255) / 256, 256, 0, stream>>>(codes, out);
  loss_out_kernel<<<1, 256, 0, stream>>>(lpartF, lpartS, probe_ok, out);
}

// Round 13
// 1217.756 us; speedup vs baseline: 8.4885x; 1.2214x over previous
//
#include <hip/hip_runtime.h>
#include <cstdint>

constexpr int NB   = 8;
constexpr int S    = 1024;
constexpr int CD   = 128;
constexpr int DIN  = 512;
constexpr int BATCH= 16;
constexpr int T    = 4096;
constexpr int NTOK = BATCH * T;        // 65536
constexpr int FCAP = 24;
constexpr float MARGIN = 4e-3f;        // > 2 * 1.3e-3 worst-case bf16 approx error

typedef __attribute__((ext_vector_type(8))) short bf16x8;
typedef __attribute__((ext_vector_type(4))) float f32x4;

__device__ __forceinline__ unsigned short f2bf(float f) {
  unsigned int u = __float_as_uint(f);
  return (unsigned short)((u + 0x7fffu + ((u >> 16) & 1u)) >> 16);
}

// ---------------------------------------------------------------------------
__global__ __launch_bounds__(256) void cbn32_kernel(const float* __restrict__ cbs,
                                                    float* __restrict__ cbn32) {
  int row = blockIdx.x * 256 + threadIdx.x;
  if (row >= NB * S) return;
  const float4* r4 = reinterpret_cast<const float4*>(cbs + (size_t)row * CD);
  double s = 0.0;
  for (int q = 0; q < 32; ++q) {
    float4 v = r4[q];
    s += (double)v.x * v.x + (double)v.y * v.y + (double)v.z * v.z + (double)v.w * v.w;
  }
  cbn32[row] = (float)s;
}

__global__ __launch_bounds__(256) void cb16_kernel(const float* __restrict__ cbs,
                                                   unsigned short* __restrict__ cb16) {
  int i = blockIdx.x * 256 + threadIdx.x;
  if (i < NB * S * CD) cb16[i] = f2bf(cbs[i]);
}

__global__ __launch_bounds__(256) void p64t_kernel(const float* __restrict__ Win,
                                                   const float* __restrict__ Wout,
                                                   double* __restrict__ P64t) {
  int n = blockIdx.x * 256 + threadIdx.x;   // 16384
  int k = n >> 7, d = n & 127;
  double s = 0.0;
  for (int D = 0; D < DIN; ++D)
    s = fma((double)Win[(size_t)d * DIN + D], (double)Wout[(size_t)D * CD + k], s);
  P64t[(size_t)k * CD + d] = s;
}

__global__ void cvec64_kernel(const float* __restrict__ Win,
                              const float* __restrict__ bout,
                              double* __restrict__ cvec64) {
  int d = threadIdx.x;  // 128
  double s = 0.0;
  for (int D = 0; D < DIN; ++D)
    s = fma((double)Win[(size_t)d * DIN + D], (double)bout[D], s);
  cvec64[d] = s;
}

// PCF32[book][s][d] = fl32( sum_k cb[book][s][k] * P64t[k][d] + cvec64[d] )
__global__ void pcf_kernel(const float* __restrict__ cbs,
                           const double* __restrict__ P64t,
                           const double* __restrict__ cvec64,
                           float* __restrict__ PCF32) {
  const int s = blockIdx.x, book = blockIdx.y;
  const int d = threadIdx.x;   // 128
  const float* cr = cbs + ((size_t)book * S + s) * CD;
  double acc = 0.0;
  for (int k = 0; k < CD; ++k)
    acc = fma((double)cr[k], P64t[(size_t)k * CD + d], acc);
  PCF32[((size_t)book * S + s) * CD + d] = (float)(acc + cvec64[d]);
}

// ---------------------------------------------------------------------------
// Acur[d][tok] = fp32( sum_D Win[d,D]*z[b,D,t] + bin[d] ); also z16 = bf16().
__global__ __launch_bounds__(256) void a32_kernel(const float* __restrict__ z,
                                                  const float* __restrict__ Win,
                                                  const float* __restrict__ bin,
                                                  float* __restrict__ Acur,
                                                  unsigned short* __restrict__ z16) {
  __shared__ __align__(16) float Al[32][132];
  __shared__ __align__(16) float Bl[32][68];
  const int tid = threadIdx.x;
  const int t0 = blockIdx.x * 64;
  const int b  = blockIdx.y;
  const int mx = tid & 15, nx = tid >> 4;
  float acc[8][4] = {};
  for (int kc = 0; kc < 16; ++kc) {
    __syncthreads();
#pragma unroll
    for (int rep = 0; rep < 4; ++rep) {
      int idx = rep * 256 + tid;
      int r = idx >> 3, q = idx & 7;
      float4 v = reinterpret_cast<const float4*>(Win)[(size_t)r * 128 + kc * 8 + q];
      Al[q * 4 + 0][r] = v.x; Al[q * 4 + 1][r] = v.y;
      Al[q * 4 + 2][r] = v.z; Al[q * 4 + 3][r] = v.w;
    }
#pragma unroll
    for (int rep = 0; rep < 2; ++rep) {
      int idx = rep * 256 + tid;
      int kk = idx >> 4, q = idx & 15;
      float4 v = reinterpret_cast<const float4*>(z + ((size_t)(b * DIN + kc * 32 + kk)) * T + t0)[q];
      *reinterpret_cast<float4*>(&Bl[kk][q * 4]) = v;
    }
    __syncthreads();
#pragma unroll
    for (int kk = 0; kk < 32; ++kk) {
      float4 a0 = *reinterpret_cast<const float4*>(&Al[kk][mx * 8]);
      float4 a1 = *reinterpret_cast<const float4*>(&Al[kk][mx * 8 + 4]);
      float4 bv = *reinterpret_cast<const float4*>(&Bl[kk][nx * 4]);
      float a[8] = {a0.x, a0.y, a0.z, a0.w, a1.x, a1.y, a1.z, a1.w};
      float bb[4] = {bv.x, bv.y, bv.z, bv.w};
#pragma unroll
      for (int u = 0; u < 8; ++u)
#pragma unroll
        for (int j = 0; j < 4; ++j) acc[u][j] = fmaf(a[u], bb[j], acc[u][j]);
    }
  }
#pragma unroll
  for (int u = 0; u < 8; ++u) {
    int d = mx * 8 + u;
    float bi = bin[d];
    size_t base = (size_t)d * NTOK + (size_t)b * T + t0 + nx * 4;
    float4 o = make_float4(acc[u][0] + bi, acc[u][1] + bi, acc[u][2] + bi, acc[u][3] + bi);
    *reinterpret_cast<float4*>(Acur + base) = o;
    unsigned int b0 = f2bf(o.x), b1 = f2bf(o.y), b2 = f2bf(o.z), b3 = f2bf(o.w);
    uint2 h; h.x = b0 | (b1 << 16); h.y = b2 | (b3 << 16);
    *reinterpret_cast<uint2*>(z16 + base) = h;
  }
}

// ---------------------------------------------------------------------------
// FUSED per-book kernel: bf16-MFMA two-pass scoring (identical numerics to
// rounds 8-12), LDS flags, then bitwise round-6 exact evaluation of flagged
// candidates (+ block-cooperative overflow scan), then in-place advance of
// Acur/z16 (books 0..6).
template <bool LAST>
__global__ __launch_bounds__(256) void fused_kernel(
    float* __restrict__ Acur,
    unsigned short* __restrict__ z16,
    const unsigned short* __restrict__ cb16b,
    const float* __restrict__ cbb,
    const float* __restrict__ cbn32b,
    const float* __restrict__ PCFb,
    int* __restrict__ codes,
    double* __restrict__ lpartF,
    int book) {
  __shared__ __align__(16) unsigned char smemA[34816];  // cbL | (epilogue) Zl
  __shared__ __align__(16) unsigned char smemB[17408];  // ZtT | epilogue arrays
  __shared__ float Cna[1024];
  __shared__ float gmin[64];
  __shared__ float wmin[4][64];
  __shared__ int   fcnt[64];
  __shared__ unsigned short fls[64][FCAP];
  __shared__ double lred[64];
  __shared__ int   scode[64];
  __shared__ int   ovn;

  auto cbL = reinterpret_cast<unsigned short(*)[136]>(smemA);
  auto ZtT = reinterpret_cast<unsigned short(*)[136]>(smemB);

  const int tid = threadIdx.x;
  const int tok0 = blockIdx.x * 64;
  const int wv = tid >> 6, ln = tid & 63;
  const int lr = ln & 15, lg = ln >> 4;

  // stage z16 [k][tok] -> ZtT [t][k]
  for (int rep = 0; rep < 4; ++rep) {
    int idx = rep * 256 + tid;
    int k = idx >> 3, tg = idx & 7;
    bf16x8 v = *reinterpret_cast<const bf16x8*>(z16 + (size_t)k * NTOK + tok0 + tg * 8);
#pragma unroll
    for (int e = 0; e < 8; ++e) ZtT[tg * 8 + e][k] = (unsigned short)v[e];
  }
#pragma unroll
  for (int rep = 0; rep < 4; ++rep) Cna[rep * 256 + tid] = cbn32b[rep * 256 + tid];
  if (tid < 64) { gmin[tid] = 3.4e38f; fcnt[tid] = 0; }

  // ======== PASS A: global min of d2a ========
  for (int c = 0; c < 8; ++c) {
    __syncthreads();
    for (int rep = 0; rep < 8; ++rep) {
      int idx = rep * 256 + tid;
      int s = idx >> 4, q = idx & 15;
      *reinterpret_cast<bf16x8*>(&cbL[s][q * 8]) =
          *reinterpret_cast<const bf16x8*>(cb16b + (size_t)(c * 128 + s) * 128 + q * 8);
    }
    __syncthreads();

    f32x4 acc[2][4];
#pragma unroll
    for (int ss = 0; ss < 2; ++ss)
#pragma unroll
      for (int ts = 0; ts < 4; ++ts) acc[ss][ts] = (f32x4){0.f, 0.f, 0.f, 0.f};
#pragma unroll
    for (int ks = 0; ks < 4; ++ks) {
      bf16x8 a0 = *reinterpret_cast<const bf16x8*>(&cbL[wv * 32 + lr][ks * 32 + lg * 8]);
      bf16x8 a1 = *reinterpret_cast<const bf16x8*>(&cbL[wv * 32 + 16 + lr][ks * 32 + lg * 8]);
      bf16x8 b0 = *reinterpret_cast<const bf16x8*>(&ZtT[lr][ks * 32 + lg * 8]);
      bf16x8 b1 = *reinterpret_cast<const bf16x8*>(&ZtT[16 + lr][ks * 32 + lg * 8]);
      bf16x8 b2 = *reinterpret_cast<const bf16x8*>(&ZtT[32 + lr][ks * 32 + lg * 8]);
      bf16x8 b3 = *reinterpret_cast<const bf16x8*>(&ZtT[48 + lr][ks * 32 + lg * 8]);
      acc[0][0] = __builtin_amdgcn_mfma_f32_16x16x32_bf16(a0, b0, acc[0][0], 0, 0, 0);
      acc[0][1] = __builtin_amdgcn_mfma_f32_16x16x32_bf16(a0, b1, acc[0][1], 0, 0, 0);
      acc[0][2] = __builtin_amdgcn_mfma_f32_16x16x32_bf16(a0, b2, acc[0][2], 0, 0, 0);
      acc[0][3] = __builtin_amdgcn_mfma_f32_16x16x32_bf16(a0, b3, acc[0][3], 0, 0, 0);
      acc[1][0] = __builtin_amdgcn_mfma_f32_16x16x32_bf16(a1, b0, acc[1][0], 0, 0, 0);
      acc[1][1] = __builtin_amdgcn_mfma_f32_16x16x32_bf16(a1, b1, acc[1][1], 0, 0, 0);
      acc[1][2] = __builtin_amdgcn_mfma_f32_16x16x32_bf16(a1, b2, acc[1][2], 0, 0, 0);
      acc[1][3] = __builtin_amdgcn_mfma_f32_16x16x32_bf16(a1, b3, acc[1][3], 0, 0, 0);
    }
#pragma unroll
    for (int ss = 0; ss < 2; ++ss)
#pragma unroll
      for (int ts = 0; ts < 4; ++ts)
#pragma unroll
        for (int r = 0; r < 4; ++r)
          acc[ss][ts][r] = fmaf(-2.f, acc[ss][ts][r],
                                Cna[c * 128 + wv * 32 + ss * 16 + lg * 4 + r]);
    float mts[4];
#pragma unroll
    for (int ts = 0; ts < 4; ++ts) {
      float m = acc[0][ts][0];
#pragma unroll
      for (int r = 1; r < 4; ++r) m = fminf(m, acc[0][ts][r]);
#pragma unroll
      for (int r = 0; r < 4; ++r) m = fminf(m, acc[1][ts][r]);
      m = fminf(m, __shfl_xor(m, 16));
      m = fminf(m, __shfl_xor(m, 32));
      mts[ts] = m;
    }
    if (lg == 0) {
#pragma unroll
      for (int ts = 0; ts < 4; ++ts) wmin[wv][ts * 16 + lr] = mts[ts];
    }
    __syncthreads();
    if (tid < 64) {
      float g = fminf(fminf(wmin[0][tid], wmin[1][tid]), fminf(wmin[2][tid], wmin[3][tid]));
      gmin[tid] = fminf(gmin[tid], g);
    }
  }
  __syncthreads();

  // ======== PASS B: recompute, flag vs global min (flags in LDS) ========
  for (int c = 0; c < 8; ++c) {
    __syncthreads();
    for (int rep = 0; rep < 8; ++rep) {
      int idx = rep * 256 + tid;
      int s = idx >> 4, q = idx & 15;
      *reinterpret_cast<bf16x8*>(&cbL[s][q * 8]) =
          *reinterpret_cast<const bf16x8*>(cb16b + (size_t)(c * 128 + s) * 128 + q * 8);
    }
    __syncthreads();

    f32x4 acc[2][4];
#pragma unroll
    for (int ss = 0; ss < 2; ++ss)
#pragma unroll
      for (int ts = 0; ts < 4; ++ts) acc[ss][ts] = (f32x4){0.f, 0.f, 0.f, 0.f};
#pragma unroll
    for (int ks = 0; ks < 4; ++ks) {
      bf16x8 a0 = *reinterpret_cast<const bf16x8*>(&cbL[wv * 32 + lr][ks * 32 + lg * 8]);
      bf16x8 a1 = *reinterpret_cast<const bf16x8*>(&cbL[wv * 32 + 16 + lr][ks * 32 + lg * 8]);
      bf16x8 b0 = *reinterpret_cast<const bf16x8*>(&ZtT[lr][ks * 32 + lg * 8]);
      bf16x8 b1 = *reinterpret_cast<const bf16x8*>(&ZtT[16 + lr][ks * 32 + lg * 8]);
      bf16x8 b2 = *reinterpret_cast<const bf16x8*>(&ZtT[32 + lr][ks * 32 + lg * 8]);
      bf16x8 b3 = *reinterpret_cast<const bf16x8*>(&ZtT[48 + lr][ks * 32 + lg * 8]);
      acc[0][0] = __builtin_amdgcn_mfma_f32_16x16x32_bf16(a0, b0, acc[0][0], 0, 0, 0);
      acc[0][1] = __builtin_amdgcn_mfma_f32_16x16x32_bf16(a0, b1, acc[0][1], 0, 0, 0);
      acc[0][2] = __builtin_amdgcn_mfma_f32_16x16x32_bf16(a0, b2, acc[0][2], 0, 0, 0);
      acc[0][3] = __builtin_amdgcn_mfma_f32_16x16x32_bf16(a0, b3, acc[0][3], 0, 0, 0);
      acc[1][0] = __builtin_amdgcn_mfma_f32_16x16x32_bf16(a1, b0, acc[1][0], 0, 0, 0);
      acc[1][1] = __builtin_amdgcn_mfma_f32_16x16x32_bf16(a1, b1, acc[1][1], 0, 0, 0);
      acc[1][2] = __builtin_amdgcn_mfma_f32_16x16x32_bf16(a1, b2, acc[1][2], 0, 0, 0);
      acc[1][3] = __builtin_amdgcn_mfma_f32_16x16x32_bf16(a1, b3, acc[1][3], 0, 0, 0);
    }
#pragma unroll
    for (int ss = 0; ss < 2; ++ss)
#pragma unroll
      for (int ts = 0; ts < 4; ++ts)
#pragma unroll
        for (int r = 0; r < 4; ++r)
          acc[ss][ts][r] = fmaf(-2.f, acc[ss][ts][r],
                                Cna[c * 128 + wv * 32 + ss * 16 + lg * 4 + r]);
#pragma unroll
    for (int ts = 0; ts < 4; ++ts) {
      int t = ts * 16 + lr;
      float thr = gmin[t] + MARGIN;
#pragma unroll
      for (int ss = 0; ss < 2; ++ss)
#pragma unroll
        for (int r = 0; r < 4; ++r) {
          float v = acc[ss][ts][r];
          int s = c * 128 + wv * 32 + ss * 16 + lg * 4 + r;
          if (v <= thr) {
            int pos = atomicAdd(&fcnt[t], 1);
            if (pos < FCAP) fls[t][pos] = (unsigned short)s;
          }
        }
    }
  }
  __syncthreads();   // all MFMA/flag work done; cbL/ZtT dead -> alias

  // ======== EPILOGUE: exact evaluation (bitwise round-6 numerics) ========
  auto Zl   = reinterpret_cast<float(*)[64]>(smemA);            // 32 KB
  auto znp  = reinterpret_cast<double(*)[64]>(smemB);           // [4][64] 2048B
  float*  znl   = reinterpret_cast<float*>(smemB + 2048);       // 256B
  auto bestv    = reinterpret_cast<float(*)[64]>(smemB + 2304); // [4][64]
  auto bests    = reinterpret_cast<int(*)[64]>(smemB + 3328);   // [4][64]
  float*  rm    = reinterpret_cast<float*>(smemB + 4352);       // [256]
  int*    ri    = reinterpret_cast<int*>(smemB + 5376);         // [256]
  int*    ovl   = reinterpret_cast<int*>(smemB + 6400);         // [64]
  unsigned char* ovf = smemB + 6656;                            // [64]

  const int b = tok0 >> 12;
  const int tl = tid & 63, h = tid >> 6;
  if (tid == 0) ovn = 0;
  for (int rep = 0; rep < 8; ++rep) {   // stage z32 (= Acur) tile
    int idx = rep * 256 + tid;
    int d = idx >> 4, q = idx & 15;
    float4 v = *reinterpret_cast<const float4*>(Acur + (size_t)d * NTOK + tok0 + q * 4);
    Zl[d][q * 4 + 0] = v.x; Zl[d][q * 4 + 1] = v.y;
    Zl[d][q * 4 + 2] = v.z; Zl[d][q * 4 + 3] = v.w;
  }
  __syncthreads();
  {
    double s = 0.0;
#pragma unroll
    for (int dd = 0; dd < 32; ++dd) { double v = (double)Zl[h * 32 + dd][tl]; s += v * v; }
    znp[h][tl] = s;
  }
  __syncthreads();
  if (tid < 64) znl[tid] = (float)(((znp[0][tid] + znp[1][tid]) + znp[2][tid]) + znp[3][tid]);
  __syncthreads();
  const float zn = znl[tl];
  const int cnt = fcnt[tl];
  float bm = 3.4e38f; int bi = 0x7fffffff;
  if (cnt <= FCAP) {
    if (h == 0) ovf[tl] = 0;
    for (int i = h; i < cnt; i += 4) {
      int s = fls[tl][i];
      const float* cr = cbb + (size_t)s * CD;
      double e = 0.0;
      for (int d = 0; d < CD; ++d) e = fma((double)cr[d], (double)Zl[d][tl], e);
      float M = (float)e;
      float d2 = __fadd_rn(__fsub_rn(zn, __fmul_rn(2.f, M)), cbn32b[s]);
      if (d2 < bm || (d2 == bm && s < bi)) { bm = d2; bi = s; }
    }
  } else {
    if (h == 0) { int p = atomicAdd(&ovn, 1); ovl[p] = tl; ovf[tl] = 1; }
  }
  bestv[h][tl] = bm; bests[h][tl] = bi;
  __syncthreads();
  if (tid < 64 && !ovf[tid]) {
    float fv = bestv[0][tid]; int fs = bests[0][tid];
#pragma unroll
    for (int x = 1; x < 4; ++x) {
      float v = bestv[x][tid]; int s = bests[x][tid];
      if (v < fv || (v == fv && s < fs)) { fv = v; fs = s; }
    }
    codes[((size_t)b * NB + book) * T + ((tok0 + tid) & (T - 1))] = fs;
    scode[tid] = fs;
    lred[tid] = (double)fv;
  }
  __syncthreads();
  const int no = ovn;
  for (int e = 0; e < no; ++e) {
    const int tt = ovl[e];
    const float zn2 = znl[tt];
    double e0 = 0.0, e1 = 0.0, e2 = 0.0, e3 = 0.0;
    const float* c0 = cbb + (size_t)(tid      ) * CD;
    const float* c1 = cbb + (size_t)(tid + 256) * CD;
    const float* c2 = cbb + (size_t)(tid + 512) * CD;
    const float* c3 = cbb + (size_t)(tid + 768) * CD;
    for (int d = 0; d < CD; ++d) {
      double zv = (double)Zl[d][tt];
      e0 = fma((double)c0[d], zv, e0);
      e1 = fma((double)c1[d], zv, e1);
      e2 = fma((double)c2[d], zv, e2);
      e3 = fma((double)c3[d], zv, e3);
    }
    float bm2 = 3.4e38f; int bi2 = 0x7fffffff;
    {
      float d2;
      d2 = __fadd_rn(__fsub_rn(zn2, __fmul_rn(2.f, (float)e0)), cbn32b[tid]);
      if (d2 < bm2) { bm2 = d2; bi2 = tid; }
      d2 = __fadd_rn(__fsub_rn(zn2, __fmul_rn(2.f, (float)e1)), cbn32b[tid + 256]);
      if (d2 < bm2) { bm2 = d2; bi2 = tid + 256; }
      d2 = __fadd_rn(__fsub_rn(zn2, __fmul_rn(2.f, (float)e2)), cbn32b[tid + 512]);
      if (d2 < bm2) { bm2 = d2; bi2 = tid + 512; }
      d2 = __fadd_rn(__fsub_rn(zn2, __fmul_rn(2.f, (float)e3)), cbn32b[tid + 768]);
      if (d2 < bm2) { bm2 = d2; bi2 = tid + 768; }
    }
    rm[tid] = bm2; ri[tid] = bi2;
    __syncthreads();
    for (int off = 128; off; off >>= 1) {
      if (tid < off) {
        float om = rm[tid + off]; int oi = ri[tid + off];
        if (om < rm[tid] || (om == rm[tid] && oi < ri[tid])) { rm[tid] = om; ri[tid] = oi; }
      }
      __syncthreads();
    }
    if (tid == 0) {
      codes[((size_t)b * NB + book) * T + ((tok0 + tt) & (T - 1))] = ri[0];
      scode[tt] = ri[0];
      lred[tt] = (double)rm[0];
    }
    __syncthreads();
  }
  if (tid == 0) {
    double sum = 0.0;
    for (int i = 0; i < 64; ++i) sum += lred[i];
    lpartF[(size_t)book * 1024 + blockIdx.x] = sum;
  }

  // ======== ADVANCE (books 0..6): Acur -= PCF[code]; z16 = bf16 ========
  if constexpr (!LAST) {
    __syncthreads();
    const int code = scode[tl];
    const float* pr = PCFb + (size_t)code * CD + h * 32;
#pragma unroll
    for (int d = 0; d < 32; ++d) {
      int dd = h * 32 + d;
      size_t idx = (size_t)dd * NTOK + tok0 + tl;
      float v = Zl[dd][tl] - pr[d];
      Acur[idx] = v;
      z16[idx] = f2bf(v);
    }
  }
}

// ---------------------------------------------------------------------------
// qs32[k][tok] = sum_books cb[book][code_book(tok)][k]   (fp32, z_q only)
__global__ __launch_bounds__(256) void qsgather_kernel(const float* __restrict__ cbs,
                                                       const int* __restrict__ codes,
                                                       float* __restrict__ qs32) {
  __shared__ int cds[64][8];
  const int tid = threadIdx.x;
  const int tok0 = blockIdx.x * 64;
  const int tl = tid & 63, h = tid >> 6;
  if (tid < 64) {
    int tok = tok0 + tid, b = tok >> 12, t = tok & (T - 1);
#pragma unroll
    for (int book = 0; book < NB; ++book)
      cds[tid][book] = codes[((size_t)b * NB + book) * T + t];
  }
  __syncthreads();
  const int tok = tok0 + tl;
  float acc[32] = {};
#pragma unroll
  for (int book = 0; book < NB; ++book) {
    const float* cr = cbs + ((size_t)book * S + cds[tl][book]) * CD + h * 32;
#pragma unroll
    for (int k = 0; k < 32; ++k) acc[k] += cr[k];
  }
#pragma unroll
  for (int k = 0; k < 32; ++k)
    qs32[(size_t)(h * 32 + k) * NTOK + tok] = acc[k];
}

// ---------------------------------------------------------------------------
// z_q (fp32, 2% tolerance): out[b][D][t] = sum_k Wout[D][k]*qs32[k][tok] + 8*bout[D]
__global__ __launch_bounds__(256) void final32_kernel(const float* __restrict__ qs32,
                                                      const float* __restrict__ Wout,
                                                      const float* __restrict__ bout,
                                                      float* __restrict__ out) {
  __shared__ __align__(16) float Al[32][132];
  __shared__ __align__(16) float Bl[32][68];
  const int tid = threadIdx.x;
  const int t0 = blockIdx.x * 64;
  const int Dg = blockIdx.y;
  const int b  = blockIdx.z;
  const int mx = tid & 15, nx = tid >> 4;
  const size_t tokbase = (size_t)b * T + t0;
  float acc[8][4] = {};
  for (int kc = 0; kc < 4; ++kc) {
    __syncthreads();
#pragma unroll
    for (int rep = 0; rep < 4; ++rep) {
      int idx = rep * 256 + tid;
      int r = idx >> 3, q = idx & 7;
      float4 v = reinterpret_cast<const float4*>(Wout)[(size_t)(Dg * 128 + r) * 32 + kc * 8 + q];
      Al[q * 4 + 0][r] = v.x; Al[q * 4 + 1][r] = v.y;
      Al[q * 4 + 2][r] = v.z; Al[q * 4 + 3][r] = v.w;
    }
#pragma unroll
    for (int rep = 0; rep < 2; ++rep) {
      int idx = rep * 256 + tid;
      int kk = idx >> 4, q = idx & 15;
      *reinterpret_cast<float4*>(&Bl[kk][q * 4]) =
          *reinterpret_cast<const float4*>(qs32 + (size_t)(kc * 32 + kk) * NTOK + tokbase + q * 4);
    }
    __syncthreads();
#pragma unroll
    for (int kk = 0; kk < 32; ++kk) {
      float4 a0 = *reinterpret_cast<const float4*>(&Al[kk][mx * 8]);
      float4 a1 = *reinterpret_cast<const float4*>(&Al[kk][mx * 8 + 4]);
      float4 bv = *reinterpret_cast<const float4*>(&Bl[kk][nx * 4]);
      float a[8] = {a0.x, a0.y, a0.z, a0.w, a1.x, a1.y, a1.z, a1.w};
      float bb[4] = {bv.x, bv.y, bv.z, bv.w};
#pragma unroll
      for (int u = 0; u < 8; ++u)
#pragma unroll
        for (int j = 0; j < 4; ++j) acc[u][j] = fmaf(a[u], bb[j], acc[u][j]);
    }
  }
#pragma unroll
  for (int u = 0; u < 8; ++u) {
    int D = Dg * 128 + mx * 8 + u;
    float bo = 8.0f * bout[D];
    float4 o = make_float4(acc[u][0] + bo, acc[u][1] + bo, acc[u][2] + bo, acc[u][3] + bo);
    reinterpret_cast<float4*>(out + ((size_t)b * DIN + D) * T + t0)[nx] = o;
  }
}

// ---------------------------------------------------------------------------
__global__ __launch_bounds__(256) void codes_out_kernel(const int* __restrict__ codes,
                                                        float* __restrict__ out) {
  int k = blockIdx.x * 256 + threadIdx.x;
  if (k < BATCH * NB * T)
    out[(size_t)BATCH * DIN * T + k] = (float)codes[k];
}

__global__ __launch_bounds__(256) void loss_out_kernel(const double* __restrict__ lpF,
                                                       float* __restrict__ out) {
  __shared__ double red[256];
  double s = 0.0;
  for (int i = threadIdx.x; i < NB * 1024; i += 256) s += lpF[i];
  red[threadIdx.x] = s;
  __syncthreads();
  for (int off = 128; off; off >>= 1) {
    if (threadIdx.x < off) red[threadIdx.x] += red[threadIdx.x + off];
    __syncthreads();
  }
  if (threadIdx.x == 0)
    out[(size_t)BATCH * DIN * T + (size_t)BATCH * NB * T] =
        (float)(red[0] * 1.25 / 8388608.0);
}

// ---------------------------------------------------------------------------
extern "C" void kernel_launch(void* const* d_in, const int* in_sizes, int n_in,
                              void* d_out, int out_size, void* d_ws, size_t ws_size,
                              hipStream_t stream) {
  (void)in_sizes; (void)n_in; (void)out_size; (void)ws_size;
  const float* z    = (const float*)d_in[0];
  const float* Win  = (const float*)d_in[1];
  const float* bin  = (const float*)d_in[2];
  const float* Wout = (const float*)d_in[3];
  const float* bout = (const float*)d_in[4];
  const float* cbs  = (const float*)d_in[5];
  float* out = (float*)d_out;
  float* Acur = out;   // fp32 running z_proj [d][tok] (33.6MB), aliases z_q region

  char* w = (char*)d_ws;
  double* P64t  = (double*)w;  w += (size_t)CD * CD * 8;
  double* cvec64= (double*)w;  w += CD * 8;
  double* lpartF= (double*)w;  w += (size_t)NB * 1024 * 8;
  float*  PCF32 = (float*)w;   w += (size_t)NB * S * CD * 4;      // 4.2 MB
  float*  qs32  = (float*)w;   w += (size_t)CD * NTOK * 4;        // 33.6 MB
  float*  cbn32 = (float*)w;   w += (size_t)NB * S * 4;
  unsigned short* z16  = (unsigned short*)w; w += (size_t)CD * NTOK * 2;   // 16.8 MB
  unsigned short* cb16 = (unsigned short*)w; w += (size_t)NB * S * CD * 2; // 2.1 MB
  int*    codes = (int*)w;     w += (size_t)BATCH * NB * T * 4;

  cbn32_kernel<<<(NB * S + 255) / 256, 256, 0, stream>>>(cbs, cbn32);
  cb16_kernel<<<(NB * S * CD + 255) / 256, 256, 0, stream>>>(cbs, cb16);
  p64t_kernel<<<64, 256, 0, stream>>>(Win, Wout, P64t);
  cvec64_kernel<<<1, 128, 0, stream>>>(Win, bout, cvec64);
  pcf_kernel<<<dim3(S, NB), 128, 0, stream>>>(cbs, P64t, cvec64, PCF32);
  a32_kernel<<<dim3(T / 64, BATCH), 256, 0, stream>>>(z, Win, bin, Acur, z16);

  for (int book = 0; book < NB; ++book) {
    const float* cb = cbs + (size_t)book * S * CD;
    const unsigned short* cbh = cb16 + (size_t)book * S * CD;
    if (book < NB - 1)
      fused_kernel<false><<<NTOK / 64, 256, 0, stream>>>(
          Acur, z16, cbh, cb, cbn32 + book * S,
          PCF32 + (size_t)book * S * CD, codes, lpartF, book);
    else
      fused_kernel<true><<<NTOK / 64, 256, 0, stream>>>(
          Acur, z16, cbh, cb, cbn32 + book * S,
          PCF32 + (size_t)book * S * CD, codes, lpartF, book);
  }
  qsgather_kernel<<<NTOK / 64, 256, 0, stream>>>(cbs, codes, qs32);
  final32_kernel<<<dim3(T / 64, DIN / 128, BATCH), 256, 0, stream>>>(qs32, Wout, bout, out);
  codes_out_kernel<<<(BATCH * NB * T + 255) / 256, 256, 0, stream>>>(codes, out);
  loss_out_kernel<<<1, 256, 0, stream>>>(lpartF, out);
}